// Round 3
// baseline (230.999 us; speedup 1.0000x reference)
//
#include <hip/hip_runtime.h>
#include <math.h>

#define NB 64
#define NS 256
#define ND 64
#define NH2 64
#define NH 128

// d_out layout (floats):
// 0: out_c[64*3]; 192: rx[64]; 256: ry[64]; 320: ex[64]; 384: ey[64];
// 448: out_c_f[64*3]; 640: prob1[64*3]; 832: prob2[64*3]   (total 1024)

#define FMA8(A_, a_, w0_, w1_) \
    A_[0]+=a_*w0_.x; A_[1]+=a_*w0_.y; A_[2]+=a_*w0_.z; A_[3]+=a_*w0_.w; \
    A_[4]+=a_*w1_.x; A_[5]+=a_*w1_.y; A_[6]+=a_*w1_.z; A_[7]+=a_*w1_.w;

// =================== K1: fused mlp11(x,y) + out_c chain partial means ===================
__global__ __launch_bounds__(512) void k1_fused(
    const float* __restrict__ x, const float* __restrict__ y,
    const float* __restrict__ w11_1, const float* __restrict__ b11_1,
    const float* __restrict__ w11_2, const float* __restrict__ b11_2,
    const float* __restrict__ w12_1, const float* __restrict__ b12_1,
    const float* __restrict__ w12_2, const float* __restrict__ b12_2,
    float* __restrict__ out_x, float* __restrict__ out_y,
    float* __restrict__ mean_part)
{
    const int b = blockIdx.x >> 2, tile = blockIdx.x & 3;
    const int t = threadIdx.x;
    const int row0 = b*NS + tile*64;

    __shared__ float sW1[64*64];
    __shared__ float sW2[64*64];
    __shared__ float sX [64*68];
    __shared__ float sH [64*68];
    __shared__ float sIN[64*132];
    __shared__ float sH2[64*132];

    // stage mlp11 weights (4096 floats each = 1024 float4, 2 per thread)
    {
        const float4* g1 = (const float4*)w11_1;
        const float4* g2 = (const float4*)w11_2;
        float4* d1 = (float4*)sW1;
        float4* d2 = (float4*)sW2;
        #pragma unroll
        for (int u=0;u<2;u++){ d1[t+512*u] = g1[t+512*u]; d2[t+512*u] = g2[t+512*u]; }
    }

    const int r8  = t>>3;          // 0..63 row
    const int c8  = (t&7)*8;       // 8-col group (64-wide GEMMs)
    const int r16 = t>>4;          // 0..31 (GEMM1 rows r16, r16+32)
    const int c8b = (t&15)*8;      // 8-col group (128-wide GEMM1)

    for (int s=0; s<2; s++){
        const float* src = s ? y : x;
        float* dstG = s ? out_y : out_x;
        #pragma unroll
        for (int u=0;u<2;u++){
            int id = t + 512*u;
            int rr = id>>4, c4 = (id&15)*4;
            *(float4*)(sX + rr*68 + c4) = *(const float4*)(src + ((size_t)(row0+rr))*ND + c4);
        }
        __syncthreads();
        // H = relu(X @ W1 + b1)
        {
            float acc[8];
            #pragma unroll
            for (int u=0;u<8;u++) acc[u] = b11_1[c8+u];
            for (int k=0;k<64;k++){
                float a0 = sX[r8*68 + k];
                const float4* w = (const float4*)(sW1 + k*64 + c8);
                float4 w0 = w[0], w1 = w[1];
                FMA8(acc, a0, w0, w1);
            }
            *(float4*)(sH + r8*68 + c8)   = make_float4(fmaxf(acc[0],0.f),fmaxf(acc[1],0.f),fmaxf(acc[2],0.f),fmaxf(acc[3],0.f));
            *(float4*)(sH + r8*68 + c8+4) = make_float4(fmaxf(acc[4],0.f),fmaxf(acc[5],0.f),fmaxf(acc[6],0.f),fmaxf(acc[7],0.f));
        }
        __syncthreads();
        // O = H @ W2 + b2 (no relu) -> global + sIN
        {
            float acc[8];
            #pragma unroll
            for (int u=0;u<8;u++) acc[u] = b11_2[c8+u];
            for (int k=0;k<64;k++){
                float a0 = sH[r8*68 + k];
                const float4* w = (const float4*)(sW2 + k*64 + c8);
                float4 w0 = w[0], w1 = w[1];
                FMA8(acc, a0, w0, w1);
            }
            float4 v0 = make_float4(acc[0],acc[1],acc[2],acc[3]);
            float4 v1 = make_float4(acc[4],acc[5],acc[6],acc[7]);
            *(float4*)(dstG + ((size_t)(row0+r8))*NH2 + c8)   = v0;
            *(float4*)(dstG + ((size_t)(row0+r8))*NH2 + c8+4) = v1;
            *(float4*)(sIN + r8*132 + s*64 + c8)   = v0;
            *(float4*)(sIN + r8*132 + s*64 + c8+4) = v1;
        }
        __syncthreads();
    }

    // GEMM1: H1[64][128] = relu(sIN @ w12_1 + b12_1) -> sH2
    {
        float acc[2][8];
        #pragma unroll
        for (int v=0;v<8;v++){ float bb = b12_1[c8b+v]; acc[0][v]=bb; acc[1][v]=bb; }
        for (int kk=0;kk<4;kk++){
            __syncthreads();
            {
                const float4* g = (const float4*)(w12_1 + kk*32*NH);
                float4* d = (float4*)sW1;
                #pragma unroll
                for (int u=0;u<2;u++) d[t+512*u] = g[t+512*u];
            }
            __syncthreads();
            for (int k=0;k<32;k++){
                float a0 = sIN[r16*132      + kk*32+k];
                float a1 = sIN[(r16+32)*132 + kk*32+k];
                const float4* w = (const float4*)(sW1 + k*NH + c8b);
                float4 w0 = w[0], w1 = w[1];
                FMA8(acc[0], a0, w0, w1);
                FMA8(acc[1], a1, w0, w1);
            }
        }
        #pragma unroll
        for (int u=0;u<2;u++){
            int rr = r16 + 32*u;
            *(float4*)(sH2 + rr*132 + c8b)   = make_float4(fmaxf(acc[u][0],0.f),fmaxf(acc[u][1],0.f),fmaxf(acc[u][2],0.f),fmaxf(acc[u][3],0.f));
            *(float4*)(sH2 + rr*132 + c8b+4) = make_float4(fmaxf(acc[u][4],0.f),fmaxf(acc[u][5],0.f),fmaxf(acc[u][6],0.f),fmaxf(acc[u][7],0.f));
        }
    }
    // GEMM2b: OUT2[64][64] = relu(sH2 @ w12_2 + b12_2) -> sX
    {
        float acc[8];
        #pragma unroll
        for (int u=0;u<8;u++) acc[u] = b12_2[c8+u];
        for (int kk=0;kk<2;kk++){
            __syncthreads();
            {
                const float4* g = (const float4*)(w12_2 + kk*64*NH2);
                float4* d = (float4*)sW1;
                #pragma unroll
                for (int u=0;u<2;u++) d[t+512*u] = g[t+512*u];
            }
            __syncthreads();
            for (int k=0;k<64;k++){
                float a0 = sH2[r8*132 + kk*64+k];
                const float4* w = (const float4*)(sW1 + k*64 + c8);
                float4 w0 = w[0], w1 = w[1];
                FMA8(acc, a0, w0, w1);
            }
        }
        *(float4*)(sX + r8*68 + c8)   = make_float4(fmaxf(acc[0],0.f),fmaxf(acc[1],0.f),fmaxf(acc[2],0.f),fmaxf(acc[3],0.f));
        *(float4*)(sX + r8*68 + c8+4) = make_float4(fmaxf(acc[4],0.f),fmaxf(acc[5],0.f),fmaxf(acc[6],0.f),fmaxf(acc[7],0.f));
    }
    __syncthreads();
    if (t < 64){
        float ssum = 0.f;
        for (int r=0;r<64;r++) ssum += sX[r*68 + t];
        mean_part[((size_t)(b*4 + tile))*64 + t] = ssum;
    }
}

// =================== K2: ridge regression, 512 threads, forward Jordan ===================
__global__ __launch_bounds__(512) void k2_reg(
    const float* __restrict__ feat_x, const float* __restrict__ feat_y,
    const float* __restrict__ x, const float* __restrict__ y,
    float* __restrict__ resx, float* __restrict__ resy,
    float* __restrict__ resn, float* __restrict__ rawn,
    float* __restrict__ dout)
{
    const int b = blockIdx.x >> 1, side = blockIdx.x & 1;
    const float* feat = side ? feat_y : feat_x;
    const float* targ = side ? x : y;
    float* res = side ? resy : resx;
    const int t = threadIdx.x;
    const int lane = t & 63, wv = t >> 6;
    const int i  = t >> 3;        // 0..63
    const int qd = t & 7;
    const int c8 = qd * 8;

    __shared__ float A[65*68];
    __shared__ float R[65*68];
    __shared__ float Zt[64*68];
    __shared__ float Tt[64*68];
    __shared__ float fcol[72];
    __shared__ float csp[8*68];
    __shared__ float sc[24];

    for (int idx=t; idx<65*68; idx+=512){ A[idx]=0.f; R[idx]=0.f; }

    float Aacc[8], Racc[8];
    #pragma unroll
    for (int v=0;v<8;v++){ Aacc[v]=0.f; Racc[v]=0.f; }
    float cz=0.f, ct=0.f, tsq=0.f;
    const int cc = t & 63, rq = t >> 6;

    // ---- build raw gram A'=Z^T Z, R'=Z^T T, col sums, sum T^2 ----
    for (int tl=0; tl<4; tl++){
        if (tl) __syncthreads();
        #pragma unroll
        for (int u=0;u<2;u++){
            int id = t + 512*u;
            int rr = id >> 4, c4 = (id & 15)*4;
            *(float4*)(Zt + rr*68 + c4) = *(const float4*)(feat + ((size_t)(b*NS + tl*64 + rr))*NH2 + c4);
            *(float4*)(Tt + rr*68 + c4) = *(const float4*)(targ + ((size_t)(b*NS + tl*64 + rr))*ND  + c4);
        }
        __syncthreads();
        for (int r=0;r<64;r++){
            float a0 = Zt[r*68 + i];
            const float4* zj = (const float4*)(Zt + r*68 + c8);
            float4 z0=zj[0], z1=zj[1];
            const float4* tj = (const float4*)(Tt + r*68 + c8);
            float4 q0=tj[0], q1=tj[1];
            FMA8(Aacc, a0, z0, z1);
            FMA8(Racc, a0, q0, q1);
        }
        #pragma unroll
        for (int rr2=0; rr2<8; rr2++){
            int r = rq*8 + rr2;
            cz += Zt[r*68 + cc];
            float tv = Tt[r*68 + cc];
            ct += tv; tsq += tv*tv;
        }
    }
    __syncthreads();
    #pragma unroll
    for (int v=0;v<8;v++){
        A[(1+i)*68 + 1+c8+v] = Aacc[v];
        R[(1+i)*68 + c8+v]   = Racc[v];
    }
    csp[rq*68 + cc] = cz;
    __syncthreads();
    if (t < 64){
        float s = 0.f;
        #pragma unroll
        for (int q=0;q<8;q++) s += csp[q*68+t];
        A[0*68 + 1+t] = s;
        A[(1+t)*68 + 0] = s;
    }
    __syncthreads();
    csp[rq*68 + cc] = ct;
    __syncthreads();
    if (t < 64){
        float s = 0.f;
        #pragma unroll
        for (int q=0;q<8;q++) s += csp[q*68+t];
        R[0*68 + t] = s;
    }
    if (t==0) A[0] = 256.0f;
    {
        float tq = tsq;
        #pragma unroll
        for (int off=32; off; off>>=1) tq += __shfl_down(tq, off);
        if (lane==0) sc[8+wv] = tq;
    }
    __syncthreads();
    if (t < 64){
        float dg = A[(1+t)*68 + (1+t)];
        #pragma unroll
        for (int off=32; off; off>>=1) dg += __shfl_down(dg, off);
        if (t==0){
            float tn2 = 0.f;
            #pragma unroll
            for (int q=0;q<8;q++) tn2 += sc[8+q];
            sc[0] = 1.0f/sqrtf(dg);
            sc[1] = 1.0f/sqrtf(tn2);
        }
    }
    __syncthreads();
    const float zinv = sc[0], tinv = sc[1];
    // scale in place + ridge (REG=1, ridge[0,0]=0)
    for (int i0 = i; i0 < 65; i0 += 64){
        for (int j = qd; j < 65; j += 8){
            float f;
            if (i0==0 && j==0) f = 1.0f;
            else if (i0==0 || j==0) f = zinv;
            else f = zinv*zinv;
            float v2 = A[i0*68+j]*f;
            if (i0==j && i0>=1) v2 += 1.0f;
            A[i0*68+j] = v2;
        }
        float rf = (i0==0) ? tinv : (zinv*tinv);
        for (int d = qd; d < 64; d += 8) R[i0*68+d] *= rf;
    }
    // ---- forward Jordan elimination (2 barriers/iter) ----
    for (int k=0; k<65; k++){
        __syncthreads();
        if (t < 65) fcol[t] = A[t*68 + k];
        if (t == 80) sc[2] = 1.0f / A[k*68 + k];
        __syncthreads();
        const int ri = i + (i >= k);
        const float fi = fcol[ri] * sc[2];
        for (int q = qd; q <= 16; q += 8){
            if (4*q + 3 >= k){
                float4 pk = *(const float4*)(A + k*68 + 4*q);
                float4 pi = *(float4*)(A + ri*68 + 4*q);
                pi.x -= fi*pk.x; pi.y -= fi*pk.y; pi.z -= fi*pk.z; pi.w -= fi*pk.w;
                *(float4*)(A + ri*68 + 4*q) = pi;
            }
        }
        #pragma unroll
        for (int m=0;m<2;m++){
            int q = qd + 8*m;
            float4 rk = *(const float4*)(R + k*68 + 4*q);
            float4 rr4 = *(float4*)(R + ri*68 + 4*q);
            rr4.x -= fi*rk.x; rr4.y -= fi*rk.y; rr4.z -= fi*rk.z; rr4.w -= fi*rk.w;
            *(float4*)(R + ri*68 + 4*q) = rr4;
        }
    }
    __syncthreads();
    // W = R / diag(A)
    for (int i0 = i; i0 < 65; i0 += 64){
        float dinv = 1.0f / A[i0*68 + i0];
        #pragma unroll
        for (int m=0;m<2;m++){
            int q = qd + 8*m;
            float4 r4 = *(float4*)(R + i0*68 + 4*q);
            r4.x*=dinv; r4.y*=dinv; r4.z*=dinv; r4.w*=dinv;
            *(float4*)(R + i0*68 + 4*q) = r4;
        }
    }
    if (t==0) sc[3] = 0.f;
    // ---- residual passes (4 x 64 rows, one row per thread-group of 8) ----
    float* rnp = Tt;
    float* rqp = Tt + 64*9;
    for (int pass=0; pass<4; pass++){
        __syncthreads();
        #pragma unroll
        for (int u=0;u<2;u++){
            int id = t + 512*u;
            int rr = id >> 4, c4 = (id & 15)*4;
            float4 v4 = *(const float4*)(feat + ((size_t)(b*NS + pass*64 + rr))*NH2 + c4);
            v4.x*=zinv; v4.y*=zinv; v4.z*=zinv; v4.w*=zinv;
            *(float4*)(Zt + rr*68 + c4) = v4;
        }
        __syncthreads();
        float acc[8];
        {
            const float4* w = (const float4*)(R + 0*68 + c8);
            float4 w0=w[0], w1=w[1];
            acc[0]=w0.x; acc[1]=w0.y; acc[2]=w0.z; acc[3]=w0.w;
            acc[4]=w1.x; acc[5]=w1.y; acc[6]=w1.z; acc[7]=w1.w;
        }
        for (int j=1;j<=64;j++){
            float a0 = Zt[i*68 + (j-1)];
            const float4* w = (const float4*)(R + j*68 + c8);
            float4 w0=w[0], w1=w[1];
            FMA8(acc, a0, w0, w1);
        }
        int gr = b*NS + pass*64 + i;
        const float4* tg = (const float4*)(targ + (size_t)gr*ND + c8);
        float4 q0 = tg[0], q1 = tg[1];
        float rv0 = q0.x*tinv - acc[0];
        float rv1 = q0.y*tinv - acc[1];
        float rv2 = q0.z*tinv - acc[2];
        float rv3 = q0.w*tinv - acc[3];
        float rv4 = q1.x*tinv - acc[4];
        float rv5 = q1.y*tinv - acc[5];
        float rv6 = q1.z*tinv - acc[6];
        float rv7 = q1.w*tinv - acc[7];
        float rn_ = rv0*rv0+rv1*rv1+rv2*rv2+rv3*rv3+rv4*rv4+rv5*rv5+rv6*rv6+rv7*rv7;
        float rq_ = q0.x*q0.x+q0.y*q0.y+q0.z*q0.z+q0.w*q0.w
                  + q1.x*q1.x+q1.y*q1.y+q1.z*q1.z+q1.w*q1.w;
        *(float4*)(res + (size_t)gr*ND + c8)     = make_float4(rv0,rv1,rv2,rv3);
        *(float4*)(res + (size_t)gr*ND + c8 + 4) = make_float4(rv4,rv5,rv6,rv7);
        rnp[i*9 + qd] = rn_;
        rqp[i*9 + qd] = rq_;
        __syncthreads();
        if (t < 64){
            float rn2=0.f, rq2=0.f;
            #pragma unroll
            for (int g=0; g<8; g++){ rn2 += rnp[t*9+g]; rq2 += rqp[t*9+g]; }
            resn[((size_t)(side*NB + b))*NS + pass*64 + t] = rn2;
            rawn[((size_t)(side*NB + b))*NS + pass*64 + t] = rq2;
            float l = rn2;
            #pragma unroll
            for (int off=32; off; off>>=1) l += __shfl_down(l, off);
            if (t==0) sc[3] += l;
        }
    }
    __syncthreads();
    if (t==0) dout[(side?256:192) + b] = sc[3];
}

// =================== K3: Renyi-2 via register-resident i-rows + broadcast j-tiles ===================
__global__ __launch_bounds__(256) void k3_renyi(
    const float* __restrict__ resx, const float* __restrict__ resy,
    const float* __restrict__ x, const float* __restrict__ y,
    const float* __restrict__ resn, const float* __restrict__ rawn,
    float* __restrict__ part3)
{
    const int blk = blockIdx.x;
    const int b = blk >> 3, side = (blk >> 2) & 1, jq = blk & 3;
    const float* Am = side ? resy : resx;
    const float* Bm = side ? y : x;
    const float* nA  = resn + ((size_t)(side*NB + b))*NS;
    const float* nBr = rawn + ((size_t)((1-side)*NB + b))*NS;
    const int t = threadIdx.x;
    const int lane = t & 63, wv = t >> 6;

    __shared__ float AJ[64*68];
    __shared__ float BJ[64*68];
    __shared__ float nAJ[64], nBJ[64];
    __shared__ float red[12];

    // stage j-tile (rows jq*64..+64), row-major
    #pragma unroll
    for (int u=0;u<4;u++){
        int id = t + 256*u;          // 1024 float4 per matrix
        int rr = id >> 4, c4 = (id & 15)*4;
        *(float4*)(AJ + rr*68 + c4) = *(const float4*)(Am + ((size_t)(b*NS + jq*64 + rr))*ND + c4);
        *(float4*)(BJ + rr*68 + c4) = *(const float4*)(Bm + ((size_t)(b*NS + jq*64 + rr))*ND + c4);
    }
    if (t < 64){ nAJ[t] = nA[jq*64+t]; nBJ[t] = nBr[jq*64+t]; }

    // own i-row in registers (i = t)
    float4 ar[16], br[16];
    {
        const float4* ga = (const float4*)(Am + ((size_t)(b*NS + t))*ND);
        const float4* gb = (const float4*)(Bm + ((size_t)(b*NS + t))*ND);
        #pragma unroll
        for (int c=0;c<16;c++){ ar[c]=ga[c]; br[c]=gb[c]; }
    }
    const float nAi = nA[t], nBi = nBr[t];
    __syncthreads();

    float Sa=0.f, Sb=0.f, Sab=0.f;
    for (int j=0;j<64;j++){
        const float4* aj = (const float4*)(AJ + j*68);
        const float4* bj = (const float4*)(BJ + j*68);
        float dax=0.f, day=0.f, daz=0.f, daw=0.f;
        float dbx=0.f, dby=0.f, dbz=0.f, dbw=0.f;
        #pragma unroll
        for (int c=0;c<16;c++){
            float4 av = aj[c];
            dax += ar[c].x*av.x; day += ar[c].y*av.y; daz += ar[c].z*av.z; daw += ar[c].w*av.w;
            float4 bv = bj[c];
            dbx += br[c].x*bv.x; dby += br[c].y*bv.y; dbz += br[c].z*bv.z; dbw += br[c].w*bv.w;
        }
        float da = (dax+day)+(daz+daw);
        float db = (dbx+dby)+(dbz+dbw);
        float dda = nAi + nAJ[j] - 2.f*da;
        float ddb = nBi + nBJ[j] - 2.f*db;
        Sa  += __expf(-2.f*dda);
        Sb  += __expf(-2.f*ddb);
        Sab += __expf(-2.f*(dda+ddb));
    }
    #pragma unroll
    for (int off=32; off; off>>=1){
        Sa += __shfl_down(Sa,off); Sb += __shfl_down(Sb,off); Sab += __shfl_down(Sab,off);
    }
    if (lane==0){ red[wv*3+0]=Sa; red[wv*3+1]=Sb; red[wv*3+2]=Sab; }
    __syncthreads();
    if (t==0){
        float* o = part3 + ((size_t)((side*NB + b)*4 + jq))*3;
        o[0] = red[0]+red[3]+red[6]+red[9];
        o[1] = red[1]+red[4]+red[7]+red[10];
        o[2] = red[2]+red[5]+red[8]+red[11];
    }
}

// =================== K4: out_c/prob1, ex/ey combine, BN + final MLP ===================
__global__ __launch_bounds__(64) void k4_final(
    const float* __restrict__ mean_part, const float* __restrict__ part3,
    const float* __restrict__ wc1, const float* __restrict__ bc1,
    const float* __restrict__ bn_gamma, const float* __restrict__ bn_beta,
    const float* __restrict__ w2, const float* __restrict__ b2,
    const float* __restrict__ wc2, const float* __restrict__ bc2,
    float* __restrict__ dout)
{
    const int t = threadIdx.x;   // batch index
    __shared__ float ic[64][5];
    __shared__ float mu[5], iv[5];

    float o0 = bc1[0], o1 = bc1[1], o2 = bc1[2];
    for (int c=0;c<64;c++){
        float mv = mean_part[(t*4+0)*64+c] + mean_part[(t*4+1)*64+c]
                 + mean_part[(t*4+2)*64+c] + mean_part[(t*4+3)*64+c];
        mv *= (1.0f/256.0f);
        o0 += mv*wc1[c*3+0]; o1 += mv*wc1[c*3+1]; o2 += mv*wc1[c*3+2];
    }
    dout[t*3+0]=o0; dout[t*3+1]=o1; dout[t*3+2]=o2;
    {
        float m = fmaxf(o0,fmaxf(o1,o2));
        float e0=__expf(o0-m), e1=__expf(o1-m), e2=__expf(o2-m);
        float inv = 1.f/(e0+e1+e2);
        dout[640+t*3+0]=e0*inv; dout[640+t*3+1]=e1*inv; dout[640+t*3+2]=e2*inv;
    }
    float exy[2];
    #pragma unroll
    for (int side=0; side<2; side++){
        const float* pp = part3 + ((size_t)((side*NB + t)*4))*3;
        float Sa = pp[0]+pp[3]+pp[6]+pp[9];
        float Sb = pp[1]+pp[4]+pp[7]+pp[10];
        float Sab= pp[2]+pp[5]+pp[8]+pp[11];
        float Hx  = 16.f - log2f(Sa);
        float Hy  = 16.f - log2f(Sb);
        float Hxy = 16.f - log2f(Sab);
        float mi = (Hx + Hy - Hxy) / fmaxf(Hx, Hy);
        dout[(side?384:320)+t] = mi;
        exy[side] = mi;
    }
    ic[t][0]=o0; ic[t][1]=o1; ic[t][2]=o2; ic[t][3]=exy[0]; ic[t][4]=exy[1];
    __syncthreads();
    if (t<5){
        float m=0.f;
        for (int bb=0;bb<64;bb++) m += ic[bb][t];
        m *= (1.f/64.f);
        float v=0.f;
        for (int bb=0;bb<64;bb++){ float d=ic[bb][t]-m; v+=d*d; }
        v *= (1.f/64.f);
        mu[t]=m; iv[t]=1.f/sqrtf(v+1e-5f);
    }
    __syncthreads();
    float vn[5];
    #pragma unroll
    for (int c=0;c<5;c++) vn[c] = (ic[t][c]-mu[c])*iv[c]*bn_gamma[c]+bn_beta[c];
    float q0=bc2[0], q1=bc2[1], q2=bc2[2];
    for (int j=0;j<64;j++){
        float hh = b2[j];
        #pragma unroll
        for (int c=0;c<5;c++) hh += vn[c]*w2[c*64+j];
        hh = fmaxf(hh,0.f);
        q0 += hh*wc2[j*3+0]; q1 += hh*wc2[j*3+1]; q2 += hh*wc2[j*3+2];
    }
    dout[448+t*3+0]=q0; dout[448+t*3+1]=q1; dout[448+t*3+2]=q2;
    float m = fmaxf(q0,fmaxf(q1,q2));
    float e0=__expf(q0-m), e1=__expf(q1-m), e2=__expf(q2-m);
    float inv=1.f/(e0+e1+e2);
    dout[832+t*3+0]=e0*inv; dout[832+t*3+1]=e1*inv; dout[832+t*3+2]=e2*inv;
}

extern "C" void kernel_launch(void* const* d_in, const int* in_sizes, int n_in,
                              void* d_out, int out_size, void* d_ws, size_t ws_size,
                              hipStream_t stream)
{
    const float* x     = (const float*)d_in[0];
    const float* y     = (const float*)d_in[1];
    const float* w11_1 = (const float*)d_in[2];
    const float* b11_1 = (const float*)d_in[3];
    const float* w11_2 = (const float*)d_in[4];
    const float* b11_2 = (const float*)d_in[5];
    const float* w12_1 = (const float*)d_in[6];
    const float* b12_1 = (const float*)d_in[7];
    const float* w12_2 = (const float*)d_in[8];
    const float* b12_2 = (const float*)d_in[9];
    const float* wc1   = (const float*)d_in[10];
    const float* bc1   = (const float*)d_in[11];
    const float* bn_g  = (const float*)d_in[12];
    const float* bn_b  = (const float*)d_in[13];
    const float* w2    = (const float*)d_in[14];
    const float* b2    = (const float*)d_in[15];
    const float* wc2   = (const float*)d_in[16];
    const float* bc2   = (const float*)d_in[17];

    float* dout = (float*)d_out;
    float* ws   = (float*)d_ws;
    float* out_x = ws;                       // 1,048,576 floats
    float* out_y = ws + (1u<<20);
    float* resx  = ws + (2u<<20);
    float* resy  = ws + (3u<<20);
    float* resn  = ws + (4u<<20);            // 2*64*256 = 32768
    float* rawn  = resn + 2*NB*NS;           // 32768
    float* mean_part = rawn + 2*NB*NS;       // 64*4*64 = 16384
    float* part3 = mean_part + NB*4*64;      // 64*2*4*3 = 1536

    hipLaunchKernelGGL(k1_fused, dim3(NB*4), dim3(512), 0, stream,
        x,y,w11_1,b11_1,w11_2,b11_2,w12_1,b12_1,w12_2,b12_2,
        out_x,out_y,mean_part);
    hipLaunchKernelGGL(k2_reg, dim3(2*NB), dim3(512), 0, stream,
        out_x,out_y,x,y,resx,resy,resn,rawn,dout);
    hipLaunchKernelGGL(k3_renyi, dim3(NB*8), dim3(256), 0, stream,
        resx,resy,x,y,resn,rawn,part3);
    hipLaunchKernelGGL(k4_final, dim3(1), dim3(64), 0, stream,
        mean_part,part3,wc1,bc1,bn_g,bn_b,w2,b2,wc2,bc2,dout);
}

// Round 4
// 184.735 us; speedup vs baseline: 1.2504x; 1.2504x over previous
//
#include <hip/hip_runtime.h>
#include <math.h>

#define NB 64
#define NS 256
#define ND 64
#define NH2 64
#define NH 128
#define GSTRIDE 8448
#define WSTRIDE 4224

// d_out layout (floats):
// 0: out_c[64*3]; 192: rx[64]; 256: ry[64]; 320: ex[64]; 384: ey[64];
// 448: out_c_f[64*3]; 640: prob1[64*3]; 832: prob2[64*3]

#define F4E(v_, e_) ((e_)==0?(v_).x:((e_)==1?(v_).y:((e_)==2?(v_).z:(v_).w)))

__device__ __forceinline__ void gemm64_4x4(
    const float* __restrict__ Xs, const float* __restrict__ Ws,
    const float* __restrict__ bias, int ig, int j0, float acc[4][4])
{
    #pragma unroll
    for (int u=0;u<4;u++)
        #pragma unroll
        for (int v=0;v<4;v++) acc[u][v] = bias[j0+v];
    #pragma unroll
    for (int ch=0; ch<16; ch++){
        const int k0 = ch*4;
        float4 xi[4], wr[4];
        #pragma unroll
        for (int u=0;u<4;u++) xi[u] = *(const float4*)(Xs + (ig+16*u)*68 + k0);
        #pragma unroll
        for (int c=0;c<4;c++) wr[c] = *(const float4*)(Ws + (k0+c)*68 + j0);
        #pragma unroll
        for (int u=0;u<4;u++){
            #pragma unroll
            for (int c=0;c<4;c++){
                const float xc = F4E(xi[u], c);
                const float4 w4 = wr[c];
                acc[u][0] += xc*w4.x; acc[u][1] += xc*w4.y;
                acc[u][2] += xc*w4.z; acc[u][3] += xc*w4.w;
            }
        }
    }
}

// =================== K1 ===================
__global__ __launch_bounds__(256) void k1_fused(
    const float* __restrict__ x, const float* __restrict__ y,
    const float* __restrict__ w11_1, const float* __restrict__ b11_1,
    const float* __restrict__ w11_2, const float* __restrict__ b11_2,
    const float* __restrict__ w12_1, const float* __restrict__ b12_1,
    const float* __restrict__ w12_2, const float* __restrict__ b12_2,
    float* __restrict__ out_x, float* __restrict__ out_y,
    float* __restrict__ mean_part)
{
    const int b = blockIdx.x >> 2, tile = blockIdx.x & 3;
    const int t = threadIdx.x;
    const int row0 = b*NS + tile*64;
    const int ig = t >> 4, jg = t & 15, j0 = jg*4;

    __shared__ float smem[6*4352 + 16*68];
    float* sX  = smem;
    float* sW1 = smem + 4352;
    float* sW2 = smem + 2*4352;
    float* sH  = smem + 3*4352;
    float* sOx = smem + 4*4352;
    float* sOy = smem + 5*4352;
    float* msum= smem + 6*4352;
    float* sH1 = smem;             // 64*132=8448 <= 8704 (sX+sW1), dead by then
    float* slab= smem + 2*4352;    // 8448 <= 8704 (sW2+sH), dead by then

    #pragma unroll
    for (int u=0;u<4;u++){
        int id = t + 256*u; int r = id>>4, c4 = (id&15)*4;
        *(float4*)(sW1 + r*68 + c4) = *(const float4*)(w11_1 + (size_t)r*64 + c4);
        *(float4*)(sW2 + r*68 + c4) = *(const float4*)(w11_2 + (size_t)r*64 + c4);
        *(float4*)(sX  + r*68 + c4) = *(const float4*)(x + ((size_t)(row0+r))*ND + c4);
    }
    __syncthreads();
    float acc[4][4];
    // G1 (x): H = relu(X W1 + b1)
    gemm64_4x4(sX, sW1, b11_1, ig, j0, acc);
    #pragma unroll
    for (int u=0;u<4;u++)
        *(float4*)(sH + (ig+16*u)*68 + j0) =
            make_float4(fmaxf(acc[u][0],0.f),fmaxf(acc[u][1],0.f),
                        fmaxf(acc[u][2],0.f),fmaxf(acc[u][3],0.f));
    __syncthreads();
    // stage X(y) concurrently with G2(x)
    #pragma unroll
    for (int u=0;u<4;u++){
        int id = t + 256*u; int r = id>>4, c4 = (id&15)*4;
        *(float4*)(sX + r*68 + c4) = *(const float4*)(y + ((size_t)(row0+r))*ND + c4);
    }
    gemm64_4x4(sH, sW2, b11_2, ig, j0, acc);
    #pragma unroll
    for (int u=0;u<4;u++){
        float4 v = make_float4(acc[u][0],acc[u][1],acc[u][2],acc[u][3]);
        *(float4*)(sOx + (ig+16*u)*68 + j0) = v;
        *(float4*)(out_x + ((size_t)(row0+ig+16*u))*NH2 + j0) = v;
    }
    __syncthreads();
    // G1 (y)
    gemm64_4x4(sX, sW1, b11_1, ig, j0, acc);
    #pragma unroll
    for (int u=0;u<4;u++)
        *(float4*)(sH + (ig+16*u)*68 + j0) =
            make_float4(fmaxf(acc[u][0],0.f),fmaxf(acc[u][1],0.f),
                        fmaxf(acc[u][2],0.f),fmaxf(acc[u][3],0.f));
    __syncthreads();
    gemm64_4x4(sH, sW2, b11_2, ig, j0, acc);
    #pragma unroll
    for (int u=0;u<4;u++){
        float4 v = make_float4(acc[u][0],acc[u][1],acc[u][2],acc[u][3]);
        *(float4*)(sOy + (ig+16*u)*68 + j0) = v;
        *(float4*)(out_y + ((size_t)(row0+ig+16*u))*NH2 + j0) = v;
    }
    __syncthreads();
    // G3: H1 = relu([Ox|Oy] @ w12_1 + b12_1), 64x128, k=128 in two halves
    float accA[4][4], accB[4][4];
    #pragma unroll
    for (int u=0;u<4;u++)
        #pragma unroll
        for (int v=0;v<4;v++){ accA[u][v] = b12_1[j0+v]; accB[u][v] = b12_1[64+j0+v]; }
    for (int half=0; half<2; half++){
        #pragma unroll
        for (int u=0;u<8;u++){
            int id = t + 256*u; int r = id>>5, c4 = (id&31)*4;
            *(float4*)(slab + r*132 + c4) = *(const float4*)(w12_1 + (size_t)(half*64+r)*NH + c4);
        }
        __syncthreads();
        const float* src = half ? sOy : sOx;
        #pragma unroll
        for (int ch=0; ch<16; ch++){
            const int k0 = ch*4;
            float4 xi[4], wa[4], wb4[4];
            #pragma unroll
            for (int u=0;u<4;u++) xi[u] = *(const float4*)(src + (ig+16*u)*68 + k0);
            #pragma unroll
            for (int c=0;c<4;c++){
                wa[c]  = *(const float4*)(slab + (k0+c)*132 + j0);
                wb4[c] = *(const float4*)(slab + (k0+c)*132 + 64 + j0);
            }
            #pragma unroll
            for (int u=0;u<4;u++){
                #pragma unroll
                for (int c=0;c<4;c++){
                    const float xc = F4E(xi[u], c);
                    const float4 a4 = wa[c], b4 = wb4[c];
                    accA[u][0] += xc*a4.x; accA[u][1] += xc*a4.y;
                    accA[u][2] += xc*a4.z; accA[u][3] += xc*a4.w;
                    accB[u][0] += xc*b4.x; accB[u][1] += xc*b4.y;
                    accB[u][2] += xc*b4.z; accB[u][3] += xc*b4.w;
                }
            }
        }
        __syncthreads();
    }
    #pragma unroll
    for (int u=0;u<4;u++){
        *(float4*)(sH1 + (ig+16*u)*132 + j0) =
            make_float4(fmaxf(accA[u][0],0.f),fmaxf(accA[u][1],0.f),
                        fmaxf(accA[u][2],0.f),fmaxf(accA[u][3],0.f));
        *(float4*)(sH1 + (ig+16*u)*132 + 64 + j0) =
            make_float4(fmaxf(accB[u][0],0.f),fmaxf(accB[u][1],0.f),
                        fmaxf(accB[u][2],0.f),fmaxf(accB[u][3],0.f));
    }
    __syncthreads();
    // G4: O2 = relu(H1 @ w12_2 + b12_2), 64x64, k=128
    float acc2[4][4];
    #pragma unroll
    for (int u=0;u<4;u++)
        #pragma unroll
        for (int v=0;v<4;v++) acc2[u][v] = b12_2[j0+v];
    for (int half=0; half<2; half++){
        #pragma unroll
        for (int u=0;u<4;u++){
            int id = t + 256*u; int r = id>>4, c4 = (id&15)*4;
            *(float4*)(slab + r*68 + c4) = *(const float4*)(w12_2 + (size_t)(half*64+r)*NH2 + c4);
        }
        __syncthreads();
        #pragma unroll
        for (int ch=0; ch<16; ch++){
            const int k0 = ch*4;
            float4 xi[4], wr[4];
            #pragma unroll
            for (int u=0;u<4;u++) xi[u] = *(const float4*)(sH1 + (ig+16*u)*132 + half*64 + k0);
            #pragma unroll
            for (int c=0;c<4;c++) wr[c] = *(const float4*)(slab + (k0+c)*68 + j0);
            #pragma unroll
            for (int u=0;u<4;u++){
                #pragma unroll
                for (int c=0;c<4;c++){
                    const float xc = F4E(xi[u], c);
                    const float4 w4 = wr[c];
                    acc2[u][0] += xc*w4.x; acc2[u][1] += xc*w4.y;
                    acc2[u][2] += xc*w4.z; acc2[u][3] += xc*w4.w;
                }
            }
        }
        __syncthreads();
    }
    {
        float s0=0.f,s1=0.f,s2=0.f,s3=0.f;
        #pragma unroll
        for (int u=0;u<4;u++){
            s0 += fmaxf(acc2[u][0],0.f); s1 += fmaxf(acc2[u][1],0.f);
            s2 += fmaxf(acc2[u][2],0.f); s3 += fmaxf(acc2[u][3],0.f);
        }
        *(float4*)(msum + ig*68 + j0) = make_float4(s0,s1,s2,s3);
    }
    __syncthreads();
    if (t < 64){
        float ss = 0.f;
        #pragma unroll
        for (int g2=0; g2<16; g2++) ss += msum[g2*68 + t];
        mean_part[((size_t)(b*4+tile))*64 + t] = ss;
    }
}

// =================== K2a: gram partials ===================
__global__ __launch_bounds__(256) void k2a_build(
    const float* __restrict__ fx, const float* __restrict__ fy,
    const float* __restrict__ x, const float* __restrict__ y,
    float* __restrict__ gram)
{
    const int blk = blockIdx.x;
    const int kh = blk & 1, side = (blk>>1)&1, b = blk>>2;
    const float* feat = side ? fy : fx;
    const float* targ = side ? x : y;
    float* g = gram + (size_t)blk*GSTRIDE;
    const int t = threadIdx.x;
    const int ig2 = t & 15, jg2 = t >> 4;
    const int i0 = ig2*4, j0 = jg2*4;
    __shared__ float Zt[64*68], Tt[64*68];
    __shared__ float red[4];

    float accA[4][4], accR[4][4];
    #pragma unroll
    for (int u=0;u<4;u++)
        #pragma unroll
        for (int v=0;v<4;v++){ accA[u][v]=0.f; accR[u][v]=0.f; }
    float szp=0.f, stp=0.f, tsqp=0.f;
    const int cc_ = t & 63, rq = t >> 6;

    for (int sub=0; sub<2; sub++){
        if (sub) __syncthreads();
        const int r0g = b*NS + kh*128 + sub*64;
        #pragma unroll
        for (int u=0;u<4;u++){
            int id = t + 256*u; int r = id>>4, c4 = (id&15)*4;
            *(float4*)(Zt + r*68 + c4) = *(const float4*)(feat + ((size_t)(r0g+r))*NH2 + c4);
            *(float4*)(Tt + r*68 + c4) = *(const float4*)(targ + ((size_t)(r0g+r))*ND + c4);
        }
        __syncthreads();
        #pragma unroll
        for (int ch=0; ch<16; ch++){
            const int r0 = ch*4;
            float4 zi[4], zj[4], tj[4];
            #pragma unroll
            for (int c=0;c<4;c++){
                zi[c] = *(const float4*)(Zt + (r0+c)*68 + i0);
                zj[c] = *(const float4*)(Zt + (r0+c)*68 + j0);
                tj[c] = *(const float4*)(Tt + (r0+c)*68 + j0);
            }
            #pragma unroll
            for (int c=0;c<4;c++){
                #pragma unroll
                for (int u=0;u<4;u++){
                    const float zv = F4E(zi[c], u);
                    const float4 a4 = zj[c], r4 = tj[c];
                    accA[u][0] += zv*a4.x; accA[u][1] += zv*a4.y;
                    accA[u][2] += zv*a4.z; accA[u][3] += zv*a4.w;
                    accR[u][0] += zv*r4.x; accR[u][1] += zv*r4.y;
                    accR[u][2] += zv*r4.z; accR[u][3] += zv*r4.w;
                }
            }
        }
        #pragma unroll
        for (int rr=0; rr<16; rr++){
            int r = rq*16 + rr;
            szp += Zt[r*68 + cc_];
            float tv = Tt[r*68 + cc_];
            stp += tv; tsqp += tv*tv;
        }
    }
    #pragma unroll
    for (int u=0;u<4;u++){
        *(float4*)(g + (i0+u)*64 + j0) = make_float4(accA[u][0],accA[u][1],accA[u][2],accA[u][3]);
        *(float4*)(g + 4096 + (i0+u)*64 + j0) = make_float4(accR[u][0],accR[u][1],accR[u][2],accR[u][3]);
    }
    __syncthreads();
    Zt[rq*68 + cc_] = szp;
    Tt[rq*68 + cc_] = stp;
    float tq = tsqp;
    #pragma unroll
    for (int off=32; off; off>>=1) tq += __shfl_down(tq, off);
    if ((t&63)==0) red[t>>6] = tq;
    __syncthreads();
    if (t < 64){
        g[8192+t] = Zt[t] + Zt[68+t] + Zt[2*68+t] + Zt[3*68+t];
        g[8256+t] = Tt[t] + Tt[68+t] + Tt[2*68+t] + Tt[3*68+t];
    }
    if (t==0) g[8320] = red[0]+red[1]+red[2]+red[3];
}

// =================== K2b: centered 64x64 SPD solve ===================
__global__ __launch_bounds__(256) void k2b_solve(
    const float* __restrict__ gram, float* __restrict__ wbuf)
{
    const int bs = blockIdx.x;
    const float* g0 = gram + (size_t)(bs*2+0)*GSTRIDE;
    const float* g1 = gram + (size_t)(bs*2+1)*GSTRIDE;
    float* wb = wbuf + (size_t)bs*WSTRIDE;
    const int t = threadIdx.x;
    __shared__ float A[64*68];
    __shared__ float R[64*68];
    __shared__ float szs[64], sts[64], fcol[64];
    __shared__ float sc[8];

    #pragma unroll
    for (int u=0;u<16;u++){
        int id = t + 256*u; int r = id>>6, c = id&63;
        A[r*68+c] = g0[id] + g1[id];
        R[r*68+c] = g0[4096+id] + g1[4096+id];
    }
    if (t<64){ szs[t] = g0[8192+t]+g1[8192+t]; sts[t] = g0[8256+t]+g1[8256+t]; }
    if (t==0) sc[1] = g0[8320]+g1[8320];
    __syncthreads();
    if (t<64){
        float dg = A[t*68+t];
        #pragma unroll
        for (int off=32; off; off>>=1) dg += __shfl_down(dg, off);
        if (t==0){ sc[0] = 1.0f/sqrtf(dg); sc[1] = 1.0f/sqrtf(sc[1]); }
    }
    __syncthreads();
    const float zinv = sc[0], tinv = sc[1];
    const float z2 = zinv*zinv, zt = zinv*tinv, inv256 = 1.0f/256.0f;
    {
        const int i = t>>2, qd = t&3;
        const float szi = szs[i];
        #pragma unroll
        for (int q=0;q<4;q++){
            const int j = qd*16 + q*4;
            float4 v = *(float4*)(A + i*68 + j);
            float4 sj = *(const float4*)(szs + j);
            v.x = z2*(v.x - szi*sj.x*inv256);
            v.y = z2*(v.y - szi*sj.y*inv256);
            v.z = z2*(v.z - szi*sj.z*inv256);
            v.w = z2*(v.w - szi*sj.w*inv256);
            if (i == j)   v.x += 1.f;
            else if (i == j+1) v.y += 1.f;
            else if (i == j+2) v.z += 1.f;
            else if (i == j+3) v.w += 1.f;
            *(float4*)(A + i*68 + j) = v;
            float4 rv = *(float4*)(R + i*68 + j);
            float4 t4 = *(const float4*)(sts + j);
            rv.x = zt*(rv.x - szi*t4.x*inv256);
            rv.y = zt*(rv.y - szi*t4.y*inv256);
            rv.z = zt*(rv.z - szi*t4.z*inv256);
            rv.w = zt*(rv.w - szi*t4.w*inv256);
            *(float4*)(R + i*68 + j) = rv;
        }
    }
    // backward Gauss-Jordan on 64x64
    for (int k=63; k>=0; k--){
        __syncthreads();
        if (t < 64) fcol[t] = A[t*68 + k];
        if (t == 64) sc[3] = 1.0f / A[k*68 + k];
        __syncthreads();
        const int i = t>>2, qd = t&3;
        const int ri = i + (i >= k);
        if (ri < 64){
            const float fi = fcol[ri] * sc[3];
            const int nq = k >> 2;
            for (int q = qd; q < nq; q += 4){
                float4 pk = *(const float4*)(A + k*68 + 4*q);
                float4 pi = *(float4*)(A + ri*68 + 4*q);
                pi.x -= fi*pk.x; pi.y -= fi*pk.y; pi.z -= fi*pk.z; pi.w -= fi*pk.w;
                *(float4*)(A + ri*68 + 4*q) = pi;
            }
            {
                const int jt = 4*nq + qd;
                if (jt < k) A[ri*68+jt] -= fi * A[k*68+jt];
            }
            #pragma unroll
            for (int m=0;m<4;m++){
                const int jc = (qd + 4*m)*4;
                float4 rk = *(const float4*)(R + k*68 + jc);
                float4 rr = *(float4*)(R + ri*68 + jc);
                rr.x -= fi*rk.x; rr.y -= fi*rk.y; rr.z -= fi*rk.z; rr.w -= fi*rk.w;
                *(float4*)(R + ri*68 + jc) = rr;
            }
        }
    }
    __syncthreads();
    {
        const int i = t>>2, qd = t&3;
        const float dinv = 1.0f / A[i*68 + i];
        #pragma unroll
        for (int m=0;m<4;m++){
            const int jc = (qd + 4*m)*4;
            float4 r4 = *(float4*)(R + i*68 + jc);
            r4.x*=dinv; r4.y*=dinv; r4.z*=dinv; r4.w*=dinv;
            *(float4*)(R + i*68 + jc) = r4;
            *(float4*)(wb + i*64 + jc) = r4;
        }
    }
    __syncthreads();
    if (t < 64){
        float s = 0.f;
        for (int i2=0; i2<64; i2++) s += szs[i2]*R[i2*68 + t];
        wb[4096+t] = (tinv*sts[t] - zinv*s) * inv256;
    }
    if (t==0){ wb[4160] = zinv; wb[4161] = tinv; }
}

// =================== K2c: residuals ===================
__global__ __launch_bounds__(256) void k2c_resid(
    const float* __restrict__ fx, const float* __restrict__ fy,
    const float* __restrict__ x, const float* __restrict__ y,
    const float* __restrict__ wbuf,
    float* __restrict__ resx, float* __restrict__ resy,
    float* __restrict__ resn, float* __restrict__ rawn,
    float* __restrict__ loss_part)
{
    const int blk = blockIdx.x;
    const int h = blk & 1, side = (blk>>1)&1, b = blk>>2;
    const float* feat = side ? fy : fx;
    const float* targ = side ? x : y;
    float* res = side ? resy : resx;
    const float* wb = wbuf + (size_t)(b*2+side)*WSTRIDE;
    const int t = threadIdx.x;
    const int ig = t>>4, jg = t&15, d0 = jg*4;
    const int row0 = b*NS + h*128;
    __shared__ float sZ[128*68];
    __shared__ float sW[64*68];
    __shared__ float c0s[64];
    __shared__ float rnp[128*17];
    __shared__ float rqp[128*17];
    __shared__ float red[4];

    #pragma unroll
    for (int u=0;u<8;u++){
        int id = t + 256*u; int r = id>>4, c4 = (id&15)*4;
        *(float4*)(sZ + r*68 + c4) = *(const float4*)(feat + ((size_t)(row0+r))*NH2 + c4);
    }
    #pragma unroll
    for (int u=0;u<4;u++){
        int id = t + 256*u; int r = id>>4, c4 = (id&15)*4;
        *(float4*)(sW + r*68 + c4) = *(const float4*)(wb + (size_t)r*64 + c4);
    }
    if (t<64) c0s[t] = wb[4096+t];
    const float zinv = wb[4160], tinv = wb[4161];
    __syncthreads();

    float acc[8][4];
    #pragma unroll
    for (int u=0;u<8;u++){ acc[u][0]=0.f; acc[u][1]=0.f; acc[u][2]=0.f; acc[u][3]=0.f; }
    #pragma unroll
    for (int ch=0; ch<16; ch++){
        const int k0 = ch*4;
        float4 wr[4];
        #pragma unroll
        for (int c=0;c<4;c++) wr[c] = *(const float4*)(sW + (k0+c)*68 + d0);
        #pragma unroll
        for (int u=0;u<8;u++){
            float4 zv = *(const float4*)(sZ + (ig+16*u)*68 + k0);
            #pragma unroll
            for (int c=0;c<4;c++){
                const float zc = F4E(zv, c);
                const float4 w4 = wr[c];
                acc[u][0] += zc*w4.x; acc[u][1] += zc*w4.y;
                acc[u][2] += zc*w4.z; acc[u][3] += zc*w4.w;
            }
        }
    }
    const float4 c04 = *(const float4*)(c0s + d0);
    #pragma unroll
    for (int u=0;u<8;u++){
        const int r = ig + 16*u;
        const int gr = row0 + r;
        float4 q = *(const float4*)(targ + (size_t)gr*ND + d0);
        float4 rr;
        rr.x = tinv*q.x - zinv*acc[u][0] - c04.x;
        rr.y = tinv*q.y - zinv*acc[u][1] - c04.y;
        rr.z = tinv*q.z - zinv*acc[u][2] - c04.z;
        rr.w = tinv*q.w - zinv*acc[u][3] - c04.w;
        *(float4*)(res + (size_t)gr*ND + d0) = rr;
        rnp[r*17 + jg] = rr.x*rr.x + rr.y*rr.y + rr.z*rr.z + rr.w*rr.w;
        rqp[r*17 + jg] = q.x*q.x + q.y*q.y + q.z*q.z + q.w*q.w;
    }
    __syncthreads();
    float myrn = 0.f;
    if (t < 128){
        float rn=0.f, rq=0.f;
        #pragma unroll
        for (int g2=0; g2<16; g2++){ rn += rnp[t*17+g2]; rq += rqp[t*17+g2]; }
        resn[(size_t)(side*NB+b)*NS + h*128 + t] = rn;
        rawn[(size_t)(side*NB+b)*NS + h*128 + t] = rq;
        myrn = rn;
    }
    float l = myrn;
    #pragma unroll
    for (int off=32; off; off>>=1) l += __shfl_down(l, off);
    if ((t&63)==0) red[t>>6] = l;
    __syncthreads();
    if (t==0) loss_part[blk] = red[0]+red[1]+red[2]+red[3];
}

// =================== K3: symmetric pair-tile Renyi ===================
__global__ __launch_bounds__(128) void k3_renyi(
    const float* __restrict__ resx, const float* __restrict__ resy,
    const float* __restrict__ x, const float* __restrict__ y,
    const float* __restrict__ resn, const float* __restrict__ rawn,
    float* __restrict__ part3)
{
    const int blk = blockIdx.x;
    const int pair = blk % 10;
    const int bs = blk / 10;
    const int side = bs & 1, b = bs >> 1;
    int ti, tj;
    if (pair < 4){ ti = 0; tj = pair; }
    else if (pair < 7){ ti = 1; tj = pair - 3; }
    else if (pair < 9){ ti = 2; tj = pair - 5; }
    else { ti = 3; tj = 3; }
    const float* Am = side ? resy : resx;
    const float* Bm = side ? y : x;
    const float* nA = resn + (size_t)(side*NB+b)*NS;
    const float* nB = rawn + (size_t)((1-side)*NB+b)*NS;
    const int t = threadIdx.x;
    __shared__ float AI[64*68], BI[64*68], AJ[64*68], BJ[64*68];
    __shared__ float nAIs[64], nBIs[64], nAJs[64], nBJs[64];
    __shared__ float red[2][3];

    {
        const int r = t>>1, cb = (t&1)*32;
        const float* ar = Am + ((size_t)(b*NS + ti*64 + r))*ND + cb;
        const float* br = Bm + ((size_t)(b*NS + ti*64 + r))*ND + cb;
        #pragma unroll
        for (int c=0;c<8;c++){
            *(float4*)(AI + r*68 + cb + 4*c) = *(const float4*)(ar + 4*c);
            *(float4*)(BI + r*68 + cb + 4*c) = *(const float4*)(br + 4*c);
        }
        if (ti != tj){
            const float* ar2 = Am + ((size_t)(b*NS + tj*64 + r))*ND + cb;
            const float* br2 = Bm + ((size_t)(b*NS + tj*64 + r))*ND + cb;
            #pragma unroll
            for (int c=0;c<8;c++){
                *(float4*)(AJ + r*68 + cb + 4*c) = *(const float4*)(ar2 + 4*c);
                *(float4*)(BJ + r*68 + cb + 4*c) = *(const float4*)(br2 + 4*c);
            }
        }
    }
    if (t<64){
        nAIs[t]=nA[ti*64+t]; nBIs[t]=nB[ti*64+t];
        nAJs[t]=nA[tj*64+t]; nBJs[t]=nB[tj*64+t];
    }
    __syncthreads();
    const float* AJp = (ti==tj) ? AI : AJ;
    const float* BJp = (ti==tj) ? BI : BJ;
    const int ig8 = t>>4, jg = t&15;
    float da[8][4], db[8][4];
    #pragma unroll
    for (int u=0;u<8;u++)
        #pragma unroll
        for (int v=0;v<4;v++){ da[u][v]=0.f; db[u][v]=0.f; }
    #pragma unroll
    for (int ch=0; ch<16; ch++){
        const int k0 = ch*4;
        float4 aj[4], bj[4];
        #pragma unroll
        for (int v=0;v<4;v++){
            aj[v] = *(const float4*)(AJp + (jg+16*v)*68 + k0);
            bj[v] = *(const float4*)(BJp + (jg+16*v)*68 + k0);
        }
        #pragma unroll
        for (int u=0;u<8;u++){
            float4 av = *(const float4*)(AI + (ig8+8*u)*68 + k0);
            float4 bv = *(const float4*)(BI + (ig8+8*u)*68 + k0);
            #pragma unroll
            for (int v=0;v<4;v++){
                da[u][v] += av.x*aj[v].x + av.y*aj[v].y + av.z*aj[v].z + av.w*aj[v].w;
                db[u][v] += bv.x*bj[v].x + bv.y*bj[v].y + bv.z*bj[v].z + bv.w*bj[v].w;
            }
        }
    }
    const float w = (ti==tj) ? 1.0f : 2.0f;
    float Sa=0.f, Sb=0.f, Sab=0.f;
    #pragma unroll
    for (int u=0;u<8;u++){
        const float na_ = nAIs[ig8+8*u], nb_ = nBIs[ig8+8*u];
        #pragma unroll
        for (int v=0;v<4;v++){
            const float dda = na_ + nAJs[jg+16*v] - 2.f*da[u][v];
            const float ddb = nb_ + nBJs[jg+16*v] - 2.f*db[u][v];
            Sa  += __expf(-2.f*dda);
            Sb  += __expf(-2.f*ddb);
            Sab += __expf(-2.f*(dda+ddb));
        }
    }
    Sa *= w; Sb *= w; Sab *= w;
    #pragma unroll
    for (int off=32; off; off>>=1){
        Sa += __shfl_down(Sa,off); Sb += __shfl_down(Sb,off); Sab += __shfl_down(Sab,off);
    }
    if ((t&63)==0){ red[t>>6][0]=Sa; red[t>>6][1]=Sb; red[t>>6][2]=Sab; }
    __syncthreads();
    if (t==0){
        float* o = part3 + (size_t)(bs*10 + pair)*3;
        o[0] = red[0][0]+red[1][0];
        o[1] = red[0][1]+red[1][1];
        o[2] = red[0][2]+red[1][2];
    }
}

// =================== K4 ===================
__global__ __launch_bounds__(64) void k4_final(
    const float* __restrict__ mean_part, const float* __restrict__ part3,
    const float* __restrict__ loss_part,
    const float* __restrict__ wc1, const float* __restrict__ bc1,
    const float* __restrict__ bn_gamma, const float* __restrict__ bn_beta,
    const float* __restrict__ w2, const float* __restrict__ b2,
    const float* __restrict__ wc2, const float* __restrict__ bc2,
    float* __restrict__ dout)
{
    const int t = threadIdx.x;
    __shared__ float ic[64][5];
    __shared__ float mu[5], iv[5];

    dout[192+t] = loss_part[4*t+0] + loss_part[4*t+1];
    dout[256+t] = loss_part[4*t+2] + loss_part[4*t+3];

    float o0 = bc1[0], o1 = bc1[1], o2 = bc1[2];
    for (int c=0;c<64;c++){
        float mv = mean_part[(t*4+0)*64+c] + mean_part[(t*4+1)*64+c]
                 + mean_part[(t*4+2)*64+c] + mean_part[(t*4+3)*64+c];
        mv *= (1.0f/256.0f);
        o0 += mv*wc1[c*3+0]; o1 += mv*wc1[c*3+1]; o2 += mv*wc1[c*3+2];
    }
    dout[t*3+0]=o0; dout[t*3+1]=o1; dout[t*3+2]=o2;
    {
        float m = fmaxf(o0,fmaxf(o1,o2));
        float e0=__expf(o0-m), e1=__expf(o1-m), e2=__expf(o2-m);
        float inv = 1.f/(e0+e1+e2);
        dout[640+t*3+0]=e0*inv; dout[640+t*3+1]=e1*inv; dout[640+t*3+2]=e2*inv;
    }
    float exy[2];
    #pragma unroll
    for (int side=0; side<2; side++){
        const float* pp = part3 + (size_t)((t*2+side)*10)*3;
        float Sa=0.f, Sb=0.f, Sab=0.f;
        #pragma unroll
        for (int p=0;p<10;p++){ Sa += pp[3*p]; Sb += pp[3*p+1]; Sab += pp[3*p+2]; }
        float Hx  = 16.f - log2f(Sa);
        float Hy  = 16.f - log2f(Sb);
        float Hxy = 16.f - log2f(Sab);
        float mi = (Hx + Hy - Hxy) / fmaxf(Hx, Hy);
        dout[(side?384:320)+t] = mi;
        exy[side] = mi;
    }
    ic[t][0]=o0; ic[t][1]=o1; ic[t][2]=o2; ic[t][3]=exy[0]; ic[t][4]=exy[1];
    __syncthreads();
    if (t<5){
        float m=0.f;
        for (int bb=0;bb<64;bb++) m += ic[bb][t];
        m *= (1.f/64.f);
        float v=0.f;
        for (int bb=0;bb<64;bb++){ float d=ic[bb][t]-m; v+=d*d; }
        v *= (1.f/64.f);
        mu[t]=m; iv[t]=1.f/sqrtf(v+1e-5f);
    }
    __syncthreads();
    float vn[5];
    #pragma unroll
    for (int c=0;c<5;c++) vn[c] = (ic[t][c]-mu[c])*iv[c]*bn_gamma[c]+bn_beta[c];
    float q0=bc2[0], q1=bc2[1], q2=bc2[2];
    for (int j=0;j<64;j++){
        float hh = b2[j];
        #pragma unroll
        for (int c=0;c<5;c++) hh += vn[c]*w2[c*64+j];
        hh = fmaxf(hh,0.f);
        q0 += hh*wc2[j*3+0]; q1 += hh*wc2[j*3+1]; q2 += hh*wc2[j*3+2];
    }
    dout[448+t*3+0]=q0; dout[448+t*3+1]=q1; dout[448+t*3+2]=q2;
    float m = fmaxf(q0,fmaxf(q1,q2));
    float e0=__expf(q0-m), e1=__expf(q1-m), e2=__expf(q2-m);
    float inv=1.f/(e0+e1+e2);
    dout[832+t*3+0]=e0*inv; dout[832+t*3+1]=e1*inv; dout[832+t*3+2]=e2*inv;
}

extern "C" void kernel_launch(void* const* d_in, const int* in_sizes, int n_in,
                              void* d_out, int out_size, void* d_ws, size_t ws_size,
                              hipStream_t stream)
{
    const float* x     = (const float*)d_in[0];
    const float* y     = (const float*)d_in[1];
    const float* w11_1 = (const float*)d_in[2];
    const float* b11_1 = (const float*)d_in[3];
    const float* w11_2 = (const float*)d_in[4];
    const float* b11_2 = (const float*)d_in[5];
    const float* w12_1 = (const float*)d_in[6];
    const float* b12_1 = (const float*)d_in[7];
    const float* w12_2 = (const float*)d_in[8];
    const float* b12_2 = (const float*)d_in[9];
    const float* wc1   = (const float*)d_in[10];
    const float* bc1   = (const float*)d_in[11];
    const float* bn_g  = (const float*)d_in[12];
    const float* bn_b  = (const float*)d_in[13];
    const float* w2    = (const float*)d_in[14];
    const float* b2    = (const float*)d_in[15];
    const float* wc2   = (const float*)d_in[16];
    const float* bc2   = (const float*)d_in[17];

    float* ws   = (float*)d_ws;
    float* dout = (float*)d_out;
    float* out_x = ws;
    float* out_y = ws + 1048576;
    float* resx  = ws + 2097152;
    float* resy  = ws + 3145728;
    float* resn  = ws + 4194304;                 // 32768
    float* rawn  = resn + 32768;                 // 32768
    float* mean_part = rawn + 32768;             // 16384
    float* part3 = mean_part + 16384;            // 3840
    float* loss_part = part3 + 3840;             // 256
    float* gram  = ws + 4280320;                 // 256*8448 = 2162688
    float* wbuf  = gram + 2162688;               // 128*4224 = 540672

    hipLaunchKernelGGL(k1_fused, dim3(NB*4), dim3(256), 0, stream,
        x,y,w11_1,b11_1,w11_2,b11_2,w12_1,b12_1,w12_2,b12_2,
        out_x,out_y,mean_part);
    hipLaunchKernelGGL(k2a_build, dim3(NB*4), dim3(256), 0, stream,
        out_x,out_y,x,y,gram);
    hipLaunchKernelGGL(k2b_solve, dim3(2*NB), dim3(256), 0, stream,
        gram,wbuf);
    hipLaunchKernelGGL(k2c_resid, dim3(NB*4), dim3(256), 0, stream,
        out_x,out_y,x,y,wbuf,resx,resy,resn,rawn,loss_part);
    hipLaunchKernelGGL(k3_renyi, dim3(NB*2*10), dim3(128), 0, stream,
        resx,resy,x,y,resn,rawn,part3);
    hipLaunchKernelGGL(k4_final, dim3(1), dim3(64), 0, stream,
        mean_part,part3,loss_part,wc1,bc1,bn_g,bn_b,w2,b2,wc2,bc2,dout);
}

// Round 5
// 139.494 us; speedup vs baseline: 1.6560x; 1.3243x over previous
//
#include <hip/hip_runtime.h>
#include <math.h>

#define NB 64
#define NS 256
#define ND 64
#define NH2 64
#define NH 128
#define GSTRIDE 8448
#define WSTRIDE 4224

// d_out layout (floats):
// 0: out_c[64*3]; 192: rx[64]; 256: ry[64]; 320: ex[64]; 384: ey[64];
// 448: out_c_f[64*3]; 640: prob1[64*3]; 832: prob2[64*3]

#define F4E(v_, e_) ((e_)==0?(v_).x:((e_)==1?(v_).y:((e_)==2?(v_).z:(v_).w)))

typedef __attribute__((ext_vector_type(8))) short bf16x8;
typedef __attribute__((ext_vector_type(4))) float f32x4;

__device__ __forceinline__ unsigned short f2bf(float f){
    union { float f; unsigned int u; } v; v.f = f;
    unsigned int r = v.u + 0x7fffu + ((v.u >> 16) & 1u);
    return (unsigned short)(r >> 16);
}

__device__ __forceinline__ void gemm64_4x4(
    const float* __restrict__ Xs, const float* __restrict__ Ws,
    const float* __restrict__ bias, int ig, int j0, float acc[4][4])
{
    #pragma unroll
    for (int u=0;u<4;u++)
        #pragma unroll
        for (int v=0;v<4;v++) acc[u][v] = bias[j0+v];
    #pragma unroll
    for (int ch=0; ch<16; ch++){
        const int k0 = ch*4;
        float4 xi[4], wr[4];
        #pragma unroll
        for (int u=0;u<4;u++) xi[u] = *(const float4*)(Xs + (ig+16*u)*68 + k0);
        #pragma unroll
        for (int c=0;c<4;c++) wr[c] = *(const float4*)(Ws + (k0+c)*68 + j0);
        #pragma unroll
        for (int u=0;u<4;u++){
            #pragma unroll
            for (int c=0;c<4;c++){
                const float xc = F4E(xi[u], c);
                const float4 w4 = wr[c];
                acc[u][0] += xc*w4.x; acc[u][1] += xc*w4.y;
                acc[u][2] += xc*w4.z; acc[u][3] += xc*w4.w;
            }
        }
    }
}

// =================== K1 ===================
__global__ __launch_bounds__(256) void k1_fused(
    const float* __restrict__ x, const float* __restrict__ y,
    const float* __restrict__ w11_1, const float* __restrict__ b11_1,
    const float* __restrict__ w11_2, const float* __restrict__ b11_2,
    const float* __restrict__ w12_1, const float* __restrict__ b12_1,
    const float* __restrict__ w12_2, const float* __restrict__ b12_2,
    float* __restrict__ out_x, float* __restrict__ out_y,
    float* __restrict__ mean_part)
{
    const int b = blockIdx.x >> 2, tile = blockIdx.x & 3;
    const int t = threadIdx.x;
    const int row0 = b*NS + tile*64;
    const int ig = t >> 4, jg = t & 15, j0 = jg*4;

    __shared__ float smem[6*4352 + 16*68];
    float* sX  = smem;
    float* sW1 = smem + 4352;
    float* sW2 = smem + 2*4352;
    float* sH  = smem + 3*4352;
    float* sOx = smem + 4*4352;
    float* sOy = smem + 5*4352;
    float* msum= smem + 6*4352;
    float* sH1 = smem;             // 64*132=8448 <= 8704 (sX+sW1), dead by then
    float* slab= smem + 2*4352;    // 8448 <= 8704 (sW2+sH), dead by then

    #pragma unroll
    for (int u=0;u<4;u++){
        int id = t + 256*u; int r = id>>4, c4 = (id&15)*4;
        *(float4*)(sW1 + r*68 + c4) = *(const float4*)(w11_1 + (size_t)r*64 + c4);
        *(float4*)(sW2 + r*68 + c4) = *(const float4*)(w11_2 + (size_t)r*64 + c4);
        *(float4*)(sX  + r*68 + c4) = *(const float4*)(x + ((size_t)(row0+r))*ND + c4);
    }
    __syncthreads();
    float acc[4][4];
    // G1 (x): H = relu(X W1 + b1)
    gemm64_4x4(sX, sW1, b11_1, ig, j0, acc);
    #pragma unroll
    for (int u=0;u<4;u++)
        *(float4*)(sH + (ig+16*u)*68 + j0) =
            make_float4(fmaxf(acc[u][0],0.f),fmaxf(acc[u][1],0.f),
                        fmaxf(acc[u][2],0.f),fmaxf(acc[u][3],0.f));
    __syncthreads();
    // stage X(y) concurrently with G2(x)
    #pragma unroll
    for (int u=0;u<4;u++){
        int id = t + 256*u; int r = id>>4, c4 = (id&15)*4;
        *(float4*)(sX + r*68 + c4) = *(const float4*)(y + ((size_t)(row0+r))*ND + c4);
    }
    gemm64_4x4(sH, sW2, b11_2, ig, j0, acc);
    #pragma unroll
    for (int u=0;u<4;u++){
        float4 v = make_float4(acc[u][0],acc[u][1],acc[u][2],acc[u][3]);
        *(float4*)(sOx + (ig+16*u)*68 + j0) = v;
        *(float4*)(out_x + ((size_t)(row0+ig+16*u))*NH2 + j0) = v;
    }
    __syncthreads();
    // G1 (y)
    gemm64_4x4(sX, sW1, b11_1, ig, j0, acc);
    #pragma unroll
    for (int u=0;u<4;u++)
        *(float4*)(sH + (ig+16*u)*68 + j0) =
            make_float4(fmaxf(acc[u][0],0.f),fmaxf(acc[u][1],0.f),
                        fmaxf(acc[u][2],0.f),fmaxf(acc[u][3],0.f));
    __syncthreads();
    gemm64_4x4(sH, sW2, b11_2, ig, j0, acc);
    #pragma unroll
    for (int u=0;u<4;u++){
        float4 v = make_float4(acc[u][0],acc[u][1],acc[u][2],acc[u][3]);
        *(float4*)(sOy + (ig+16*u)*68 + j0) = v;
        *(float4*)(out_y + ((size_t)(row0+ig+16*u))*NH2 + j0) = v;
    }
    __syncthreads();
    // G3: H1 = relu([Ox|Oy] @ w12_1 + b12_1), 64x128, k=128 in two halves
    float accA[4][4], accB[4][4];
    #pragma unroll
    for (int u=0;u<4;u++)
        #pragma unroll
        for (int v=0;v<4;v++){ accA[u][v] = b12_1[j0+v]; accB[u][v] = b12_1[64+j0+v]; }
    for (int half=0; half<2; half++){
        #pragma unroll
        for (int u=0;u<8;u++){
            int id = t + 256*u; int r = id>>5, c4 = (id&31)*4;
            *(float4*)(slab + r*132 + c4) = *(const float4*)(w12_1 + (size_t)(half*64+r)*NH + c4);
        }
        __syncthreads();
        const float* src = half ? sOy : sOx;
        #pragma unroll
        for (int ch=0; ch<16; ch++){
            const int k0 = ch*4;
            float4 xi[4], wa[4], wb4[4];
            #pragma unroll
            for (int u=0;u<4;u++) xi[u] = *(const float4*)(src + (ig+16*u)*68 + k0);
            #pragma unroll
            for (int c=0;c<4;c++){
                wa[c]  = *(const float4*)(slab + (k0+c)*132 + j0);
                wb4[c] = *(const float4*)(slab + (k0+c)*132 + 64 + j0);
            }
            #pragma unroll
            for (int u=0;u<4;u++){
                #pragma unroll
                for (int c=0;c<4;c++){
                    const float xc = F4E(xi[u], c);
                    const float4 a4 = wa[c], b4 = wb4[c];
                    accA[u][0] += xc*a4.x; accA[u][1] += xc*a4.y;
                    accA[u][2] += xc*a4.z; accA[u][3] += xc*a4.w;
                    accB[u][0] += xc*b4.x; accB[u][1] += xc*b4.y;
                    accB[u][2] += xc*b4.z; accB[u][3] += xc*b4.w;
                }
            }
        }
        __syncthreads();
    }
    #pragma unroll
    for (int u=0;u<4;u++){
        *(float4*)(sH1 + (ig+16*u)*132 + j0) =
            make_float4(fmaxf(accA[u][0],0.f),fmaxf(accA[u][1],0.f),
                        fmaxf(accA[u][2],0.f),fmaxf(accA[u][3],0.f));
        *(float4*)(sH1 + (ig+16*u)*132 + 64 + j0) =
            make_float4(fmaxf(accB[u][0],0.f),fmaxf(accB[u][1],0.f),
                        fmaxf(accB[u][2],0.f),fmaxf(accB[u][3],0.f));
    }
    __syncthreads();
    // G4: O2 = relu(H1 @ w12_2 + b12_2), 64x64, k=128
    float acc2[4][4];
    #pragma unroll
    for (int u=0;u<4;u++)
        #pragma unroll
        for (int v=0;v<4;v++) acc2[u][v] = b12_2[j0+v];
    for (int half=0; half<2; half++){
        #pragma unroll
        for (int u=0;u<4;u++){
            int id = t + 256*u; int r = id>>4, c4 = (id&15)*4;
            *(float4*)(slab + r*68 + c4) = *(const float4*)(w12_2 + (size_t)(half*64+r)*NH2 + c4);
        }
        __syncthreads();
        #pragma unroll
        for (int ch=0; ch<16; ch++){
            const int k0 = ch*4;
            float4 xi[4], wr[4];
            #pragma unroll
            for (int u=0;u<4;u++) xi[u] = *(const float4*)(sH1 + (ig+16*u)*132 + half*64 + k0);
            #pragma unroll
            for (int c=0;c<4;c++) wr[c] = *(const float4*)(slab + (k0+c)*68 + j0);
            #pragma unroll
            for (int u=0;u<4;u++){
                #pragma unroll
                for (int c=0;c<4;c++){
                    const float xc = F4E(xi[u], c);
                    const float4 w4 = wr[c];
                    acc2[u][0] += xc*w4.x; acc2[u][1] += xc*w4.y;
                    acc2[u][2] += xc*w4.z; acc2[u][3] += xc*w4.w;
                }
            }
        }
        __syncthreads();
    }
    {
        float s0=0.f,s1=0.f,s2=0.f,s3=0.f;
        #pragma unroll
        for (int u=0;u<4;u++){
            s0 += fmaxf(acc2[u][0],0.f); s1 += fmaxf(acc2[u][1],0.f);
            s2 += fmaxf(acc2[u][2],0.f); s3 += fmaxf(acc2[u][3],0.f);
        }
        *(float4*)(msum + ig*68 + j0) = make_float4(s0,s1,s2,s3);
    }
    __syncthreads();
    if (t < 64){
        float ss = 0.f;
        #pragma unroll
        for (int g2=0; g2<16; g2++) ss += msum[g2*68 + t];
        mean_part[((size_t)(b*4+tile))*64 + t] = ss;
    }
}

// =================== K2a: gram partials ===================
__global__ __launch_bounds__(256) void k2a_build(
    const float* __restrict__ fx, const float* __restrict__ fy,
    const float* __restrict__ x, const float* __restrict__ y,
    float* __restrict__ gram)
{
    const int blk = blockIdx.x;
    const int kh = blk & 1, side = (blk>>1)&1, b = blk>>2;
    const float* feat = side ? fy : fx;
    const float* targ = side ? x : y;
    float* g = gram + (size_t)blk*GSTRIDE;
    const int t = threadIdx.x;
    const int ig2 = t & 15, jg2 = t >> 4;
    const int i0 = ig2*4, j0 = jg2*4;
    __shared__ float Zt[64*68], Tt[64*68];
    __shared__ float red[4];

    float accA[4][4], accR[4][4];
    #pragma unroll
    for (int u=0;u<4;u++)
        #pragma unroll
        for (int v=0;v<4;v++){ accA[u][v]=0.f; accR[u][v]=0.f; }
    float szp=0.f, stp=0.f, tsqp=0.f;
    const int cc_ = t & 63, rq = t >> 6;

    for (int sub=0; sub<2; sub++){
        if (sub) __syncthreads();
        const int r0g = b*NS + kh*128 + sub*64;
        #pragma unroll
        for (int u=0;u<4;u++){
            int id = t + 256*u; int r = id>>4, c4 = (id&15)*4;
            *(float4*)(Zt + r*68 + c4) = *(const float4*)(feat + ((size_t)(r0g+r))*NH2 + c4);
            *(float4*)(Tt + r*68 + c4) = *(const float4*)(targ + ((size_t)(r0g+r))*ND + c4);
        }
        __syncthreads();
        #pragma unroll
        for (int ch=0; ch<16; ch++){
            const int r0 = ch*4;
            float4 zi[4], zj[4], tj[4];
            #pragma unroll
            for (int c=0;c<4;c++){
                zi[c] = *(const float4*)(Zt + (r0+c)*68 + i0);
                zj[c] = *(const float4*)(Zt + (r0+c)*68 + j0);
                tj[c] = *(const float4*)(Tt + (r0+c)*68 + j0);
            }
            #pragma unroll
            for (int c=0;c<4;c++){
                #pragma unroll
                for (int u=0;u<4;u++){
                    const float zv = F4E(zi[c], u);
                    const float4 a4 = zj[c], r4 = tj[c];
                    accA[u][0] += zv*a4.x; accA[u][1] += zv*a4.y;
                    accA[u][2] += zv*a4.z; accA[u][3] += zv*a4.w;
                    accR[u][0] += zv*r4.x; accR[u][1] += zv*r4.y;
                    accR[u][2] += zv*r4.z; accR[u][3] += zv*r4.w;
                }
            }
        }
        #pragma unroll
        for (int rr=0; rr<16; rr++){
            int r = rq*16 + rr;
            szp += Zt[r*68 + cc_];
            float tv = Tt[r*68 + cc_];
            stp += tv; tsqp += tv*tv;
        }
    }
    #pragma unroll
    for (int u=0;u<4;u++){
        *(float4*)(g + (i0+u)*64 + j0) = make_float4(accA[u][0],accA[u][1],accA[u][2],accA[u][3]);
        *(float4*)(g + 4096 + (i0+u)*64 + j0) = make_float4(accR[u][0],accR[u][1],accR[u][2],accR[u][3]);
    }
    __syncthreads();
    Zt[rq*68 + cc_] = szp;
    Tt[rq*68 + cc_] = stp;
    float tq = tsqp;
    #pragma unroll
    for (int off=32; off; off>>=1) tq += __shfl_down(tq, off);
    if ((t&63)==0) red[t>>6] = tq;
    __syncthreads();
    if (t < 64){
        g[8192+t] = Zt[t] + Zt[68+t] + Zt[2*68+t] + Zt[3*68+t];
        g[8256+t] = Tt[t] + Tt[68+t] + Tt[2*68+t] + Tt[3*68+t];
    }
    if (t==0) g[8320] = red[0]+red[1]+red[2]+red[3];
}

// =================== K2b: centered 64x64 SPD solve ===================
__global__ __launch_bounds__(256) void k2b_solve(
    const float* __restrict__ gram, float* __restrict__ wbuf)
{
    const int bs = blockIdx.x;
    const float* g0 = gram + (size_t)(bs*2+0)*GSTRIDE;
    const float* g1 = gram + (size_t)(bs*2+1)*GSTRIDE;
    float* wb = wbuf + (size_t)bs*WSTRIDE;
    const int t = threadIdx.x;
    __shared__ float A[64*68];
    __shared__ float R[64*68];
    __shared__ float szs[64], sts[64], fcol[64];
    __shared__ float sc[8];

    #pragma unroll
    for (int u=0;u<16;u++){
        int id = t + 256*u; int r = id>>6, c = id&63;
        A[r*68+c] = g0[id] + g1[id];
        R[r*68+c] = g0[4096+id] + g1[4096+id];
    }
    if (t<64){ szs[t] = g0[8192+t]+g1[8192+t]; sts[t] = g0[8256+t]+g1[8256+t]; }
    if (t==0) sc[1] = g0[8320]+g1[8320];
    __syncthreads();
    if (t<64){
        float dg = A[t*68+t];
        #pragma unroll
        for (int off=32; off; off>>=1) dg += __shfl_down(dg, off);
        if (t==0){ sc[0] = 1.0f/sqrtf(dg); sc[1] = 1.0f/sqrtf(sc[1]); }
    }
    __syncthreads();
    const float zinv = sc[0], tinv = sc[1];
    const float z2 = zinv*zinv, zt = zinv*tinv, inv256 = 1.0f/256.0f;
    {
        const int i = t>>2, qd = t&3;
        const float szi = szs[i];
        #pragma unroll
        for (int q=0;q<4;q++){
            const int j = qd*16 + q*4;
            float4 v = *(float4*)(A + i*68 + j);
            float4 sj = *(const float4*)(szs + j);
            v.x = z2*(v.x - szi*sj.x*inv256);
            v.y = z2*(v.y - szi*sj.y*inv256);
            v.z = z2*(v.z - szi*sj.z*inv256);
            v.w = z2*(v.w - szi*sj.w*inv256);
            if (i == j)   v.x += 1.f;
            else if (i == j+1) v.y += 1.f;
            else if (i == j+2) v.z += 1.f;
            else if (i == j+3) v.w += 1.f;
            *(float4*)(A + i*68 + j) = v;
            float4 rv = *(float4*)(R + i*68 + j);
            float4 t4 = *(const float4*)(sts + j);
            rv.x = zt*(rv.x - szi*t4.x*inv256);
            rv.y = zt*(rv.y - szi*t4.y*inv256);
            rv.z = zt*(rv.z - szi*t4.z*inv256);
            rv.w = zt*(rv.w - szi*t4.w*inv256);
            *(float4*)(R + i*68 + j) = rv;
        }
    }
    // backward Gauss-Jordan on 64x64
    for (int k=63; k>=0; k--){
        __syncthreads();
        if (t < 64) fcol[t] = A[t*68 + k];
        if (t == 64) sc[3] = 1.0f / A[k*68 + k];
        __syncthreads();
        const int i = t>>2, qd = t&3;
        const int ri = i + (i >= k);
        if (ri < 64){
            const float fi = fcol[ri] * sc[3];
            const int nq = k >> 2;
            for (int q = qd; q < nq; q += 4){
                float4 pk = *(const float4*)(A + k*68 + 4*q);
                float4 pi = *(float4*)(A + ri*68 + 4*q);
                pi.x -= fi*pk.x; pi.y -= fi*pk.y; pi.z -= fi*pk.z; pi.w -= fi*pk.w;
                *(float4*)(A + ri*68 + 4*q) = pi;
            }
            {
                const int jt = 4*nq + qd;
                if (jt < k) A[ri*68+jt] -= fi * A[k*68+jt];
            }
            #pragma unroll
            for (int m=0;m<4;m++){
                const int jc = (qd + 4*m)*4;
                float4 rk = *(const float4*)(R + k*68 + jc);
                float4 rr = *(float4*)(R + ri*68 + jc);
                rr.x -= fi*rk.x; rr.y -= fi*rk.y; rr.z -= fi*rk.z; rr.w -= fi*rk.w;
                *(float4*)(R + ri*68 + jc) = rr;
            }
        }
    }
    __syncthreads();
    {
        const int i = t>>2, qd = t&3;
        const float dinv = 1.0f / A[i*68 + i];
        #pragma unroll
        for (int m=0;m<4;m++){
            const int jc = (qd + 4*m)*4;
            float4 r4 = *(float4*)(R + i*68 + jc);
            r4.x*=dinv; r4.y*=dinv; r4.z*=dinv; r4.w*=dinv;
            *(float4*)(R + i*68 + jc) = r4;
            *(float4*)(wb + i*64 + jc) = r4;
        }
    }
    __syncthreads();
    if (t < 64){
        float s = 0.f;
        for (int i2=0; i2<64; i2++) s += szs[i2]*R[i2*68 + t];
        wb[4096+t] = (tinv*sts[t] - zinv*s) * inv256;
    }
    if (t==0){ wb[4160] = zinv; wb[4161] = tinv; }
}

// =================== K2c: residuals (+ bf16 emission for K3) ===================
__global__ __launch_bounds__(256) void k2c_resid(
    const float* __restrict__ fx, const float* __restrict__ fy,
    const float* __restrict__ x, const float* __restrict__ y,
    const float* __restrict__ wbuf,
    float* __restrict__ resx, float* __restrict__ resy,
    float* __restrict__ resn, float* __restrict__ rawn,
    float* __restrict__ loss_part,
    unsigned short* __restrict__ resbf, unsigned short* __restrict__ tgbf)
{
    const int blk = blockIdx.x;
    const int h = blk & 1, side = (blk>>1)&1, b = blk>>2;
    const float* feat = side ? fy : fx;
    const float* targ = side ? x : y;
    float* res = side ? resy : resx;
    const float* wb = wbuf + (size_t)(b*2+side)*WSTRIDE;
    const int t = threadIdx.x;
    const int ig = t>>4, jg = t&15, d0 = jg*4;
    const int row0 = b*NS + h*128;
    __shared__ float sZ[128*68];
    __shared__ float sW[64*68];
    __shared__ float c0s[64];
    __shared__ float rnp[128*17];
    __shared__ float rqp[128*17];
    __shared__ float red[4];

    #pragma unroll
    for (int u=0;u<8;u++){
        int id = t + 256*u; int r = id>>4, c4 = (id&15)*4;
        *(float4*)(sZ + r*68 + c4) = *(const float4*)(feat + ((size_t)(row0+r))*NH2 + c4);
    }
    #pragma unroll
    for (int u=0;u<4;u++){
        int id = t + 256*u; int r = id>>4, c4 = (id&15)*4;
        *(float4*)(sW + r*68 + c4) = *(const float4*)(wb + (size_t)r*64 + c4);
    }
    if (t<64) c0s[t] = wb[4096+t];
    const float zinv = wb[4160], tinv = wb[4161];
    __syncthreads();

    float acc[8][4];
    #pragma unroll
    for (int u=0;u<8;u++){ acc[u][0]=0.f; acc[u][1]=0.f; acc[u][2]=0.f; acc[u][3]=0.f; }
    #pragma unroll
    for (int ch=0; ch<16; ch++){
        const int k0 = ch*4;
        float4 wr[4];
        #pragma unroll
        for (int c=0;c<4;c++) wr[c] = *(const float4*)(sW + (k0+c)*68 + d0);
        #pragma unroll
        for (int u=0;u<8;u++){
            float4 zv = *(const float4*)(sZ + (ig+16*u)*68 + k0);
            #pragma unroll
            for (int c=0;c<4;c++){
                const float zc = F4E(zv, c);
                const float4 w4 = wr[c];
                acc[u][0] += zc*w4.x; acc[u][1] += zc*w4.y;
                acc[u][2] += zc*w4.z; acc[u][3] += zc*w4.w;
            }
        }
    }
    const float4 c04 = *(const float4*)(c0s + d0);
    #pragma unroll
    for (int u=0;u<8;u++){
        const int r = ig + 16*u;
        const int gr = row0 + r;
        float4 q = *(const float4*)(targ + (size_t)gr*ND + d0);
        float4 rr;
        rr.x = tinv*q.x - zinv*acc[u][0] - c04.x;
        rr.y = tinv*q.y - zinv*acc[u][1] - c04.y;
        rr.z = tinv*q.z - zinv*acc[u][2] - c04.z;
        rr.w = tinv*q.w - zinv*acc[u][3] - c04.w;
        *(float4*)(res + (size_t)gr*ND + d0) = rr;
        *(ushort4*)(resbf + ((size_t)side*NB*NS + gr)*64 + d0) =
            make_ushort4(f2bf(rr.x), f2bf(rr.y), f2bf(rr.z), f2bf(rr.w));
        *(ushort4*)(tgbf + ((size_t)side*NB*NS + gr)*64 + d0) =
            make_ushort4(f2bf(q.x), f2bf(q.y), f2bf(q.z), f2bf(q.w));
        rnp[r*17 + jg] = rr.x*rr.x + rr.y*rr.y + rr.z*rr.z + rr.w*rr.w;
        rqp[r*17 + jg] = q.x*q.x + q.y*q.y + q.z*q.z + q.w*q.w;
    }
    __syncthreads();
    float myrn = 0.f;
    if (t < 128){
        float rn=0.f, rq=0.f;
        #pragma unroll
        for (int g2=0; g2<16; g2++){ rn += rnp[t*17+g2]; rq += rqp[t*17+g2]; }
        resn[(size_t)(side*NB+b)*NS + h*128 + t] = rn;
        rawn[(size_t)(side*NB+b)*NS + h*128 + t] = rq;
        myrn = rn;
    }
    float l = myrn;
    #pragma unroll
    for (int off=32; off; off>>=1) l += __shfl_down(l, off);
    if ((t&63)==0) red[t>>6] = l;
    __syncthreads();
    if (t==0) loss_part[blk] = red[0]+red[1]+red[2]+red[3];
}

// =================== K3: Renyi-2 Grams via bf16 MFMA ===================
// block = ((side*NB + b)*2 + jh); 256 threads = 4 waves; wave w owns i-rows [64w,64w+64)
__global__ __launch_bounds__(256) void k3_renyi(
    const unsigned short* __restrict__ resbf, const unsigned short* __restrict__ tgbf,
    const float* __restrict__ resn, const float* __restrict__ rawn,
    float* __restrict__ part3)
{
    const int blk = blockIdx.x;
    const int jh = blk & 1;
    const int b = (blk >> 1) & (NB-1);
    const int side = (blk >> 1) >> 6;
    const unsigned short* Am = resbf + ((size_t)side*NB*NS + (size_t)b*NS)*64;
    const unsigned short* Bm = tgbf  + ((size_t)(1-side)*NB*NS + (size_t)b*NS)*64;
    const float* nA = resn + (size_t)(side*NB+b)*NS;
    const float* nB = rawn + (size_t)((1-side)*NB+b)*NS;
    const int t = threadIdx.x;
    const int lane = t & 63, wv = t >> 6;

    __shared__ unsigned short Abf[256*72];   // row stride 72 bf16 = 144 B (2-way-free banks)
    __shared__ unsigned short Bbf[256*72];
    __shared__ float nAs[256], nBs[256];
    __shared__ float red[4][3];

    #pragma unroll
    for (int u=0;u<8;u++){
        int id = t + 256*u;                 // 2048 16B-chunks per matrix
        int r = id>>3, c = id&7;
        *(float4*)((char*)Abf + r*144 + c*16) = *(const float4*)(Am + (size_t)r*64 + c*8);
        *(float4*)((char*)Bbf + r*144 + c*16) = *(const float4*)(Bm + (size_t)r*64 + c*8);
    }
    nAs[t] = nA[t];
    nBs[t] = nB[t];
    __syncthreads();

    const int lrow = lane & 15;
    const int lkb  = (lane >> 4) * 16;      // byte offset of this lane's k-slice (8 bf16)
    const char* pA = (const char*)Abf;
    const char* pB = (const char*)Bbf;
    const f32x4 zero4 = {0.f, 0.f, 0.f, 0.f};
    const float CEXP = -2.8853900817779268f;  // -2 * log2(e): exp(-2d) = 2^(CEXP*d)

    float Sa=0.f, Sb=0.f, Sab=0.f;
    #pragma unroll
    for (int it=0; it<4; it++){
        const int i0 = wv*64 + it*16;
        const int arow = i0 + lrow;
        bf16x8 aA0 = *(const bf16x8*)(pA + arow*144 + lkb);
        bf16x8 aA1 = *(const bf16x8*)(pA + arow*144 + lkb + 64);
        bf16x8 aB0 = *(const bf16x8*)(pB + arow*144 + lkb);
        bf16x8 aB1 = *(const bf16x8*)(pB + arow*144 + lkb + 64);
        float nAi[4], nBi[4];
        #pragma unroll
        for (int e=0;e<4;e++){
            int gi = i0 + (lane>>4)*4 + e;
            nAi[e] = nAs[gi]; nBi[e] = nBs[gi];
        }
        #pragma unroll
        for (int jt=0; jt<8; jt++){
            const int j0 = jh*128 + jt*16;
            const int brow = j0 + lrow;
            bf16x8 bA0 = *(const bf16x8*)(pA + brow*144 + lkb);
            bf16x8 bA1 = *(const bf16x8*)(pA + brow*144 + lkb + 64);
            bf16x8 bB0 = *(const bf16x8*)(pB + brow*144 + lkb);
            bf16x8 bB1 = *(const bf16x8*)(pB + brow*144 + lkb + 64);
            f32x4 cA = __builtin_amdgcn_mfma_f32_16x16x32_bf16(aA0, bA0, zero4, 0, 0, 0);
            cA = __builtin_amdgcn_mfma_f32_16x16x32_bf16(aA1, bA1, cA, 0, 0, 0);
            f32x4 cB = __builtin_amdgcn_mfma_f32_16x16x32_bf16(aB0, bB0, zero4, 0, 0, 0);
            cB = __builtin_amdgcn_mfma_f32_16x16x32_bf16(aB1, bB1, cB, 0, 0, 0);
            const int gj = j0 + lrow;       // C/D: col = lane&15
            const float nAj = nAs[gj], nBj = nBs[gj];
            #pragma unroll
            for (int e=0;e<4;e++){
                const int gi = i0 + (lane>>4)*4 + e;   // C/D: row = (lane>>4)*4+e
                const float dda = (gi==gj) ? 0.f : (nAi[e] + nAj - 2.f*cA[e]);
                const float ddb = (gi==gj) ? 0.f : (nBi[e] + nBj - 2.f*cB[e]);
                const float ka2 = exp2f(CEXP*dda);
                const float kb2 = exp2f(CEXP*ddb);
                Sa += ka2; Sb += kb2; Sab += ka2*kb2;
            }
        }
    }
    #pragma unroll
    for (int off=32; off; off>>=1){
        Sa += __shfl_down(Sa,off); Sb += __shfl_down(Sb,off); Sab += __shfl_down(Sab,off);
    }
    if (lane==0){ red[wv][0]=Sa; red[wv][1]=Sb; red[wv][2]=Sab; }
    __syncthreads();
    if (t==0){
        float* o = part3 + (size_t)blk*3;
        o[0] = red[0][0]+red[1][0]+red[2][0]+red[3][0];
        o[1] = red[0][1]+red[1][1]+red[2][1]+red[3][1];
        o[2] = red[0][2]+red[1][2]+red[2][2]+red[3][2];
    }
}

// =================== K4 ===================
__global__ __launch_bounds__(64) void k4_final(
    const float* __restrict__ mean_part, const float* __restrict__ part3,
    const float* __restrict__ loss_part,
    const float* __restrict__ wc1, const float* __restrict__ bc1,
    const float* __restrict__ bn_gamma, const float* __restrict__ bn_beta,
    const float* __restrict__ w2, const float* __restrict__ b2,
    const float* __restrict__ wc2, const float* __restrict__ bc2,
    float* __restrict__ dout)
{
    const int t = threadIdx.x;
    __shared__ float ic[64][5];
    __shared__ float mu[5], iv[5];

    dout[192+t] = loss_part[4*t+0] + loss_part[4*t+1];
    dout[256+t] = loss_part[4*t+2] + loss_part[4*t+3];

    float o0 = bc1[0], o1 = bc1[1], o2 = bc1[2];
    for (int c=0;c<64;c++){
        float mv = mean_part[(t*4+0)*64+c] + mean_part[(t*4+1)*64+c]
                 + mean_part[(t*4+2)*64+c] + mean_part[(t*4+3)*64+c];
        mv *= (1.0f/256.0f);
        o0 += mv*wc1[c*3+0]; o1 += mv*wc1[c*3+1]; o2 += mv*wc1[c*3+2];
    }
    dout[t*3+0]=o0; dout[t*3+1]=o1; dout[t*3+2]=o2;
    {
        float m = fmaxf(o0,fmaxf(o1,o2));
        float e0=__expf(o0-m), e1=__expf(o1-m), e2=__expf(o2-m);
        float inv = 1.f/(e0+e1+e2);
        dout[640+t*3+0]=e0*inv; dout[640+t*3+1]=e1*inv; dout[640+t*3+2]=e2*inv;
    }
    float exy[2];
    #pragma unroll
    for (int side=0; side<2; side++){
        const float* pp = part3 + (size_t)((side*NB + t)*2)*3;
        float Sa = pp[0]+pp[3];
        float Sb = pp[1]+pp[4];
        float Sab= pp[2]+pp[5];
        float Hx  = 16.f - log2f(Sa);
        float Hy  = 16.f - log2f(Sb);
        float Hxy = 16.f - log2f(Sab);
        float mi = (Hx + Hy - Hxy) / fmaxf(Hx, Hy);
        dout[(side?384:320)+t] = mi;
        exy[side] = mi;
    }
    ic[t][0]=o0; ic[t][1]=o1; ic[t][2]=o2; ic[t][3]=exy[0]; ic[t][4]=exy[1];
    __syncthreads();
    if (t<5){
        float m=0.f;
        for (int bb=0;bb<64;bb++) m += ic[bb][t];
        m *= (1.f/64.f);
        float v=0.f;
        for (int bb=0;bb<64;bb++){ float d=ic[bb][t]-m; v+=d*d; }
        v *= (1.f/64.f);
        mu[t]=m; iv[t]=1.f/sqrtf(v+1e-5f);
    }
    __syncthreads();
    float vn[5];
    #pragma unroll
    for (int c=0;c<5;c++) vn[c] = (ic[t][c]-mu[c])*iv[c]*bn_gamma[c]+bn_beta[c];
    float q0=bc2[0], q1=bc2[1], q2=bc2[2];
    for (int j=0;j<64;j++){
        float hh = b2[j];
        #pragma unroll
        for (int c=0;c<5;c++) hh += vn[c]*w2[c*64+j];
        hh = fmaxf(hh,0.f);
        q0 += hh*wc2[j*3+0]; q1 += hh*wc2[j*3+1]; q2 += hh*wc2[j*3+2];
    }
    dout[448+t*3+0]=q0; dout[448+t*3+1]=q1; dout[448+t*3+2]=q2;
    float m = fmaxf(q0,fmaxf(q1,q2));
    float e0=__expf(q0-m), e1=__expf(q1-m), e2=__expf(q2-m);
    float inv=1.f/(e0+e1+e2);
    dout[832+t*3+0]=e0*inv; dout[832+t*3+1]=e1*inv; dout[832+t*3+2]=e2*inv;
}

extern "C" void kernel_launch(void* const* d_in, const int* in_sizes, int n_in,
                              void* d_out, int out_size, void* d_ws, size_t ws_size,
                              hipStream_t stream)
{
    const float* x     = (const float*)d_in[0];
    const float* y     = (const float*)d_in[1];
    const float* w11_1 = (const float*)d_in[2];
    const float* b11_1 = (const float*)d_in[3];
    const float* w11_2 = (const float*)d_in[4];
    const float* b11_2 = (const float*)d_in[5];
    const float* w12_1 = (const float*)d_in[6];
    const float* b12_1 = (const float*)d_in[7];
    const float* w12_2 = (const float*)d_in[8];
    const float* b12_2 = (const float*)d_in[9];
    const float* wc1   = (const float*)d_in[10];
    const float* bc1   = (const float*)d_in[11];
    const float* bn_g  = (const float*)d_in[12];
    const float* bn_b  = (const float*)d_in[13];
    const float* w2    = (const float*)d_in[14];
    const float* b2    = (const float*)d_in[15];
    const float* wc2   = (const float*)d_in[16];
    const float* bc2   = (const float*)d_in[17];

    float* ws   = (float*)d_ws;
    float* dout = (float*)d_out;
    float* out_x = ws;
    float* out_y = ws + 1048576;
    float* resx  = ws + 2097152;
    float* resy  = ws + 3145728;
    float* resn  = ws + 4194304;                 // 32768
    float* rawn  = resn + 32768;                 // 32768
    float* mean_part = rawn + 32768;             // 16384
    float* part3 = mean_part + 16384;            // 768 (pad region 3840)
    float* loss_part = part3 + 3840;             // 256
    float* gram  = ws + 4280320;                 // 256*8448 = 2162688 floats
    float* wbuf  = gram + 2162688;               // 128*4224 = 540672
    // bf16 staging overlays gram (dead after k2b; k2c writes, k3 reads)
    unsigned short* resbf = (unsigned short*)gram;          // 2*64*256*64 ushorts
    unsigned short* tgbf  = resbf + 2097152;                // 2*64*256*64 ushorts

    hipLaunchKernelGGL(k1_fused, dim3(NB*4), dim3(256), 0, stream,
        x,y,w11_1,b11_1,w11_2,b11_2,w12_1,b12_1,w12_2,b12_2,
        out_x,out_y,mean_part);
    hipLaunchKernelGGL(k2a_build, dim3(NB*4), dim3(256), 0, stream,
        out_x,out_y,x,y,gram);
    hipLaunchKernelGGL(k2b_solve, dim3(2*NB), dim3(256), 0, stream,
        gram,wbuf);
    hipLaunchKernelGGL(k2c_resid, dim3(NB*4), dim3(256), 0, stream,
        out_x,out_y,x,y,wbuf,resx,resy,resn,rawn,loss_part,resbf,tgbf);
    hipLaunchKernelGGL(k3_renyi, dim3(NB*2*2), dim3(256), 0, stream,
        resbf,tgbf,resn,rawn,part3);
    hipLaunchKernelGGL(k4_final, dim3(1), dim3(64), 0, stream,
        mean_part,part3,loss_part,wc1,bc1,bn_g,bn_b,w2,b2,wc2,bc2,dout);
}

// Round 6
// 118.783 us; speedup vs baseline: 1.9447x; 1.1744x over previous
//
#include <hip/hip_runtime.h>
#include <math.h>

#define NB 64
#define NS 256
#define ND 64
#define NH2 64
#define NH 128
#define GSTRIDE 8448
#define WSTRIDE 4224

// d_out layout (floats):
// 0: out_c[64*3]; 192: rx[64]; 256: ry[64]; 320: ex[64]; 384: ey[64];
// 448: out_c_f[64*3]; 640: prob1[64*3]; 832: prob2[64*3]

#define F4E(v_, e_) ((e_)==0?(v_).x:((e_)==1?(v_).y:((e_)==2?(v_).z:(v_).w)))

typedef __attribute__((ext_vector_type(8))) short bf16x8;
typedef __attribute__((ext_vector_type(4))) float f32x4;

__device__ __forceinline__ unsigned short f2bf(float f){
    union { float f; unsigned int u; } v; v.f = f;
    unsigned int r = v.u + 0x7fffu + ((v.u >> 16) & 1u);
    return (unsigned short)(r >> 16);
}

__device__ __forceinline__ void gemm64_4x4(
    const float* __restrict__ Xs, const float* __restrict__ Ws,
    const float* __restrict__ bias, int ig, int j0, float acc[4][4])
{
    #pragma unroll
    for (int u=0;u<4;u++)
        #pragma unroll
        for (int v=0;v<4;v++) acc[u][v] = bias[j0+v];
    #pragma unroll
    for (int ch=0; ch<16; ch++){
        const int k0 = ch*4;
        float4 xi[4], wr[4];
        #pragma unroll
        for (int u=0;u<4;u++) xi[u] = *(const float4*)(Xs + (ig+16*u)*68 + k0);
        #pragma unroll
        for (int c=0;c<4;c++) wr[c] = *(const float4*)(Ws + (k0+c)*68 + j0);
        #pragma unroll
        for (int u=0;u<4;u++){
            #pragma unroll
            for (int c=0;c<4;c++){
                const float xc = F4E(xi[u], c);
                const float4 w4 = wr[c];
                acc[u][0] += xc*w4.x; acc[u][1] += xc*w4.y;
                acc[u][2] += xc*w4.z; acc[u][3] += xc*w4.w;
            }
        }
    }
}

// =================== K1 ===================
__global__ __launch_bounds__(256) void k1_fused(
    const float* __restrict__ x, const float* __restrict__ y,
    const float* __restrict__ w11_1, const float* __restrict__ b11_1,
    const float* __restrict__ w11_2, const float* __restrict__ b11_2,
    const float* __restrict__ w12_1, const float* __restrict__ b12_1,
    const float* __restrict__ w12_2, const float* __restrict__ b12_2,
    float* __restrict__ out_x, float* __restrict__ out_y,
    float* __restrict__ mean_part)
{
    const int b = blockIdx.x >> 2, tile = blockIdx.x & 3;
    const int t = threadIdx.x;
    const int row0 = b*NS + tile*64;
    const int ig = t >> 4, jg = t & 15, j0 = jg*4;

    __shared__ float smem[6*4352 + 16*68];
    float* sX  = smem;
    float* sW1 = smem + 4352;
    float* sW2 = smem + 2*4352;
    float* sH  = smem + 3*4352;
    float* sOx = smem + 4*4352;
    float* sOy = smem + 5*4352;
    float* msum= smem + 6*4352;
    float* sH1 = smem;             // 64*132=8448 <= 8704 (sX+sW1), dead by then
    float* slab= smem + 2*4352;    // 8448 <= 8704 (sW2+sH), dead by then

    #pragma unroll
    for (int u=0;u<4;u++){
        int id = t + 256*u; int r = id>>4, c4 = (id&15)*4;
        *(float4*)(sW1 + r*68 + c4) = *(const float4*)(w11_1 + (size_t)r*64 + c4);
        *(float4*)(sW2 + r*68 + c4) = *(const float4*)(w11_2 + (size_t)r*64 + c4);
        *(float4*)(sX  + r*68 + c4) = *(const float4*)(x + ((size_t)(row0+r))*ND + c4);
    }
    __syncthreads();
    float acc[4][4];
    // G1 (x): H = relu(X W1 + b1)
    gemm64_4x4(sX, sW1, b11_1, ig, j0, acc);
    #pragma unroll
    for (int u=0;u<4;u++)
        *(float4*)(sH + (ig+16*u)*68 + j0) =
            make_float4(fmaxf(acc[u][0],0.f),fmaxf(acc[u][1],0.f),
                        fmaxf(acc[u][2],0.f),fmaxf(acc[u][3],0.f));
    __syncthreads();
    // stage X(y) concurrently with G2(x)
    #pragma unroll
    for (int u=0;u<4;u++){
        int id = t + 256*u; int r = id>>4, c4 = (id&15)*4;
        *(float4*)(sX + r*68 + c4) = *(const float4*)(y + ((size_t)(row0+r))*ND + c4);
    }
    gemm64_4x4(sH, sW2, b11_2, ig, j0, acc);
    #pragma unroll
    for (int u=0;u<4;u++){
        float4 v = make_float4(acc[u][0],acc[u][1],acc[u][2],acc[u][3]);
        *(float4*)(sOx + (ig+16*u)*68 + j0) = v;
        *(float4*)(out_x + ((size_t)(row0+ig+16*u))*NH2 + j0) = v;
    }
    __syncthreads();
    // G1 (y)
    gemm64_4x4(sX, sW1, b11_1, ig, j0, acc);
    #pragma unroll
    for (int u=0;u<4;u++)
        *(float4*)(sH + (ig+16*u)*68 + j0) =
            make_float4(fmaxf(acc[u][0],0.f),fmaxf(acc[u][1],0.f),
                        fmaxf(acc[u][2],0.f),fmaxf(acc[u][3],0.f));
    __syncthreads();
    gemm64_4x4(sH, sW2, b11_2, ig, j0, acc);
    #pragma unroll
    for (int u=0;u<4;u++){
        float4 v = make_float4(acc[u][0],acc[u][1],acc[u][2],acc[u][3]);
        *(float4*)(sOy + (ig+16*u)*68 + j0) = v;
        *(float4*)(out_y + ((size_t)(row0+ig+16*u))*NH2 + j0) = v;
    }
    __syncthreads();
    // G3: H1 = relu([Ox|Oy] @ w12_1 + b12_1), 64x128, k=128 in two halves
    float accA[4][4], accB[4][4];
    #pragma unroll
    for (int u=0;u<4;u++)
        #pragma unroll
        for (int v=0;v<4;v++){ accA[u][v] = b12_1[j0+v]; accB[u][v] = b12_1[64+j0+v]; }
    for (int half=0; half<2; half++){
        #pragma unroll
        for (int u=0;u<8;u++){
            int id = t + 256*u; int r = id>>5, c4 = (id&31)*4;
            *(float4*)(slab + r*132 + c4) = *(const float4*)(w12_1 + (size_t)(half*64+r)*NH + c4);
        }
        __syncthreads();
        const float* src = half ? sOy : sOx;
        #pragma unroll
        for (int ch=0; ch<16; ch++){
            const int k0 = ch*4;
            float4 xi[4], wa[4], wb4[4];
            #pragma unroll
            for (int u=0;u<4;u++) xi[u] = *(const float4*)(src + (ig+16*u)*68 + k0);
            #pragma unroll
            for (int c=0;c<4;c++){
                wa[c]  = *(const float4*)(slab + (k0+c)*132 + j0);
                wb4[c] = *(const float4*)(slab + (k0+c)*132 + 64 + j0);
            }
            #pragma unroll
            for (int u=0;u<4;u++){
                #pragma unroll
                for (int c=0;c<4;c++){
                    const float xc = F4E(xi[u], c);
                    const float4 a4 = wa[c], b4 = wb4[c];
                    accA[u][0] += xc*a4.x; accA[u][1] += xc*a4.y;
                    accA[u][2] += xc*a4.z; accA[u][3] += xc*a4.w;
                    accB[u][0] += xc*b4.x; accB[u][1] += xc*b4.y;
                    accB[u][2] += xc*b4.z; accB[u][3] += xc*b4.w;
                }
            }
        }
        __syncthreads();
    }
    #pragma unroll
    for (int u=0;u<4;u++){
        *(float4*)(sH1 + (ig+16*u)*132 + j0) =
            make_float4(fmaxf(accA[u][0],0.f),fmaxf(accA[u][1],0.f),
                        fmaxf(accA[u][2],0.f),fmaxf(accA[u][3],0.f));
        *(float4*)(sH1 + (ig+16*u)*132 + 64 + j0) =
            make_float4(fmaxf(accB[u][0],0.f),fmaxf(accB[u][1],0.f),
                        fmaxf(accB[u][2],0.f),fmaxf(accB[u][3],0.f));
    }
    __syncthreads();
    // G4: O2 = relu(H1 @ w12_2 + b12_2), 64x64, k=128
    float acc2[4][4];
    #pragma unroll
    for (int u=0;u<4;u++)
        #pragma unroll
        for (int v=0;v<4;v++) acc2[u][v] = b12_2[j0+v];
    for (int half=0; half<2; half++){
        #pragma unroll
        for (int u=0;u<4;u++){
            int id = t + 256*u; int r = id>>4, c4 = (id&15)*4;
            *(float4*)(slab + r*68 + c4) = *(const float4*)(w12_2 + (size_t)(half*64+r)*NH2 + c4);
        }
        __syncthreads();
        #pragma unroll
        for (int ch=0; ch<16; ch++){
            const int k0 = ch*4;
            float4 xi[4], wr[4];
            #pragma unroll
            for (int u=0;u<4;u++) xi[u] = *(const float4*)(sH1 + (ig+16*u)*132 + half*64 + k0);
            #pragma unroll
            for (int c=0;c<4;c++) wr[c] = *(const float4*)(slab + (k0+c)*68 + j0);
            #pragma unroll
            for (int u=0;u<4;u++){
                #pragma unroll
                for (int c=0;c<4;c++){
                    const float xc = F4E(xi[u], c);
                    const float4 w4 = wr[c];
                    acc2[u][0] += xc*w4.x; acc2[u][1] += xc*w4.y;
                    acc2[u][2] += xc*w4.z; acc2[u][3] += xc*w4.w;
                }
            }
        }
        __syncthreads();
    }
    {
        float s0=0.f,s1=0.f,s2=0.f,s3=0.f;
        #pragma unroll
        for (int u=0;u<4;u++){
            s0 += fmaxf(acc2[u][0],0.f); s1 += fmaxf(acc2[u][1],0.f);
            s2 += fmaxf(acc2[u][2],0.f); s3 += fmaxf(acc2[u][3],0.f);
        }
        *(float4*)(msum + ig*68 + j0) = make_float4(s0,s1,s2,s3);
    }
    __syncthreads();
    if (t < 64){
        float ss = 0.f;
        #pragma unroll
        for (int g2=0; g2<16; g2++) ss += msum[g2*68 + t];
        mean_part[((size_t)(b*4+tile))*64 + t] = ss;
    }
}

// =================== K2a: gram partials ===================
__global__ __launch_bounds__(256) void k2a_build(
    const float* __restrict__ fx, const float* __restrict__ fy,
    const float* __restrict__ x, const float* __restrict__ y,
    float* __restrict__ gram)
{
    const int blk = blockIdx.x;
    const int kh = blk & 1, side = (blk>>1)&1, b = blk>>2;
    const float* feat = side ? fy : fx;
    const float* targ = side ? x : y;
    float* g = gram + (size_t)blk*GSTRIDE;
    const int t = threadIdx.x;
    const int ig2 = t & 15, jg2 = t >> 4;
    const int i0 = ig2*4, j0 = jg2*4;
    __shared__ float Zt[64*68], Tt[64*68];
    __shared__ float red[4];

    float accA[4][4], accR[4][4];
    #pragma unroll
    for (int u=0;u<4;u++)
        #pragma unroll
        for (int v=0;v<4;v++){ accA[u][v]=0.f; accR[u][v]=0.f; }
    float szp=0.f, stp=0.f, tsqp=0.f;
    const int cc_ = t & 63, rq = t >> 6;

    for (int sub=0; sub<2; sub++){
        if (sub) __syncthreads();
        const int r0g = b*NS + kh*128 + sub*64;
        #pragma unroll
        for (int u=0;u<4;u++){
            int id = t + 256*u; int r = id>>4, c4 = (id&15)*4;
            *(float4*)(Zt + r*68 + c4) = *(const float4*)(feat + ((size_t)(r0g+r))*NH2 + c4);
            *(float4*)(Tt + r*68 + c4) = *(const float4*)(targ + ((size_t)(r0g+r))*ND + c4);
        }
        __syncthreads();
        #pragma unroll
        for (int ch=0; ch<16; ch++){
            const int r0 = ch*4;
            float4 zi[4], zj[4], tj[4];
            #pragma unroll
            for (int c=0;c<4;c++){
                zi[c] = *(const float4*)(Zt + (r0+c)*68 + i0);
                zj[c] = *(const float4*)(Zt + (r0+c)*68 + j0);
                tj[c] = *(const float4*)(Tt + (r0+c)*68 + j0);
            }
            #pragma unroll
            for (int c=0;c<4;c++){
                #pragma unroll
                for (int u=0;u<4;u++){
                    const float zv = F4E(zi[c], u);
                    const float4 a4 = zj[c], r4 = tj[c];
                    accA[u][0] += zv*a4.x; accA[u][1] += zv*a4.y;
                    accA[u][2] += zv*a4.z; accA[u][3] += zv*a4.w;
                    accR[u][0] += zv*r4.x; accR[u][1] += zv*r4.y;
                    accR[u][2] += zv*r4.z; accR[u][3] += zv*r4.w;
                }
            }
        }
        #pragma unroll
        for (int rr=0; rr<16; rr++){
            int r = rq*16 + rr;
            szp += Zt[r*68 + cc_];
            float tv = Tt[r*68 + cc_];
            stp += tv; tsqp += tv*tv;
        }
    }
    #pragma unroll
    for (int u=0;u<4;u++){
        *(float4*)(g + (i0+u)*64 + j0) = make_float4(accA[u][0],accA[u][1],accA[u][2],accA[u][3]);
        *(float4*)(g + 4096 + (i0+u)*64 + j0) = make_float4(accR[u][0],accR[u][1],accR[u][2],accR[u][3]);
    }
    __syncthreads();
    Zt[rq*68 + cc_] = szp;
    Tt[rq*68 + cc_] = stp;
    float tq = tsqp;
    #pragma unroll
    for (int off=32; off; off>>=1) tq += __shfl_down(tq, off);
    if ((t&63)==0) red[t>>6] = tq;
    __syncthreads();
    if (t < 64){
        g[8192+t] = Zt[t] + Zt[68+t] + Zt[2*68+t] + Zt[3*68+t];
        g[8256+t] = Tt[t] + Tt[68+t] + Tt[2*68+t] + Tt[3*68+t];
    }
    if (t==0) g[8320] = red[0]+red[1]+red[2]+red[3];
}

// =================== K2b: centered 64x64 SPD solve, rank-2 lookahead Jordan ===================
__global__ __launch_bounds__(256) void k2b_solve(
    const float* __restrict__ gram, float* __restrict__ wbuf)
{
    const int bs = blockIdx.x;
    const float* g0 = gram + (size_t)(bs*2+0)*GSTRIDE;
    const float* g1 = gram + (size_t)(bs*2+1)*GSTRIDE;
    float* wb = wbuf + (size_t)bs*WSTRIDE;
    const int t = threadIdx.x;
    __shared__ float A[64*68];
    __shared__ float R[64*68];
    __shared__ float szs[64], sts[64];
    __shared__ float fc0[64], fc1[64];
    __shared__ float sc[8];

    #pragma unroll
    for (int u=0;u<16;u++){
        int id = t + 256*u; int r = id>>6, c = id&63;
        A[r*68+c] = g0[id] + g1[id];
        R[r*68+c] = g0[4096+id] + g1[4096+id];
    }
    if (t<64){ szs[t] = g0[8192+t]+g1[8192+t]; sts[t] = g0[8256+t]+g1[8256+t]; }
    if (t==0) sc[1] = g0[8320]+g1[8320];
    __syncthreads();
    if (t<64){
        float dg = A[t*68+t];
        #pragma unroll
        for (int off=32; off; off>>=1) dg += __shfl_down(dg, off);
        if (t==0){ sc[0] = 1.0f/sqrtf(dg); sc[1] = 1.0f/sqrtf(sc[1]); }
    }
    __syncthreads();
    const float zinv = sc[0], tinv = sc[1];
    const float z2 = zinv*zinv, zt = zinv*tinv, inv256 = 1.0f/256.0f;
    const int i = t>>2, qd = t&3;
    {
        const float szi = szs[i];
        #pragma unroll
        for (int q=0;q<4;q++){
            const int j = qd*16 + q*4;
            float4 v = *(float4*)(A + i*68 + j);
            float4 sj = *(const float4*)(szs + j);
            v.x = z2*(v.x - szi*sj.x*inv256);
            v.y = z2*(v.y - szi*sj.y*inv256);
            v.z = z2*(v.z - szi*sj.z*inv256);
            v.w = z2*(v.w - szi*sj.w*inv256);
            if (i == j)   v.x += 1.f;
            else if (i == j+1) v.y += 1.f;
            else if (i == j+2) v.z += 1.f;
            else if (i == j+3) v.w += 1.f;
            *(float4*)(A + i*68 + j) = v;
            float4 rv = *(float4*)(R + i*68 + j);
            float4 t4 = *(const float4*)(sts + j);
            rv.x = zt*(rv.x - szi*t4.x*inv256);
            rv.y = zt*(rv.y - szi*t4.y*inv256);
            rv.z = zt*(rv.z - szi*t4.z*inv256);
            rv.w = zt*(rv.w - szi*t4.w*inv256);
            *(float4*)(R + i*68 + j) = rv;
        }
    }
    __syncthreads();
    if (t < 64){ fc0[t] = A[t*68 + 0]; fc1[t] = A[t*68 + 1]; }
    __syncthreads();

    // rank-2 lookahead Jordan: 32 iterations, 2 pivots each
    for (int kk=0; kk<32; kk++){
        const int k = 2*kk;
        // pivot scalars (LDS broadcast reads, all threads)
        const float p00  = fc0[k];
        const float a01  = fc1[k];
        const float rp00 = 1.0f/p00;
        const float fk1  = fc0[k+1]*rp00;
        const float rp11 = 1.0f/(fc1[k+1] - fk1*a01);
        const float fi = (i==k)   ? 0.f : fc0[i]*rp00;
        const float gi = (i==k+1) ? 0.f : (fc1[i] - fi*a01)*rp11;
        const float c0 = fi - gi*fk1;
        const float c1 = gi;
        // read pivot-row chunks into registers (before anyone writes)
        const int cq0 = k>>2;           // first live A-chunk
        const int fwq = (k+2)>>2;       // chunk holding cols k+2,k+3
        float4 pkA[4], p1A[4], pkR[4], p1R[4];
        #pragma unroll
        for (int m=0;m<4;m++){
            const int q = qd + 4*m;
            const int jc = q*4;
            if (q >= cq0){
                pkA[m] = *(const float4*)(A + k*68 + jc);
                p1A[m] = *(const float4*)(A + (k+1)*68 + jc);
            }
            pkR[m] = *(const float4*)(R + k*68 + jc);
            p1R[m] = *(const float4*)(R + (k+1)*68 + jc);
        }
        __syncthreads();
        // update own row (A live chunks + all R chunks); forward next fc
        #pragma unroll
        for (int m=0;m<4;m++){
            const int q = qd + 4*m;
            const int jc = q*4;
            if (q >= cq0){
                float4 v = *(float4*)(A + i*68 + jc);
                v.x -= c0*pkA[m].x + c1*p1A[m].x;
                v.y -= c0*pkA[m].y + c1*p1A[m].y;
                v.z -= c0*pkA[m].z + c1*p1A[m].z;
                v.w -= c0*pkA[m].w + c1*p1A[m].w;
                *(float4*)(A + i*68 + jc) = v;
                if (q == fwq && k+2 < 64){
                    if (((k+2)&3) == 0){ fc0[i] = v.x; fc1[i] = v.y; }
                    else               { fc0[i] = v.z; fc1[i] = v.w; }
                }
            }
            float4 r4 = *(float4*)(R + i*68 + jc);
            r4.x -= c0*pkR[m].x + c1*p1R[m].x;
            r4.y -= c0*pkR[m].y + c1*p1R[m].y;
            r4.z -= c0*pkR[m].z + c1*p1R[m].z;
            r4.w -= c0*pkR[m].w + c1*p1R[m].w;
            *(float4*)(R + i*68 + jc) = r4;
        }
        __syncthreads();
    }
    // W = R / diag(A)
    {
        const float dinv = 1.0f / A[i*68 + i];
        #pragma unroll
        for (int m=0;m<4;m++){
            const int jc = (qd + 4*m)*4;
            float4 r4 = *(float4*)(R + i*68 + jc);
            r4.x*=dinv; r4.y*=dinv; r4.z*=dinv; r4.w*=dinv;
            *(float4*)(R + i*68 + jc) = r4;
            *(float4*)(wb + i*64 + jc) = r4;
        }
    }
    __syncthreads();
    if (t < 64){
        float s = 0.f;
        for (int i2=0; i2<64; i2++) s += szs[i2]*R[i2*68 + t];
        wb[4096+t] = (tinv*sts[t] - zinv*s) * inv256;
    }
    if (t==0){ wb[4160] = zinv; wb[4161] = tinv; }
}

// =================== K2c: residuals (+ bf16 emission for K3) ===================
__global__ __launch_bounds__(256) void k2c_resid(
    const float* __restrict__ fx, const float* __restrict__ fy,
    const float* __restrict__ x, const float* __restrict__ y,
    const float* __restrict__ wbuf,
    float* __restrict__ resx, float* __restrict__ resy,
    float* __restrict__ resn, float* __restrict__ rawn,
    float* __restrict__ loss_part,
    unsigned short* __restrict__ resbf, unsigned short* __restrict__ tgbf)
{
    const int blk = blockIdx.x;
    const int h = blk & 1, side = (blk>>1)&1, b = blk>>2;
    const float* feat = side ? fy : fx;
    const float* targ = side ? x : y;
    float* res = side ? resy : resx;
    const float* wb = wbuf + (size_t)(b*2+side)*WSTRIDE;
    const int t = threadIdx.x;
    const int ig = t>>4, jg = t&15, d0 = jg*4;
    const int row0 = b*NS + h*128;
    __shared__ float sZ[128*68];
    __shared__ float sW[64*68];
    __shared__ float c0s[64];
    __shared__ float rnp[128*17];
    __shared__ float rqp[128*17];
    __shared__ float red[4];

    #pragma unroll
    for (int u=0;u<8;u++){
        int id = t + 256*u; int r = id>>4, c4 = (id&15)*4;
        *(float4*)(sZ + r*68 + c4) = *(const float4*)(feat + ((size_t)(row0+r))*NH2 + c4);
    }
    #pragma unroll
    for (int u=0;u<4;u++){
        int id = t + 256*u; int r = id>>4, c4 = (id&15)*4;
        *(float4*)(sW + r*68 + c4) = *(const float4*)(wb + (size_t)r*64 + c4);
    }
    if (t<64) c0s[t] = wb[4096+t];
    const float zinv = wb[4160], tinv = wb[4161];
    __syncthreads();

    float acc[8][4];
    #pragma unroll
    for (int u=0;u<8;u++){ acc[u][0]=0.f; acc[u][1]=0.f; acc[u][2]=0.f; acc[u][3]=0.f; }
    #pragma unroll
    for (int ch=0; ch<16; ch++){
        const int k0 = ch*4;
        float4 wr[4];
        #pragma unroll
        for (int c=0;c<4;c++) wr[c] = *(const float4*)(sW + (k0+c)*68 + d0);
        #pragma unroll
        for (int u=0;u<8;u++){
            float4 zv = *(const float4*)(sZ + (ig+16*u)*68 + k0);
            #pragma unroll
            for (int c=0;c<4;c++){
                const float zc = F4E(zv, c);
                const float4 w4 = wr[c];
                acc[u][0] += zc*w4.x; acc[u][1] += zc*w4.y;
                acc[u][2] += zc*w4.z; acc[u][3] += zc*w4.w;
            }
        }
    }
    const float4 c04 = *(const float4*)(c0s + d0);
    #pragma unroll
    for (int u=0;u<8;u++){
        const int r = ig + 16*u;
        const int gr = row0 + r;
        float4 q = *(const float4*)(targ + (size_t)gr*ND + d0);
        float4 rr;
        rr.x = tinv*q.x - zinv*acc[u][0] - c04.x;
        rr.y = tinv*q.y - zinv*acc[u][1] - c04.y;
        rr.z = tinv*q.z - zinv*acc[u][2] - c04.z;
        rr.w = tinv*q.w - zinv*acc[u][3] - c04.w;
        *(float4*)(res + (size_t)gr*ND + d0) = rr;
        *(ushort4*)(resbf + ((size_t)side*NB*NS + gr)*64 + d0) =
            make_ushort4(f2bf(rr.x), f2bf(rr.y), f2bf(rr.z), f2bf(rr.w));
        *(ushort4*)(tgbf + ((size_t)side*NB*NS + gr)*64 + d0) =
            make_ushort4(f2bf(q.x), f2bf(q.y), f2bf(q.z), f2bf(q.w));
        rnp[r*17 + jg] = rr.x*rr.x + rr.y*rr.y + rr.z*rr.z + rr.w*rr.w;
        rqp[r*17 + jg] = q.x*q.x + q.y*q.y + q.z*q.z + q.w*q.w;
    }
    __syncthreads();
    float myrn = 0.f;
    if (t < 128){
        float rn=0.f, rq=0.f;
        #pragma unroll
        for (int g2=0; g2<16; g2++){ rn += rnp[t*17+g2]; rq += rqp[t*17+g2]; }
        resn[(size_t)(side*NB+b)*NS + h*128 + t] = rn;
        rawn[(size_t)(side*NB+b)*NS + h*128 + t] = rq;
        myrn = rn;
    }
    float l = myrn;
    #pragma unroll
    for (int off=32; off; off>>=1) l += __shfl_down(l, off);
    if ((t&63)==0) red[t>>6] = l;
    __syncthreads();
    if (t==0) loss_part[blk] = red[0]+red[1]+red[2]+red[3];
}

// =================== K3: Renyi-2 Grams via bf16 MFMA ===================
// block = ((side*NB + b)*2 + jh); 256 threads = 4 waves; wave w owns i-rows [64w,64w+64)
__global__ __launch_bounds__(256) void k3_renyi(
    const unsigned short* __restrict__ resbf, const unsigned short* __restrict__ tgbf,
    const float* __restrict__ resn, const float* __restrict__ rawn,
    float* __restrict__ part3)
{
    const int blk = blockIdx.x;
    const int jh = blk & 1;
    const int b = (blk >> 1) & (NB-1);
    const int side = (blk >> 1) >> 6;
    const unsigned short* Am = resbf + ((size_t)side*NB*NS + (size_t)b*NS)*64;
    const unsigned short* Bm = tgbf  + ((size_t)(1-side)*NB*NS + (size_t)b*NS)*64;
    const float* nA = resn + (size_t)(side*NB+b)*NS;
    const float* nB = rawn + (size_t)((1-side)*NB+b)*NS;
    const int t = threadIdx.x;
    const int lane = t & 63, wv = t >> 6;

    __shared__ unsigned short Abf[256*72];   // row stride 72 bf16 = 144 B (2-way-free banks)
    __shared__ unsigned short Bbf[256*72];
    __shared__ float nAs[256], nBs[256];
    __shared__ float red[4][3];

    #pragma unroll
    for (int u=0;u<8;u++){
        int id = t + 256*u;                 // 2048 16B-chunks per matrix
        int r = id>>3, c = id&7;
        *(float4*)((char*)Abf + r*144 + c*16) = *(const float4*)(Am + (size_t)r*64 + c*8);
        *(float4*)((char*)Bbf + r*144 + c*16) = *(const float4*)(Bm + (size_t)r*64 + c*8);
    }
    nAs[t] = nA[t];
    nBs[t] = nB[t];
    __syncthreads();

    const int lrow = lane & 15;
    const int lkb  = (lane >> 4) * 16;      // byte offset of this lane's k-slice (8 bf16)
    const char* pA = (const char*)Abf;
    const char* pB = (const char*)Bbf;
    const f32x4 zero4 = {0.f, 0.f, 0.f, 0.f};
    const float CEXP = -2.8853900817779268f;  // -2 * log2(e): exp(-2d) = 2^(CEXP*d)

    float Sa=0.f, Sb=0.f, Sab=0.f;
    #pragma unroll
    for (int it=0; it<4; it++){
        const int i0 = wv*64 + it*16;
        const int arow = i0 + lrow;
        bf16x8 aA0 = *(const bf16x8*)(pA + arow*144 + lkb);
        bf16x8 aA1 = *(const bf16x8*)(pA + arow*144 + lkb + 64);
        bf16x8 aB0 = *(const bf16x8*)(pB + arow*144 + lkb);
        bf16x8 aB1 = *(const bf16x8*)(pB + arow*144 + lkb + 64);
        float nAi[4], nBi[4];
        #pragma unroll
        for (int e=0;e<4;e++){
            int gi = i0 + (lane>>4)*4 + e;
            nAi[e] = nAs[gi]; nBi[e] = nBs[gi];
        }
        #pragma unroll
        for (int jt=0; jt<8; jt++){
            const int j0 = jh*128 + jt*16;
            const int brow = j0 + lrow;
            bf16x8 bA0 = *(const bf16x8*)(pA + brow*144 + lkb);
            bf16x8 bA1 = *(const bf16x8*)(pA + brow*144 + lkb + 64);
            bf16x8 bB0 = *(const bf16x8*)(pB + brow*144 + lkb);
            bf16x8 bB1 = *(const bf16x8*)(pB + brow*144 + lkb + 64);
            f32x4 cA = __builtin_amdgcn_mfma_f32_16x16x32_bf16(aA0, bA0, zero4, 0, 0, 0);
            cA = __builtin_amdgcn_mfma_f32_16x16x32_bf16(aA1, bA1, cA, 0, 0, 0);
            f32x4 cB = __builtin_amdgcn_mfma_f32_16x16x32_bf16(aB0, bB0, zero4, 0, 0, 0);
            cB = __builtin_amdgcn_mfma_f32_16x16x32_bf16(aB1, bB1, cB, 0, 0, 0);
            const int gj = j0 + lrow;       // C/D: col = lane&15
            const float nAj = nAs[gj], nBj = nBs[gj];
            #pragma unroll
            for (int e=0;e<4;e++){
                const int gi = i0 + (lane>>4)*4 + e;   // C/D: row = (lane>>4)*4+e
                const float dda = (gi==gj) ? 0.f : (nAi[e] + nAj - 2.f*cA[e]);
                const float ddb = (gi==gj) ? 0.f : (nBi[e] + nBj - 2.f*cB[e]);
                const float ka2 = exp2f(CEXP*dda);
                const float kb2 = exp2f(CEXP*ddb);
                Sa += ka2; Sb += kb2; Sab += ka2*kb2;
            }
        }
    }
    #pragma unroll
    for (int off=32; off; off>>=1){
        Sa += __shfl_down(Sa,off); Sb += __shfl_down(Sb,off); Sab += __shfl_down(Sab,off);
    }
    if (lane==0){ red[wv][0]=Sa; red[wv][1]=Sb; red[wv][2]=Sab; }
    __syncthreads();
    if (t==0){
        float* o = part3 + (size_t)blk*3;
        o[0] = red[0][0]+red[1][0]+red[2][0]+red[3][0];
        o[1] = red[0][1]+red[1][1]+red[2][1]+red[3][1];
        o[2] = red[0][2]+red[1][2]+red[2][2]+red[3][2];
    }
}

// =================== K4 ===================
__global__ __launch_bounds__(64) void k4_final(
    const float* __restrict__ mean_part, const float* __restrict__ part3,
    const float* __restrict__ loss_part,
    const float* __restrict__ wc1, const float* __restrict__ bc1,
    const float* __restrict__ bn_gamma, const float* __restrict__ bn_beta,
    const float* __restrict__ w2, const float* __restrict__ b2,
    const float* __restrict__ wc2, const float* __restrict__ bc2,
    float* __restrict__ dout)
{
    const int t = threadIdx.x;
    __shared__ float ic[64][5];
    __shared__ float mu[5], iv[5];

    dout[192+t] = loss_part[4*t+0] + loss_part[4*t+1];
    dout[256+t] = loss_part[4*t+2] + loss_part[4*t+3];

    float o0 = bc1[0], o1 = bc1[1], o2 = bc1[2];
    for (int c=0;c<64;c++){
        float mv = mean_part[(t*4+0)*64+c] + mean_part[(t*4+1)*64+c]
                 + mean_part[(t*4+2)*64+c] + mean_part[(t*4+3)*64+c];
        mv *= (1.0f/256.0f);
        o0 += mv*wc1[c*3+0]; o1 += mv*wc1[c*3+1]; o2 += mv*wc1[c*3+2];
    }
    dout[t*3+0]=o0; dout[t*3+1]=o1; dout[t*3+2]=o2;
    {
        float m = fmaxf(o0,fmaxf(o1,o2));
        float e0=__expf(o0-m), e1=__expf(o1-m), e2=__expf(o2-m);
        float inv = 1.f/(e0+e1+e2);
        dout[640+t*3+0]=e0*inv; dout[640+t*3+1]=e1*inv; dout[640+t*3+2]=e2*inv;
    }
    float exy[2];
    #pragma unroll
    for (int side=0; side<2; side++){
        const float* pp = part3 + (size_t)((side*NB + t)*2)*3;
        float Sa = pp[0]+pp[3];
        float Sb = pp[1]+pp[4];
        float Sab= pp[2]+pp[5];
        float Hx  = 16.f - log2f(Sa);
        float Hy  = 16.f - log2f(Sb);
        float Hxy = 16.f - log2f(Sab);
        float mi = (Hx + Hy - Hxy) / fmaxf(Hx, Hy);
        dout[(side?384:320)+t] = mi;
        exy[side] = mi;
    }
    ic[t][0]=o0; ic[t][1]=o1; ic[t][2]=o2; ic[t][3]=exy[0]; ic[t][4]=exy[1];
    __syncthreads();
    if (t<5){
        float m=0.f;
        for (int bb=0;bb<64;bb++) m += ic[bb][t];
        m *= (1.f/64.f);
        float v=0.f;
        for (int bb=0;bb<64;bb++){ float d=ic[bb][t]-m; v+=d*d; }
        v *= (1.f/64.f);
        mu[t]=m; iv[t]=1.f/sqrtf(v+1e-5f);
    }
    __syncthreads();
    float vn[5];
    #pragma unroll
    for (int c=0;c<5;c++) vn[c] = (ic[t][c]-mu[c])*iv[c]*bn_gamma[c]+bn_beta[c];
    float q0=bc2[0], q1=bc2[1], q2=bc2[2];
    for (int j=0;j<64;j++){
        float hh = b2[j];
        #pragma unroll
        for (int c=0;c<5;c++) hh += vn[c]*w2[c*64+j];
        hh = fmaxf(hh,0.f);
        q0 += hh*wc2[j*3+0]; q1 += hh*wc2[j*3+1]; q2 += hh*wc2[j*3+2];
    }
    dout[448+t*3+0]=q0; dout[448+t*3+1]=q1; dout[448+t*3+2]=q2;
    float m = fmaxf(q0,fmaxf(q1,q2));
    float e0=__expf(q0-m), e1=__expf(q1-m), e2=__expf(q2-m);
    float inv=1.f/(e0+e1+e2);
    dout[832+t*3+0]=e0*inv; dout[832+t*3+1]=e1*inv; dout[832+t*3+2]=e2*inv;
}

extern "C" void kernel_launch(void* const* d_in, const int* in_sizes, int n_in,
                              void* d_out, int out_size, void* d_ws, size_t ws_size,
                              hipStream_t stream)
{
    const float* x     = (const float*)d_in[0];
    const float* y     = (const float*)d_in[1];
    const float* w11_1 = (const float*)d_in[2];
    const float* b11_1 = (const float*)d_in[3];
    const float* w11_2 = (const float*)d_in[4];
    const float* b11_2 = (const float*)d_in[5];
    const float* w12_1 = (const float*)d_in[6];
    const float* b12_1 = (const float*)d_in[7];
    const float* w12_2 = (const float*)d_in[8];
    const float* b12_2 = (const float*)d_in[9];
    const float* wc1   = (const float*)d_in[10];
    const float* bc1   = (const float*)d_in[11];
    const float* bn_g  = (const float*)d_in[12];
    const float* bn_b  = (const float*)d_in[13];
    const float* w2    = (const float*)d_in[14];
    const float* b2    = (const float*)d_in[15];
    const float* wc2   = (const float*)d_in[16];
    const float* bc2   = (const float*)d_in[17];

    float* ws   = (float*)d_ws;
    float* dout = (float*)d_out;
    float* out_x = ws;
    float* out_y = ws + 1048576;
    float* resx  = ws + 2097152;
    float* resy  = ws + 3145728;
    float* resn  = ws + 4194304;                 // 32768
    float* rawn  = resn + 32768;                 // 32768
    float* mean_part = rawn + 32768;             // 16384
    float* part3 = mean_part + 16384;            // 768 (pad region 3840)
    float* loss_part = part3 + 3840;             // 256
    float* gram  = ws + 4280320;                 // 256*8448 = 2162688 floats
    float* wbuf  = gram + 2162688;               // 128*4224 = 540672
    // bf16 staging overlays gram (dead after k2b; k2c writes, k3 reads)
    unsigned short* resbf = (unsigned short*)gram;          // 2*64*256*64 ushorts
    unsigned short* tgbf  = resbf + 2097152;                // 2*64*256*64 ushorts

    hipLaunchKernelGGL(k1_fused, dim3(NB*4), dim3(256), 0, stream,
        x,y,w11_1,b11_1,w11_2,b11_2,w12_1,b12_1,w12_2,b12_2,
        out_x,out_y,mean_part);
    hipLaunchKernelGGL(k2a_build, dim3(NB*4), dim3(256), 0, stream,
        out_x,out_y,x,y,gram);
    hipLaunchKernelGGL(k2b_solve, dim3(2*NB), dim3(256), 0, stream,
        gram,wbuf);
    hipLaunchKernelGGL(k2c_resid, dim3(NB*4), dim3(256), 0, stream,
        out_x,out_y,x,y,wbuf,resx,resy,resn,rawn,loss_part,resbf,tgbf);
    hipLaunchKernelGGL(k3_renyi, dim3(NB*2*2), dim3(256), 0, stream,
        resbf,tgbf,resn,rawn,part3);
    hipLaunchKernelGGL(k4_final, dim3(1), dim3(64), 0, stream,
        mean_part,part3,loss_part,wc1,bc1,bn_g,bn_b,w2,b2,wc2,bc2,dout);
}

// Round 7
// 109.695 us; speedup vs baseline: 2.1058x; 1.0828x over previous
//
#include <hip/hip_runtime.h>
#include <math.h>

#define NB 64
#define NS 256
#define ND 64
#define NH2 64
#define NH 128
#define GSTRIDE 8448
#define WSTRIDE 4224

// d_out layout (floats):
// 0: out_c[64*3]; 192: rx[64]; 256: ry[64]; 320: ex[64]; 384: ey[64];
// 448: out_c_f[64*3]; 640: prob1[64*3]; 832: prob2[64*3]

#define F4E(v_, e_) ((e_)==0?(v_).x:((e_)==1?(v_).y:((e_)==2?(v_).z:(v_).w)))

typedef __attribute__((ext_vector_type(8))) short bf16x8;
typedef __attribute__((ext_vector_type(4))) float f32x4;

__device__ __forceinline__ unsigned short f2bf(float f){
    union { float f; unsigned int u; } v; v.f = f;
    unsigned int r = v.u + 0x7fffu + ((v.u >> 16) & 1u);
    return (unsigned short)(r >> 16);
}
__device__ __forceinline__ float bf2f(unsigned short h){
    union { unsigned int u; float f; } v; v.u = ((unsigned int)h) << 16;
    return v.f;
}
// split f32 into hi/lo bf16 and store to two LDS planes
__device__ __forceinline__ void sw2(unsigned short* ph, unsigned short* pl, int idx, float f){
    unsigned short h = f2bf(f);
    ph[idx] = h;
    pl[idx] = f2bf(f - bf2f(h));
}

#define LD8(P_, row_, kb_) (*(const bf16x8*)((const char*)(P_) + (size_t)(row_)*144 + (kb_)))

// K=64 tile MAC: acc += A[ar..ar+15][0:64] * B[br..br+15][0:64]^T  (hi/lo 3-combo)
__device__ __forceinline__ f32x4 mm64(
    const unsigned short* Ah, const unsigned short* Al,
    const unsigned short* Bh, const unsigned short* Bl,
    int ar, int br, int lrow, int lkb, f32x4 acc)
{
    const int ra = ar + lrow, rb = br + lrow;
    bf16x8 ah0 = LD8(Ah, ra, lkb), ah1 = LD8(Ah, ra, lkb+64);
    bf16x8 al0 = LD8(Al, ra, lkb), al1 = LD8(Al, ra, lkb+64);
    bf16x8 bh0 = LD8(Bh, rb, lkb), bh1 = LD8(Bh, rb, lkb+64);
    bf16x8 bl0 = LD8(Bl, rb, lkb), bl1 = LD8(Bl, rb, lkb+64);
    acc = __builtin_amdgcn_mfma_f32_16x16x32_bf16(ah0, bh0, acc, 0,0,0);
    acc = __builtin_amdgcn_mfma_f32_16x16x32_bf16(ah1, bh1, acc, 0,0,0);
    acc = __builtin_amdgcn_mfma_f32_16x16x32_bf16(ah0, bl0, acc, 0,0,0);
    acc = __builtin_amdgcn_mfma_f32_16x16x32_bf16(ah1, bl1, acc, 0,0,0);
    acc = __builtin_amdgcn_mfma_f32_16x16x32_bf16(al0, bh0, acc, 0,0,0);
    acc = __builtin_amdgcn_mfma_f32_16x16x32_bf16(al1, bh1, acc, 0,0,0);
    return acc;
}

// =================== K1: MFMA bf16-hi/lo fused MLP ===================
// grid = NB*4 (64-sample tiles); 256 threads = 4 waves
__global__ __launch_bounds__(256) void k1_fused(
    const float* __restrict__ x, const float* __restrict__ y,
    const float* __restrict__ w11_1, const float* __restrict__ b11_1,
    const float* __restrict__ w11_2, const float* __restrict__ b11_2,
    const float* __restrict__ w12_1, const float* __restrict__ b12_1,
    const float* __restrict__ w12_2, const float* __restrict__ b12_2,
    float* __restrict__ out_x, float* __restrict__ out_y,
    float* __restrict__ mean_part)
{
    const int b = blockIdx.x >> 2, tile = blockIdx.x & 3;
    const int t = threadIdx.x;
    const int lane = t & 63, wv = t >> 6;
    const int lrow = lane & 15;
    const int lkb  = (lane >> 4) * 16;
    const int row0g = b*NS + tile*64;

    // LDS planes ([rows][72] bf16 each; row stride 144 B)
    __shared__ unsigned short XYh[9216], XYl[9216];   // 128 rows: x|y inputs; later w12_1^T halves (128 cols)
    __shared__ unsigned short W1h[4608], W1l[4608];   // 64 rows: W1^T; later w12_2^T half1
    __shared__ unsigned short W2h[4608], W2l[4608];   // 64 rows: W2^T; later w12_2^T half0
    __shared__ unsigned short Hh [9216], Hl [9216];   // 128 rows: H(x|y); later H1 k-halves
    __shared__ unsigned short Oh [9216], Ol [9216];   // 128 rows: Ox|Oy
    __shared__ float msum[4*68];

    // ---- P0: stage XY (x rows 0..63, y rows 64..127) + W1^T + W2^T ----
    #pragma unroll
    for (int u=0;u<8;u++){
        int id = t + 256*u;                    // 2048 float4
        int r = id>>4, c0 = (id&15)*4;
        const float* src = (r < 64) ? (x + ((size_t)(row0g + r))*ND)
                                    : (y + ((size_t)(row0g + r - 64))*ND);
        float4 v = *(const float4*)(src + c0);
        sw2(XYh, XYl, r*72 + c0+0, v.x);
        sw2(XYh, XYl, r*72 + c0+1, v.y);
        sw2(XYh, XYl, r*72 + c0+2, v.z);
        sw2(XYh, XYl, r*72 + c0+3, v.w);
    }
    #pragma unroll
    for (int u=0;u<4;u++){
        int id = t + 256*u;                    // 1024 float4 per weight
        int r = id>>4, c0 = (id&15)*4;
        float4 v1 = *(const float4*)(w11_1 + (size_t)r*64 + c0);
        float4 v2 = *(const float4*)(w11_2 + (size_t)r*64 + c0);
        #pragma unroll
        for (int i2=0;i2<4;i2++){
            sw2(W1h, W1l, (c0+i2)*72 + r, F4E(v1,i2));
            sw2(W2h, W2l, (c0+i2)*72 + r, F4E(v2,i2));
        }
    }
    __syncthreads();

    // ---- P1: G1  H = relu(XY @ W1 + b1)  (128x64, K=64) ----
    #pragma unroll
    for (int it=0; it<2; it++){
        const int ar = 32*wv + 16*it;
        #pragma unroll
        for (int jt=0; jt<4; jt++){
            float bb = b11_1[jt*16 + lrow];
            f32x4 acc = {bb,bb,bb,bb};
            acc = mm64(XYh, XYl, W1h, W1l, ar, jt*16, lrow, lkb, acc);
            #pragma unroll
            for (int e=0;e<4;e++){
                int row = ar + (lane>>4)*4 + e;
                int col = jt*16 + lrow;
                sw2(Hh, Hl, row*72 + col, fmaxf(acc[e], 0.f));
            }
        }
    }
    __syncthreads();

    // ---- P2: stage w12_1^T half0 into XY region; G2  O = H @ W2 + b2 ----
    #pragma unroll
    for (int u=0;u<8;u++){
        int id = t + 256*u;                    // 2048 float4 (64k x 128n)
        int kr = id>>5, c0 = (id&31)*4;
        float4 v = *(const float4*)(w12_1 + (size_t)kr*NH + c0);
        #pragma unroll
        for (int i2=0;i2<4;i2++) sw2(XYh, XYl, (c0+i2)*72 + kr, F4E(v,i2));
    }
    #pragma unroll
    for (int it=0; it<2; it++){
        const int ar = 32*wv + 16*it;
        #pragma unroll
        for (int jt=0; jt<4; jt++){
            float bb = b11_2[jt*16 + lrow];
            f32x4 acc = {bb,bb,bb,bb};
            acc = mm64(Hh, Hl, W2h, W2l, ar, jt*16, lrow, lkb, acc);
            #pragma unroll
            for (int e=0;e<4;e++){
                int row = ar + (lane>>4)*4 + e;
                int col = jt*16 + lrow;
                float v = acc[e];
                sw2(Oh, Ol, row*72 + col, v);
                float* dst = (row < 64) ? out_x : out_y;
                dst[((size_t)(row0g + (row & 63)))*NH2 + col] = v;
            }
        }
    }
    __syncthreads();

    // ---- P3: G3 pass0: acc3 += Ox @ w12_1[0:64,:] ----
    f32x4 acc3[8];
    #pragma unroll
    for (int jt=0; jt<8; jt++){
        float bb = b12_1[jt*16 + lrow];
        f32x4 v = {bb,bb,bb,bb};
        acc3[jt] = v;
    }
    #pragma unroll
    for (int jt=0; jt<8; jt++)
        acc3[jt] = mm64(Oh, Ol, XYh, XYl, 16*wv, jt*16, lrow, lkb, acc3[jt]);
    __syncthreads();

    // ---- P4: stage w12_1^T half1 -> XY region; w12_2^T halves -> W2/W1 slots ----
    #pragma unroll
    for (int u=0;u<8;u++){
        int id = t + 256*u;
        int kr = id>>5, c0 = (id&31)*4;
        float4 v = *(const float4*)(w12_1 + (size_t)(64+kr)*NH + c0);
        #pragma unroll
        for (int i2=0;i2<4;i2++) sw2(XYh, XYl, (c0+i2)*72 + kr, F4E(v,i2));
    }
    #pragma unroll
    for (int u=0;u<4;u++){
        int id = t + 256*u;                    // 1024 float4 per half
        int kr = id>>4, c0 = (id&15)*4;
        float4 v0 = *(const float4*)(w12_2 + (size_t)kr*NH2 + c0);
        float4 v1 = *(const float4*)(w12_2 + (size_t)(64+kr)*NH2 + c0);
        #pragma unroll
        for (int i2=0;i2<4;i2++){
            sw2(W2h, W2l, (c0+i2)*72 + kr, F4E(v0,i2));   // k-half0
            sw2(W1h, W1l, (c0+i2)*72 + kr, F4E(v1,i2));   // k-half1
        }
    }
    __syncthreads();

    // ---- P5: G3 pass1: acc3 += Oy @ w12_1[64:128,:]; epi -> H1 (relu) into H region ----
    #pragma unroll
    for (int jt=0; jt<8; jt++)
        acc3[jt] = mm64(Oh, Ol, XYh, XYl, 64 + 16*wv, jt*16, lrow, lkb, acc3[jt]);
    #pragma unroll
    for (int jt=0; jt<8; jt++){
        #pragma unroll
        for (int e=0;e<4;e++){
            int row = 16*wv + (lane>>4)*4 + e;        // sample 0..63
            int col = jt*16 + lrow;                   // 0..127
            float v = fmaxf(acc3[jt][e], 0.f);
            int idx = (col < 64) ? (row*72 + col) : ((64+row)*72 + (col-64));
            sw2(Hh, Hl, idx, v);
        }
    }
    __syncthreads();

    // ---- P6: G4: O2 = relu(H1 @ w12_2 + b), two K-passes; column sums ----
    {
        f32x4 acc2[4];
        #pragma unroll
        for (int jt=0; jt<4; jt++){
            float bb = b12_2[jt*16 + lrow];
            f32x4 v = {bb,bb,bb,bb};
            acc2[jt] = v;
        }
        #pragma unroll
        for (int jt=0; jt<4; jt++){
            acc2[jt] = mm64(Hh, Hl, W2h, W2l, 16*wv,      jt*16, lrow, lkb, acc2[jt]);
            acc2[jt] = mm64(Hh, Hl, W1h, W1l, 64 + 16*wv, jt*16, lrow, lkb, acc2[jt]);
        }
        #pragma unroll
        for (int jt=0; jt<4; jt++){
            float s = fmaxf(acc2[jt][0],0.f) + fmaxf(acc2[jt][1],0.f)
                    + fmaxf(acc2[jt][2],0.f) + fmaxf(acc2[jt][3],0.f);
            s += __shfl_down(s, 32);
            s += __shfl_down(s, 16);
            if (lane < 16) msum[wv*68 + jt*16 + lane] = s;
        }
    }
    __syncthreads();
    if (t < 64){
        float ss = msum[t] + msum[68+t] + msum[2*68+t] + msum[3*68+t];
        mean_part[((size_t)(b*4+tile))*64 + t] = ss;
    }
}

// =================== K2a: gram partials ===================
__global__ __launch_bounds__(256) void k2a_build(
    const float* __restrict__ fx, const float* __restrict__ fy,
    const float* __restrict__ x, const float* __restrict__ y,
    float* __restrict__ gram)
{
    const int blk = blockIdx.x;
    const int kh = blk & 1, side = (blk>>1)&1, b = blk>>2;
    const float* feat = side ? fy : fx;
    const float* targ = side ? x : y;
    float* g = gram + (size_t)blk*GSTRIDE;
    const int t = threadIdx.x;
    const int ig2 = t & 15, jg2 = t >> 4;
    const int i0 = ig2*4, j0 = jg2*4;
    __shared__ float Zt[64*68], Tt[64*68];
    __shared__ float red[4];

    float accA[4][4], accR[4][4];
    #pragma unroll
    for (int u=0;u<4;u++)
        #pragma unroll
        for (int v=0;v<4;v++){ accA[u][v]=0.f; accR[u][v]=0.f; }
    float szp=0.f, stp=0.f, tsqp=0.f;
    const int cc_ = t & 63, rq = t >> 6;

    for (int sub=0; sub<2; sub++){
        if (sub) __syncthreads();
        const int r0g = b*NS + kh*128 + sub*64;
        #pragma unroll
        for (int u=0;u<4;u++){
            int id = t + 256*u; int r = id>>4, c4 = (id&15)*4;
            *(float4*)(Zt + r*68 + c4) = *(const float4*)(feat + ((size_t)(r0g+r))*NH2 + c4);
            *(float4*)(Tt + r*68 + c4) = *(const float4*)(targ + ((size_t)(r0g+r))*ND + c4);
        }
        __syncthreads();
        #pragma unroll
        for (int ch=0; ch<16; ch++){
            const int r0 = ch*4;
            float4 zi[4], zj[4], tj[4];
            #pragma unroll
            for (int c=0;c<4;c++){
                zi[c] = *(const float4*)(Zt + (r0+c)*68 + i0);
                zj[c] = *(const float4*)(Zt + (r0+c)*68 + j0);
                tj[c] = *(const float4*)(Tt + (r0+c)*68 + j0);
            }
            #pragma unroll
            for (int c=0;c<4;c++){
                #pragma unroll
                for (int u=0;u<4;u++){
                    const float zv = F4E(zi[c], u);
                    const float4 a4 = zj[c], r4 = tj[c];
                    accA[u][0] += zv*a4.x; accA[u][1] += zv*a4.y;
                    accA[u][2] += zv*a4.z; accA[u][3] += zv*a4.w;
                    accR[u][0] += zv*r4.x; accR[u][1] += zv*r4.y;
                    accR[u][2] += zv*r4.z; accR[u][3] += zv*r4.w;
                }
            }
        }
        #pragma unroll
        for (int rr=0; rr<16; rr++){
            int r = rq*16 + rr;
            szp += Zt[r*68 + cc_];
            float tv = Tt[r*68 + cc_];
            stp += tv; tsqp += tv*tv;
        }
    }
    #pragma unroll
    for (int u=0;u<4;u++){
        *(float4*)(g + (i0+u)*64 + j0) = make_float4(accA[u][0],accA[u][1],accA[u][2],accA[u][3]);
        *(float4*)(g + 4096 + (i0+u)*64 + j0) = make_float4(accR[u][0],accR[u][1],accR[u][2],accR[u][3]);
    }
    __syncthreads();
    Zt[rq*68 + cc_] = szp;
    Tt[rq*68 + cc_] = stp;
    float tq = tsqp;
    #pragma unroll
    for (int off=32; off; off>>=1) tq += __shfl_down(tq, off);
    if ((t&63)==0) red[t>>6] = tq;
    __syncthreads();
    if (t < 64){
        g[8192+t] = Zt[t] + Zt[68+t] + Zt[2*68+t] + Zt[3*68+t];
        g[8256+t] = Tt[t] + Tt[68+t] + Tt[2*68+t] + Tt[3*68+t];
    }
    if (t==0) g[8320] = red[0]+red[1]+red[2]+red[3];
}

// =================== K2b: centered 64x64 SPD solve, rank-2 lookahead Jordan ===================
__global__ __launch_bounds__(256) void k2b_solve(
    const float* __restrict__ gram, float* __restrict__ wbuf)
{
    const int bs = blockIdx.x;
    const float* g0 = gram + (size_t)(bs*2+0)*GSTRIDE;
    const float* g1 = gram + (size_t)(bs*2+1)*GSTRIDE;
    float* wb = wbuf + (size_t)bs*WSTRIDE;
    const int t = threadIdx.x;
    __shared__ float A[64*68];
    __shared__ float R[64*68];
    __shared__ float szs[64], sts[64];
    __shared__ float fc0[64], fc1[64];
    __shared__ float sc[8];

    #pragma unroll
    for (int u=0;u<16;u++){
        int id = t + 256*u; int r = id>>6, c = id&63;
        A[r*68+c] = g0[id] + g1[id];
        R[r*68+c] = g0[4096+id] + g1[4096+id];
    }
    if (t<64){ szs[t] = g0[8192+t]+g1[8192+t]; sts[t] = g0[8256+t]+g1[8256+t]; }
    if (t==0) sc[1] = g0[8320]+g1[8320];
    __syncthreads();
    if (t<64){
        float dg = A[t*68+t];
        #pragma unroll
        for (int off=32; off; off>>=1) dg += __shfl_down(dg, off);
        if (t==0){ sc[0] = 1.0f/sqrtf(dg); sc[1] = 1.0f/sqrtf(sc[1]); }
    }
    __syncthreads();
    const float zinv = sc[0], tinv = sc[1];
    const float z2 = zinv*zinv, zt = zinv*tinv, inv256 = 1.0f/256.0f;
    const int i = t>>2, qd = t&3;
    {
        const float szi = szs[i];
        #pragma unroll
        for (int q=0;q<4;q++){
            const int j = qd*16 + q*4;
            float4 v = *(float4*)(A + i*68 + j);
            float4 sj = *(const float4*)(szs + j);
            v.x = z2*(v.x - szi*sj.x*inv256);
            v.y = z2*(v.y - szi*sj.y*inv256);
            v.z = z2*(v.z - szi*sj.z*inv256);
            v.w = z2*(v.w - szi*sj.w*inv256);
            if (i == j)   v.x += 1.f;
            else if (i == j+1) v.y += 1.f;
            else if (i == j+2) v.z += 1.f;
            else if (i == j+3) v.w += 1.f;
            *(float4*)(A + i*68 + j) = v;
            float4 rv = *(float4*)(R + i*68 + j);
            float4 t4 = *(const float4*)(sts + j);
            rv.x = zt*(rv.x - szi*t4.x*inv256);
            rv.y = zt*(rv.y - szi*t4.y*inv256);
            rv.z = zt*(rv.z - szi*t4.z*inv256);
            rv.w = zt*(rv.w - szi*t4.w*inv256);
            *(float4*)(R + i*68 + j) = rv;
        }
    }
    __syncthreads();
    if (t < 64){ fc0[t] = A[t*68 + 0]; fc1[t] = A[t*68 + 1]; }
    __syncthreads();

    for (int kk=0; kk<32; kk++){
        const int k = 2*kk;
        const float p00  = fc0[k];
        const float a01  = fc1[k];
        const float rp00 = 1.0f/p00;
        const float fk1  = fc0[k+1]*rp00;
        const float rp11 = 1.0f/(fc1[k+1] - fk1*a01);
        const float fi = (i==k)   ? 0.f : fc0[i]*rp00;
        const float gi = (i==k+1) ? 0.f : (fc1[i] - fi*a01)*rp11;
        const float c0 = fi - gi*fk1;
        const float c1 = gi;
        const int cq0 = k>>2;
        const int fwq = (k+2)>>2;
        float4 pkA[4], p1A[4], pkR[4], p1R[4];
        #pragma unroll
        for (int m=0;m<4;m++){
            const int q = qd + 4*m;
            const int jc = q*4;
            if (q >= cq0){
                pkA[m] = *(const float4*)(A + k*68 + jc);
                p1A[m] = *(const float4*)(A + (k+1)*68 + jc);
            }
            pkR[m] = *(const float4*)(R + k*68 + jc);
            p1R[m] = *(const float4*)(R + (k+1)*68 + jc);
        }
        __syncthreads();
        #pragma unroll
        for (int m=0;m<4;m++){
            const int q = qd + 4*m;
            const int jc = q*4;
            if (q >= cq0){
                float4 v = *(float4*)(A + i*68 + jc);
                v.x -= c0*pkA[m].x + c1*p1A[m].x;
                v.y -= c0*pkA[m].y + c1*p1A[m].y;
                v.z -= c0*pkA[m].z + c1*p1A[m].z;
                v.w -= c0*pkA[m].w + c1*p1A[m].w;
                *(float4*)(A + i*68 + jc) = v;
                if (q == fwq && k+2 < 64){
                    if (((k+2)&3) == 0){ fc0[i] = v.x; fc1[i] = v.y; }
                    else               { fc0[i] = v.z; fc1[i] = v.w; }
                }
            }
            float4 r4 = *(float4*)(R + i*68 + jc);
            r4.x -= c0*pkR[m].x + c1*p1R[m].x;
            r4.y -= c0*pkR[m].y + c1*p1R[m].y;
            r4.z -= c0*pkR[m].z + c1*p1R[m].z;
            r4.w -= c0*pkR[m].w + c1*p1R[m].w;
            *(float4*)(R + i*68 + jc) = r4;
        }
        __syncthreads();
    }
    {
        const float dinv = 1.0f / A[i*68 + i];
        #pragma unroll
        for (int m=0;m<4;m++){
            const int jc = (qd + 4*m)*4;
            float4 r4 = *(float4*)(R + i*68 + jc);
            r4.x*=dinv; r4.y*=dinv; r4.z*=dinv; r4.w*=dinv;
            *(float4*)(R + i*68 + jc) = r4;
            *(float4*)(wb + i*64 + jc) = r4;
        }
    }
    __syncthreads();
    if (t < 64){
        float s = 0.f;
        for (int i2=0; i2<64; i2++) s += szs[i2]*R[i2*68 + t];
        wb[4096+t] = (tinv*sts[t] - zinv*s) * inv256;
    }
    if (t==0){ wb[4160] = zinv; wb[4161] = tinv; }
}

// =================== K2c: residuals (+ bf16 emission for K3) ===================
__global__ __launch_bounds__(256) void k2c_resid(
    const float* __restrict__ fx, const float* __restrict__ fy,
    const float* __restrict__ x, const float* __restrict__ y,
    const float* __restrict__ wbuf,
    float* __restrict__ resx, float* __restrict__ resy,
    float* __restrict__ resn, float* __restrict__ rawn,
    float* __restrict__ loss_part,
    unsigned short* __restrict__ resbf, unsigned short* __restrict__ tgbf)
{
    const int blk = blockIdx.x;
    const int h = blk & 1, side = (blk>>1)&1, b = blk>>2;
    const float* feat = side ? fy : fx;
    const float* targ = side ? x : y;
    float* res = side ? resy : resx;
    const float* wb = wbuf + (size_t)(b*2+side)*WSTRIDE;
    const int t = threadIdx.x;
    const int ig = t>>4, jg = t&15, d0 = jg*4;
    const int row0 = b*NS + h*128;
    __shared__ float sZ[128*68];
    __shared__ float sW[64*68];
    __shared__ float c0s[64];
    __shared__ float rnp[128*17];
    __shared__ float rqp[128*17];
    __shared__ float red[4];

    #pragma unroll
    for (int u=0;u<8;u++){
        int id = t + 256*u; int r = id>>4, c4 = (id&15)*4;
        *(float4*)(sZ + r*68 + c4) = *(const float4*)(feat + ((size_t)(row0+r))*NH2 + c4);
    }
    #pragma unroll
    for (int u=0;u<4;u++){
        int id = t + 256*u; int r = id>>4, c4 = (id&15)*4;
        *(float4*)(sW + r*68 + c4) = *(const float4*)(wb + (size_t)r*64 + c4);
    }
    if (t<64) c0s[t] = wb[4096+t];
    const float zinv = wb[4160], tinv = wb[4161];
    __syncthreads();

    float acc[8][4];
    #pragma unroll
    for (int u=0;u<8;u++){ acc[u][0]=0.f; acc[u][1]=0.f; acc[u][2]=0.f; acc[u][3]=0.f; }
    #pragma unroll
    for (int ch=0; ch<16; ch++){
        const int k0 = ch*4;
        float4 wr[4];
        #pragma unroll
        for (int c=0;c<4;c++) wr[c] = *(const float4*)(sW + (k0+c)*68 + d0);
        #pragma unroll
        for (int u=0;u<8;u++){
            float4 zv = *(const float4*)(sZ + (ig+16*u)*68 + k0);
            #pragma unroll
            for (int c=0;c<4;c++){
                const float zc = F4E(zv, c);
                const float4 w4 = wr[c];
                acc[u][0] += zc*w4.x; acc[u][1] += zc*w4.y;
                acc[u][2] += zc*w4.z; acc[u][3] += zc*w4.w;
            }
        }
    }
    const float4 c04 = *(const float4*)(c0s + d0);
    #pragma unroll
    for (int u=0;u<8;u++){
        const int r = ig + 16*u;
        const int gr = row0 + r;
        float4 q = *(const float4*)(targ + (size_t)gr*ND + d0);
        float4 rr;
        rr.x = tinv*q.x - zinv*acc[u][0] - c04.x;
        rr.y = tinv*q.y - zinv*acc[u][1] - c04.y;
        rr.z = tinv*q.z - zinv*acc[u][2] - c04.z;
        rr.w = tinv*q.w - zinv*acc[u][3] - c04.w;
        *(float4*)(res + (size_t)gr*ND + d0) = rr;
        *(ushort4*)(resbf + ((size_t)side*NB*NS + gr)*64 + d0) =
            make_ushort4(f2bf(rr.x), f2bf(rr.y), f2bf(rr.z), f2bf(rr.w));
        *(ushort4*)(tgbf + ((size_t)side*NB*NS + gr)*64 + d0) =
            make_ushort4(f2bf(q.x), f2bf(q.y), f2bf(q.z), f2bf(q.w));
        rnp[r*17 + jg] = rr.x*rr.x + rr.y*rr.y + rr.z*rr.z + rr.w*rr.w;
        rqp[r*17 + jg] = q.x*q.x + q.y*q.y + q.z*q.z + q.w*q.w;
    }
    __syncthreads();
    float myrn = 0.f;
    if (t < 128){
        float rn=0.f, rq=0.f;
        #pragma unroll
        for (int g2=0; g2<16; g2++){ rn += rnp[t*17+g2]; rq += rqp[t*17+g2]; }
        resn[(size_t)(side*NB+b)*NS + h*128 + t] = rn;
        rawn[(size_t)(side*NB+b)*NS + h*128 + t] = rq;
        myrn = rn;
    }
    float l = myrn;
    #pragma unroll
    for (int off=32; off; off>>=1) l += __shfl_down(l, off);
    if ((t&63)==0) red[t>>6] = l;
    __syncthreads();
    if (t==0) loss_part[blk] = red[0]+red[1]+red[2]+red[3];
}

// =================== K3: Renyi-2 Grams via bf16 MFMA ===================
__global__ __launch_bounds__(256) void k3_renyi(
    const unsigned short* __restrict__ resbf, const unsigned short* __restrict__ tgbf,
    const float* __restrict__ resn, const float* __restrict__ rawn,
    float* __restrict__ part3)
{
    const int blk = blockIdx.x;
    const int jh = blk & 1;
    const int b = (blk >> 1) & (NB-1);
    const int side = (blk >> 1) >> 6;
    const unsigned short* Am = resbf + ((size_t)side*NB*NS + (size_t)b*NS)*64;
    const unsigned short* Bm = tgbf  + ((size_t)(1-side)*NB*NS + (size_t)b*NS)*64;
    const float* nA = resn + (size_t)(side*NB+b)*NS;
    const float* nB = rawn + (size_t)((1-side)*NB+b)*NS;
    const int t = threadIdx.x;
    const int lane = t & 63, wv = t >> 6;

    __shared__ unsigned short Abf[256*72];
    __shared__ unsigned short Bbf[256*72];
    __shared__ float nAs[256], nBs[256];
    __shared__ float red[4][3];

    #pragma unroll
    for (int u=0;u<8;u++){
        int id = t + 256*u;
        int r = id>>3, c = id&7;
        *(float4*)((char*)Abf + r*144 + c*16) = *(const float4*)(Am + (size_t)r*64 + c*8);
        *(float4*)((char*)Bbf + r*144 + c*16) = *(const float4*)(Bm + (size_t)r*64 + c*8);
    }
    nAs[t] = nA[t];
    nBs[t] = nB[t];
    __syncthreads();

    const int lrow = lane & 15;
    const int lkb  = (lane >> 4) * 16;
    const char* pA = (const char*)Abf;
    const char* pB = (const char*)Bbf;
    const f32x4 zero4 = {0.f, 0.f, 0.f, 0.f};
    const float CEXP = -2.8853900817779268f;

    float Sa=0.f, Sb=0.f, Sab=0.f;
    #pragma unroll
    for (int it=0; it<4; it++){
        const int i0 = wv*64 + it*16;
        const int arow = i0 + lrow;
        bf16x8 aA0 = *(const bf16x8*)(pA + arow*144 + lkb);
        bf16x8 aA1 = *(const bf16x8*)(pA + arow*144 + lkb + 64);
        bf16x8 aB0 = *(const bf16x8*)(pB + arow*144 + lkb);
        bf16x8 aB1 = *(const bf16x8*)(pB + arow*144 + lkb + 64);
        float nAi[4], nBi[4];
        #pragma unroll
        for (int e=0;e<4;e++){
            int gi = i0 + (lane>>4)*4 + e;
            nAi[e] = nAs[gi]; nBi[e] = nBs[gi];
        }
        #pragma unroll
        for (int jt=0; jt<8; jt++){
            const int j0 = jh*128 + jt*16;
            const int brow = j0 + lrow;
            bf16x8 bA0 = *(const bf16x8*)(pA + brow*144 + lkb);
            bf16x8 bA1 = *(const bf16x8*)(pA + brow*144 + lkb + 64);
            bf16x8 bB0 = *(const bf16x8*)(pB + brow*144 + lkb);
            bf16x8 bB1 = *(const bf16x8*)(pB + brow*144 + lkb + 64);
            f32x4 cA = __builtin_amdgcn_mfma_f32_16x16x32_bf16(aA0, bA0, zero4, 0, 0, 0);
            cA = __builtin_amdgcn_mfma_f32_16x16x32_bf16(aA1, bA1, cA, 0, 0, 0);
            f32x4 cB = __builtin_amdgcn_mfma_f32_16x16x32_bf16(aB0, bB0, zero4, 0, 0, 0);
            cB = __builtin_amdgcn_mfma_f32_16x16x32_bf16(aB1, bB1, cB, 0, 0, 0);
            const int gj = j0 + lrow;
            const float nAj = nAs[gj], nBj = nBs[gj];
            #pragma unroll
            for (int e=0;e<4;e++){
                const int gi = i0 + (lane>>4)*4 + e;
                const float dda = (gi==gj) ? 0.f : (nAi[e] + nAj - 2.f*cA[e]);
                const float ddb = (gi==gj) ? 0.f : (nBi[e] + nBj - 2.f*cB[e]);
                const float ka2 = exp2f(CEXP*dda);
                const float kb2 = exp2f(CEXP*ddb);
                Sa += ka2; Sb += kb2; Sab += ka2*kb2;
            }
        }
    }
    #pragma unroll
    for (int off=32; off; off>>=1){
        Sa += __shfl_down(Sa,off); Sb += __shfl_down(Sb,off); Sab += __shfl_down(Sab,off);
    }
    if (lane==0){ red[wv][0]=Sa; red[wv][1]=Sb; red[wv][2]=Sab; }
    __syncthreads();
    if (t==0){
        float* o = part3 + (size_t)blk*3;
        o[0] = red[0][0]+red[1][0]+red[2][0]+red[3][0];
        o[1] = red[0][1]+red[1][1]+red[2][1]+red[3][1];
        o[2] = red[0][2]+red[1][2]+red[2][2]+red[3][2];
    }
}

// =================== K4 ===================
__global__ __launch_bounds__(64) void k4_final(
    const float* __restrict__ mean_part, const float* __restrict__ part3,
    const float* __restrict__ loss_part,
    const float* __restrict__ wc1, const float* __restrict__ bc1,
    const float* __restrict__ bn_gamma, const float* __restrict__ bn_beta,
    const float* __restrict__ w2, const float* __restrict__ b2,
    const float* __restrict__ wc2, const float* __restrict__ bc2,
    float* __restrict__ dout)
{
    const int t = threadIdx.x;
    __shared__ float ic[64][5];
    __shared__ float mu[5], iv[5];

    dout[192+t] = loss_part[4*t+0] + loss_part[4*t+1];
    dout[256+t] = loss_part[4*t+2] + loss_part[4*t+3];

    float o0 = bc1[0], o1 = bc1[1], o2 = bc1[2];
    for (int c=0;c<64;c++){
        float mv = mean_part[(t*4+0)*64+c] + mean_part[(t*4+1)*64+c]
                 + mean_part[(t*4+2)*64+c] + mean_part[(t*4+3)*64+c];
        mv *= (1.0f/256.0f);
        o0 += mv*wc1[c*3+0]; o1 += mv*wc1[c*3+1]; o2 += mv*wc1[c*3+2];
    }
    dout[t*3+0]=o0; dout[t*3+1]=o1; dout[t*3+2]=o2;
    {
        float m = fmaxf(o0,fmaxf(o1,o2));
        float e0=__expf(o0-m), e1=__expf(o1-m), e2=__expf(o2-m);
        float inv = 1.f/(e0+e1+e2);
        dout[640+t*3+0]=e0*inv; dout[640+t*3+1]=e1*inv; dout[640+t*3+2]=e2*inv;
    }
    float exy[2];
    #pragma unroll
    for (int side=0; side<2; side++){
        const float* pp = part3 + (size_t)((side*NB + t)*2)*3;
        float Sa = pp[0]+pp[3];
        float Sb = pp[1]+pp[4];
        float Sab= pp[2]+pp[5];
        float Hx  = 16.f - log2f(Sa);
        float Hy  = 16.f - log2f(Sb);
        float Hxy = 16.f - log2f(Sab);
        float mi = (Hx + Hy - Hxy) / fmaxf(Hx, Hy);
        dout[(side?384:320)+t] = mi;
        exy[side] = mi;
    }
    ic[t][0]=o0; ic[t][1]=o1; ic[t][2]=o2; ic[t][3]=exy[0]; ic[t][4]=exy[1];
    __syncthreads();
    if (t<5){
        float m=0.f;
        for (int bb=0;bb<64;bb++) m += ic[bb][t];
        m *= (1.f/64.f);
        float v=0.f;
        for (int bb=0;bb<64;bb++){ float d=ic[bb][t]-m; v+=d*d; }
        v *= (1.f/64.f);
        mu[t]=m; iv[t]=1.f/sqrtf(v+1e-5f);
    }
    __syncthreads();
    float vn[5];
    #pragma unroll
    for (int c=0;c<5;c++) vn[c] = (ic[t][c]-mu[c])*iv[c]*bn_gamma[c]+bn_beta[c];
    float q0=bc2[0], q1=bc2[1], q2=bc2[2];
    for (int j=0;j<64;j++){
        float hh = b2[j];
        #pragma unroll
        for (int c=0;c<5;c++) hh += vn[c]*w2[c*64+j];
        hh = fmaxf(hh,0.f);
        q0 += hh*wc2[j*3+0]; q1 += hh*wc2[j*3+1]; q2 += hh*wc2[j*3+2];
    }
    dout[448+t*3+0]=q0; dout[448+t*3+1]=q1; dout[448+t*3+2]=q2;
    float m = fmaxf(q0,fmaxf(q1,q2));
    float e0=__expf(q0-m), e1=__expf(q1-m), e2=__expf(q2-m);
    float inv=1.f/(e0+e1+e2);
    dout[832+t*3+0]=e0*inv; dout[832+t*3+1]=e1*inv; dout[832+t*3+2]=e2*inv;
}

extern "C" void kernel_launch(void* const* d_in, const int* in_sizes, int n_in,
                              void* d_out, int out_size, void* d_ws, size_t ws_size,
                              hipStream_t stream)
{
    const float* x     = (const float*)d_in[0];
    const float* y     = (const float*)d_in[1];
    const float* w11_1 = (const float*)d_in[2];
    const float* b11_1 = (const float*)d_in[3];
    const float* w11_2 = (const float*)d_in[4];
    const float* b11_2 = (const float*)d_in[5];
    const float* w12_1 = (const float*)d_in[6];
    const float* b12_1 = (const float*)d_in[7];
    const float* w12_2 = (const float*)d_in[8];
    const float* b12_2 = (const float*)d_in[9];
    const float* wc1   = (const float*)d_in[10];
    const float* bc1   = (const float*)d_in[11];
    const float* bn_g  = (const float*)d_in[12];
    const float* bn_b  = (const float*)d_in[13];
    const float* w2    = (const float*)d_in[14];
    const float* b2    = (const float*)d_in[15];
    const float* wc2   = (const float*)d_in[16];
    const float* bc2   = (const float*)d_in[17];

    float* ws   = (float*)d_ws;
    float* dout = (float*)d_out;
    float* out_x = ws;
    float* out_y = ws + 1048576;
    float* resx  = ws + 2097152;
    float* resy  = ws + 3145728;
    float* resn  = ws + 4194304;                 // 32768
    float* rawn  = resn + 32768;                 // 32768
    float* mean_part = rawn + 32768;             // 16384
    float* part3 = mean_part + 16384;            // 768 (pad region 3840)
    float* loss_part = part3 + 3840;             // 256
    float* gram  = ws + 4280320;                 // 256*8448 floats
    float* wbuf  = gram + 2162688;               // 128*4224 floats
    unsigned short* resbf = (unsigned short*)gram;   // overlays gram (dead after k2b)
    unsigned short* tgbf  = resbf + 2097152;

    hipLaunchKernelGGL(k1_fused, dim3(NB*4), dim3(256), 0, stream,
        x,y,w11_1,b11_1,w11_2,b11_2,w12_1,b12_1,w12_2,b12_2,
        out_x,out_y,mean_part);
    hipLaunchKernelGGL(k2a_build, dim3(NB*4), dim3(256), 0, stream,
        out_x,out_y,x,y,gram);
    hipLaunchKernelGGL(k2b_solve, dim3(2*NB), dim3(256), 0, stream,
        gram,wbuf);
    hipLaunchKernelGGL(k2c_resid, dim3(NB*4), dim3(256), 0, stream,
        out_x,out_y,x,y,wbuf,resx,resy,resn,rawn,loss_part,resbf,tgbf);
    hipLaunchKernelGGL(k3_renyi, dim3(NB*2*2), dim3(256), 0, stream,
        resbf,tgbf,resn,rawn,part3);
    hipLaunchKernelGGL(k4_final, dim3(1), dim3(64), 0, stream,
        mean_part,part3,loss_part,wc1,bc1,bn_g,bn_b,w2,b2,wc2,bc2,dout);
}

// Round 8
// 88.476 us; speedup vs baseline: 2.6109x; 1.2398x over previous
//
#include <hip/hip_runtime.h>
#include <math.h>

#define NB 64
#define NS 256
#define ND 64
#define NH2 64
#define NH 128
#define GSTRIDE 8448
#define WSTRIDE 4224

// d_out layout (floats):
// 0: out_c[64*3]; 192: rx[64]; 256: ry[64]; 320: ex[64]; 384: ey[64];
// 448: out_c_f[64*3]; 640: prob1[64*3]; 832: prob2[64*3]

#define F4E(v_, e_) ((e_)==0?(v_).x:((e_)==1?(v_).y:((e_)==2?(v_).z:(v_).w)))

typedef __attribute__((ext_vector_type(8))) short bf16x8;
typedef __attribute__((ext_vector_type(4))) float f32x4;

__device__ __forceinline__ unsigned short f2bf(float f){
    union { float f; unsigned int u; } v; v.f = f;
    unsigned int r = v.u + 0x7fffu + ((v.u >> 16) & 1u);
    return (unsigned short)(r >> 16);
}
__device__ __forceinline__ float bf2f(unsigned short h){
    union { unsigned int u; float f; } v; v.u = ((unsigned int)h) << 16;
    return v.f;
}
// split f32 into hi/lo bf16 and store to two LDS planes (scalar)
__device__ __forceinline__ void sw2(unsigned short* ph, unsigned short* pl, int idx, float f){
    unsigned short h = f2bf(f);
    ph[idx] = h;
    pl[idx] = f2bf(f - bf2f(h));
}
// packed pair store (idx must be even)
__device__ __forceinline__ void sw2x2(unsigned short* ph, unsigned short* pl, int idx, float f0, float f1){
    unsigned short h0 = f2bf(f0), h1 = f2bf(f1);
    ushort2 hh; hh.x = h0; hh.y = h1;
    *(ushort2*)(ph + idx) = hh;
    ushort2 ll; ll.x = f2bf(f0 - bf2f(h0)); ll.y = f2bf(f1 - bf2f(h1));
    *(ushort2*)(pl + idx) = ll;
}

#define LD8(P_, row_, kb_) (*(const bf16x8*)((const char*)(P_) + (size_t)(row_)*144 + (kb_)))

// K=64 tile MAC: acc += A[ar..ar+15][0:64] * B[br..br+15][0:64]^T  (hi/lo 3-combo)
__device__ __forceinline__ f32x4 mm64(
    const unsigned short* Ah, const unsigned short* Al,
    const unsigned short* Bh, const unsigned short* Bl,
    int ar, int br, int lrow, int lkb, f32x4 acc)
{
    const int ra = ar + lrow, rb = br + lrow;
    bf16x8 ah0 = LD8(Ah, ra, lkb), ah1 = LD8(Ah, ra, lkb+64);
    bf16x8 al0 = LD8(Al, ra, lkb), al1 = LD8(Al, ra, lkb+64);
    bf16x8 bh0 = LD8(Bh, rb, lkb), bh1 = LD8(Bh, rb, lkb+64);
    bf16x8 bl0 = LD8(Bl, rb, lkb), bl1 = LD8(Bl, rb, lkb+64);
    acc = __builtin_amdgcn_mfma_f32_16x16x32_bf16(ah0, bh0, acc, 0,0,0);
    acc = __builtin_amdgcn_mfma_f32_16x16x32_bf16(ah1, bh1, acc, 0,0,0);
    acc = __builtin_amdgcn_mfma_f32_16x16x32_bf16(ah0, bl0, acc, 0,0,0);
    acc = __builtin_amdgcn_mfma_f32_16x16x32_bf16(ah1, bl1, acc, 0,0,0);
    acc = __builtin_amdgcn_mfma_f32_16x16x32_bf16(al0, bh0, acc, 0,0,0);
    acc = __builtin_amdgcn_mfma_f32_16x16x32_bf16(al1, bh1, acc, 0,0,0);
    return acc;
}

// =================== K1: MFMA bf16-hi/lo fused MLP ===================
__global__ __launch_bounds__(256) void k1_fused(
    const float* __restrict__ x, const float* __restrict__ y,
    const float* __restrict__ w11_1, const float* __restrict__ b11_1,
    const float* __restrict__ w11_2, const float* __restrict__ b11_2,
    const float* __restrict__ w12_1, const float* __restrict__ b12_1,
    const float* __restrict__ w12_2, const float* __restrict__ b12_2,
    float* __restrict__ out_x, float* __restrict__ out_y,
    float* __restrict__ mean_part)
{
    const int b = blockIdx.x >> 2, tile = blockIdx.x & 3;
    const int t = threadIdx.x;
    const int lane = t & 63, wv = t >> 6;
    const int lrow = lane & 15;
    const int lkb  = (lane >> 4) * 16;
    const int row0g = b*NS + tile*64;

    __shared__ unsigned short XYh[9216], XYl[9216];
    __shared__ unsigned short W1h[4608], W1l[4608];
    __shared__ unsigned short W2h[4608], W2l[4608];
    __shared__ unsigned short Hh [9216], Hl [9216];
    __shared__ unsigned short Oh [9216], Ol [9216];
    __shared__ float msum[4*68];

    // ---- P0: stage XY + W1^T + W2^T (packed ushort2 stores) ----
    #pragma unroll
    for (int u=0;u<8;u++){
        int id = t + 256*u;
        int r = id>>4, c0 = (id&15)*4;
        const float* src = (r < 64) ? (x + ((size_t)(row0g + r))*ND)
                                    : (y + ((size_t)(row0g + r - 64))*ND);
        float4 v = *(const float4*)(src + c0);
        sw2x2(XYh, XYl, r*72 + c0,   v.x, v.y);
        sw2x2(XYh, XYl, r*72 + c0+2, v.z, v.w);
    }
    #pragma unroll
    for (int u=0;u<2;u++){
        int id = t + 256*u;                    // 512 row-pair jobs
        int rp = id>>4, c0 = (id&15)*4;
        float4 a0 = *(const float4*)(w11_1 + (size_t)(2*rp  )*64 + c0);
        float4 a1 = *(const float4*)(w11_1 + (size_t)(2*rp+1)*64 + c0);
        float4 b0 = *(const float4*)(w11_2 + (size_t)(2*rp  )*64 + c0);
        float4 b1 = *(const float4*)(w11_2 + (size_t)(2*rp+1)*64 + c0);
        #pragma unroll
        for (int i2=0;i2<4;i2++){
            sw2x2(W1h, W1l, (c0+i2)*72 + 2*rp, F4E(a0,i2), F4E(a1,i2));
            sw2x2(W2h, W2l, (c0+i2)*72 + 2*rp, F4E(b0,i2), F4E(b1,i2));
        }
    }
    __syncthreads();

    // ---- P1: G1  H = relu(XY @ W1 + b1) ----
    #pragma unroll
    for (int it=0; it<2; it++){
        const int ar = 32*wv + 16*it;
        #pragma unroll
        for (int jt=0; jt<4; jt++){
            float bb = b11_1[jt*16 + lrow];
            f32x4 acc = {bb,bb,bb,bb};
            acc = mm64(XYh, XYl, W1h, W1l, ar, jt*16, lrow, lkb, acc);
            #pragma unroll
            for (int e=0;e<4;e++){
                int row = ar + (lane>>4)*4 + e;
                int col = jt*16 + lrow;
                sw2(Hh, Hl, row*72 + col, fmaxf(acc[e], 0.f));
            }
        }
    }
    __syncthreads();

    // ---- P2: stage w12_1^T half0 -> XY region (packed); G2  O = H @ W2 + b2 ----
    #pragma unroll
    for (int u=0;u<4;u++){
        int id = t + 256*u;                    // 1024 row-pair jobs
        int krp = id>>5, c0 = (id&31)*4;
        float4 v0 = *(const float4*)(w12_1 + (size_t)(2*krp  )*NH + c0);
        float4 v1 = *(const float4*)(w12_1 + (size_t)(2*krp+1)*NH + c0);
        #pragma unroll
        for (int i2=0;i2<4;i2++)
            sw2x2(XYh, XYl, (c0+i2)*72 + 2*krp, F4E(v0,i2), F4E(v1,i2));
    }
    #pragma unroll
    for (int it=0; it<2; it++){
        const int ar = 32*wv + 16*it;
        #pragma unroll
        for (int jt=0; jt<4; jt++){
            float bb = b11_2[jt*16 + lrow];
            f32x4 acc = {bb,bb,bb,bb};
            acc = mm64(Hh, Hl, W2h, W2l, ar, jt*16, lrow, lkb, acc);
            #pragma unroll
            for (int e=0;e<4;e++){
                int row = ar + (lane>>4)*4 + e;
                int col = jt*16 + lrow;
                float v = acc[e];
                sw2(Oh, Ol, row*72 + col, v);
                float* dst = (row < 64) ? out_x : out_y;
                dst[((size_t)(row0g + (row & 63)))*NH2 + col] = v;
            }
        }
    }
    __syncthreads();

    // ---- P3: G3 pass0: acc3 += Ox @ w12_1[0:64,:] ----
    f32x4 acc3[8];
    #pragma unroll
    for (int jt=0; jt<8; jt++){
        float bb = b12_1[jt*16 + lrow];
        f32x4 v = {bb,bb,bb,bb};
        acc3[jt] = v;
    }
    #pragma unroll
    for (int jt=0; jt<8; jt++)
        acc3[jt] = mm64(Oh, Ol, XYh, XYl, 16*wv, jt*16, lrow, lkb, acc3[jt]);
    __syncthreads();

    // ---- P4: stage w12_1^T half1 + w12_2^T halves (packed) ----
    #pragma unroll
    for (int u=0;u<4;u++){
        int id = t + 256*u;
        int krp = id>>5, c0 = (id&31)*4;
        float4 v0 = *(const float4*)(w12_1 + (size_t)(64+2*krp  )*NH + c0);
        float4 v1 = *(const float4*)(w12_1 + (size_t)(64+2*krp+1)*NH + c0);
        #pragma unroll
        for (int i2=0;i2<4;i2++)
            sw2x2(XYh, XYl, (c0+i2)*72 + 2*krp, F4E(v0,i2), F4E(v1,i2));
    }
    #pragma unroll
    for (int u=0;u<2;u++){
        int id = t + 256*u;                    // 512 row-pair jobs
        int krp = id>>4, c0 = (id&15)*4;
        float4 h0a = *(const float4*)(w12_2 + (size_t)(2*krp  )*NH2 + c0);
        float4 h0b = *(const float4*)(w12_2 + (size_t)(2*krp+1)*NH2 + c0);
        float4 h1a = *(const float4*)(w12_2 + (size_t)(64+2*krp  )*NH2 + c0);
        float4 h1b = *(const float4*)(w12_2 + (size_t)(64+2*krp+1)*NH2 + c0);
        #pragma unroll
        for (int i2=0;i2<4;i2++){
            sw2x2(W2h, W2l, (c0+i2)*72 + 2*krp, F4E(h0a,i2), F4E(h0b,i2));
            sw2x2(W1h, W1l, (c0+i2)*72 + 2*krp, F4E(h1a,i2), F4E(h1b,i2));
        }
    }
    __syncthreads();

    // ---- P5: G3 pass1 + epi -> H1 ----
    #pragma unroll
    for (int jt=0; jt<8; jt++)
        acc3[jt] = mm64(Oh, Ol, XYh, XYl, 64 + 16*wv, jt*16, lrow, lkb, acc3[jt]);
    #pragma unroll
    for (int jt=0; jt<8; jt++){
        #pragma unroll
        for (int e=0;e<4;e++){
            int row = 16*wv + (lane>>4)*4 + e;
            int col = jt*16 + lrow;
            float v = fmaxf(acc3[jt][e], 0.f);
            int idx = (col < 64) ? (row*72 + col) : ((64+row)*72 + (col-64));
            sw2(Hh, Hl, idx, v);
        }
    }
    __syncthreads();

    // ---- P6: G4 + column sums ----
    {
        f32x4 acc2[4];
        #pragma unroll
        for (int jt=0; jt<4; jt++){
            float bb = b12_2[jt*16 + lrow];
            f32x4 v = {bb,bb,bb,bb};
            acc2[jt] = v;
        }
        #pragma unroll
        for (int jt=0; jt<4; jt++){
            acc2[jt] = mm64(Hh, Hl, W2h, W2l, 16*wv,      jt*16, lrow, lkb, acc2[jt]);
            acc2[jt] = mm64(Hh, Hl, W1h, W1l, 64 + 16*wv, jt*16, lrow, lkb, acc2[jt]);
        }
        #pragma unroll
        for (int jt=0; jt<4; jt++){
            float s = fmaxf(acc2[jt][0],0.f) + fmaxf(acc2[jt][1],0.f)
                    + fmaxf(acc2[jt][2],0.f) + fmaxf(acc2[jt][3],0.f);
            s += __shfl_down(s, 32);
            s += __shfl_down(s, 16);
            if (lane < 16) msum[wv*68 + jt*16 + lane] = s;
        }
    }
    __syncthreads();
    if (t < 64){
        float ss = msum[t] + msum[68+t] + msum[2*68+t] + msum[3*68+t];
        mean_part[((size_t)(b*4+tile))*64 + t] = ss;
    }
}

// =================== K2a: gram partials (unchanged) ===================
__global__ __launch_bounds__(256) void k2a_build(
    const float* __restrict__ fx, const float* __restrict__ fy,
    const float* __restrict__ x, const float* __restrict__ y,
    float* __restrict__ gram)
{
    const int blk = blockIdx.x;
    const int kh = blk & 1, side = (blk>>1)&1, b = blk>>2;
    const float* feat = side ? fy : fx;
    const float* targ = side ? x : y;
    float* g = gram + (size_t)blk*GSTRIDE;
    const int t = threadIdx.x;
    const int ig2 = t & 15, jg2 = t >> 4;
    const int i0 = ig2*4, j0 = jg2*4;
    __shared__ float Zt[64*68], Tt[64*68];
    __shared__ float red[4];

    float accA[4][4], accR[4][4];
    #pragma unroll
    for (int u=0;u<4;u++)
        #pragma unroll
        for (int v=0;v<4;v++){ accA[u][v]=0.f; accR[u][v]=0.f; }
    float szp=0.f, stp=0.f, tsqp=0.f;
    const int cc_ = t & 63, rq = t >> 6;

    for (int sub=0; sub<2; sub++){
        if (sub) __syncthreads();
        const int r0g = b*NS + kh*128 + sub*64;
        #pragma unroll
        for (int u=0;u<4;u++){
            int id = t + 256*u; int r = id>>4, c4 = (id&15)*4;
            *(float4*)(Zt + r*68 + c4) = *(const float4*)(feat + ((size_t)(r0g+r))*NH2 + c4);
            *(float4*)(Tt + r*68 + c4) = *(const float4*)(targ + ((size_t)(r0g+r))*ND + c4);
        }
        __syncthreads();
        #pragma unroll
        for (int ch=0; ch<16; ch++){
            const int r0 = ch*4;
            float4 zi[4], zj[4], tj[4];
            #pragma unroll
            for (int c=0;c<4;c++){
                zi[c] = *(const float4*)(Zt + (r0+c)*68 + i0);
                zj[c] = *(const float4*)(Zt + (r0+c)*68 + j0);
                tj[c] = *(const float4*)(Tt + (r0+c)*68 + j0);
            }
            #pragma unroll
            for (int c=0;c<4;c++){
                #pragma unroll
                for (int u=0;u<4;u++){
                    const float zv = F4E(zi[c], u);
                    const float4 a4 = zj[c], r4 = tj[c];
                    accA[u][0] += zv*a4.x; accA[u][1] += zv*a4.y;
                    accA[u][2] += zv*a4.z; accA[u][3] += zv*a4.w;
                    accR[u][0] += zv*r4.x; accR[u][1] += zv*r4.y;
                    accR[u][2] += zv*r4.z; accR[u][3] += zv*r4.w;
                }
            }
        }
        #pragma unroll
        for (int rr=0; rr<16; rr++){
            int r = rq*16 + rr;
            szp += Zt[r*68 + cc_];
            float tv = Tt[r*68 + cc_];
            stp += tv; tsqp += tv*tv;
        }
    }
    #pragma unroll
    for (int u=0;u<4;u++){
        *(float4*)(g + (i0+u)*64 + j0) = make_float4(accA[u][0],accA[u][1],accA[u][2],accA[u][3]);
        *(float4*)(g + 4096 + (i0+u)*64 + j0) = make_float4(accR[u][0],accR[u][1],accR[u][2],accR[u][3]);
    }
    __syncthreads();
    Zt[rq*68 + cc_] = szp;
    Tt[rq*68 + cc_] = stp;
    float tq = tsqp;
    #pragma unroll
    for (int off=32; off; off>>=1) tq += __shfl_down(tq, off);
    if ((t&63)==0) red[t>>6] = tq;
    __syncthreads();
    if (t < 64){
        g[8192+t] = Zt[t] + Zt[68+t] + Zt[2*68+t] + Zt[3*68+t];
        g[8256+t] = Tt[t] + Tt[68+t] + Tt[2*68+t] + Tt[3*68+t];
    }
    if (t==0) g[8320] = red[0]+red[1]+red[2]+red[3];
}

// =================== K2b: Neumann/Horner solve via MFMA ===================
// A = I + G, trace(G)<=1 PSD -> spec(A) in [1,2]. A = 1.5(I+E), ||E||<=1/3.
// W = (I+E)^-1 R'' via 12 Horner steps W <- R'' - E*W, R''=R/1.5.
__global__ __launch_bounds__(256) void k2b_solve(
    const float* __restrict__ gram, float* __restrict__ wbuf)
{
    const int bs = blockIdx.x;
    const float* g0 = gram + (size_t)(bs*2+0)*GSTRIDE;
    const float* g1 = gram + (size_t)(bs*2+1)*GSTRIDE;
    float* wb = wbuf + (size_t)bs*WSTRIDE;
    const int t = threadIdx.x;
    const int lane = t & 63, wv = t >> 6;
    const int lrow = lane & 15;
    const int lkb  = (lane >> 4) * 16;

    __shared__ float Rf[64*68];                 // R'' (f32)
    __shared__ float Wf[64*68];                 // raw A, then final W (f32)
    __shared__ unsigned short Eh[4608], El[4608];
    __shared__ unsigned short Wth[2][4608], Wtl[2][4608];   // W^T planes, dbuf
    __shared__ float szs[64], sts[64];
    __shared__ float sc[8];

    #pragma unroll
    for (int u=0;u<16;u++){
        int id = t + 256*u; int r = id>>6, c = id&63;
        Wf[r*68+c] = g0[id] + g1[id];                      // raw A'
        Rf[r*68+c] = g0[4096+id] + g1[4096+id];            // raw R'
    }
    if (t<64){ szs[t] = g0[8192+t]+g1[8192+t]; sts[t] = g0[8256+t]+g1[8256+t]; }
    if (t==0) sc[1] = g0[8320]+g1[8320];
    __syncthreads();
    if (t<64){
        float dg = Wf[t*68+t];
        #pragma unroll
        for (int off=32; off; off>>=1) dg += __shfl_down(dg, off);
        if (t==0){ sc[0] = 1.0f/sqrtf(dg); sc[1] = 1.0f/sqrtf(sc[1]); }
    }
    __syncthreads();
    const float zinv = sc[0], tinv = sc[1];
    const float z2 = zinv*zinv, zt = zinv*tinv, inv256 = 1.0f/256.0f;
    const float i23 = 2.0f/3.0f;   // 1/1.5
    const int i = t>>2, qd = t&3;
    // center/scale -> E planes (bf16 hi/lo) + R'' (f32) + initial Wt=R''^T planes
    {
        const float szi = szs[i];
        #pragma unroll
        for (int q=0;q<4;q++){
            const int j = qd*16 + q*4;
            float4 a4 = *(const float4*)(Wf + i*68 + j);
            float4 sj = *(const float4*)(szs + j);
            float v0 = z2*(a4.x - szi*sj.x*inv256);
            float v1 = z2*(a4.y - szi*sj.y*inv256);
            float v2 = z2*(a4.z - szi*sj.z*inv256);
            float v3 = z2*(a4.w - szi*sj.w*inv256);
            if (i == j)   v0 += 1.f;
            else if (i == j+1) v1 += 1.f;
            else if (i == j+2) v2 += 1.f;
            else if (i == j+3) v3 += 1.f;
            // E = A/1.5 - I
            float e0 = v0*i23 - ((i==j  ) ? 1.f : 0.f);
            float e1 = v1*i23 - ((i==j+1) ? 1.f : 0.f);
            float e2 = v2*i23 - ((i==j+2) ? 1.f : 0.f);
            float e3 = v3*i23 - ((i==j+3) ? 1.f : 0.f);
            sw2x2(Eh, El, i*72 + j,   e0, e1);
            sw2x2(Eh, El, i*72 + j+2, e2, e3);
            float4 rv = *(float4*)(Rf + i*68 + j);
            float4 t4 = *(const float4*)(sts + j);
            float r0 = zt*(rv.x - szi*t4.x*inv256)*i23;
            float r1 = zt*(rv.y - szi*t4.y*inv256)*i23;
            float r2 = zt*(rv.z - szi*t4.z*inv256)*i23;
            float r3 = zt*(rv.w - szi*t4.w*inv256)*i23;
            *(float4*)(Rf + i*68 + j) = make_float4(r0,r1,r2,r3);
            sw2(Wth[0], Wtl[0], (j  )*72 + i, r0);
            sw2(Wth[0], Wtl[0], (j+1)*72 + i, r1);
            sw2(Wth[0], Wtl[0], (j+2)*72 + i, r2);
            sw2(Wth[0], Wtl[0], (j+3)*72 + i, r3);
        }
    }
    __syncthreads();

    // Horner: W <- R'' - E*W  (12 iterations, dbuf planes, 1 barrier each)
    int cur = 0;
    for (int n=0; n<12; n++){
        f32x4 acc[4];
        #pragma unroll
        for (int jt=0; jt<4; jt++){
            f32x4 zz = {0.f,0.f,0.f,0.f};
            acc[jt] = mm64(Eh, El, Wth[cur], Wtl[cur], 16*wv, jt*16, lrow, lkb, zz);
        }
        const int gi0 = 16*wv + (lane>>4)*4;
        #pragma unroll
        for (int jt=0; jt<4; jt++){
            const int gj = jt*16 + lrow;
            float w0 = Rf[(gi0  )*68 + gj] - acc[jt][0];
            float w1 = Rf[(gi0+1)*68 + gj] - acc[jt][1];
            float w2 = Rf[(gi0+2)*68 + gj] - acc[jt][2];
            float w3 = Rf[(gi0+3)*68 + gj] - acc[jt][3];
            sw2x2(Wth[cur^1], Wtl[cur^1], gj*72 + gi0,   w0, w1);
            sw2x2(Wth[cur^1], Wtl[cur^1], gj*72 + gi0+2, w2, w3);
            if (n == 11){
                Wf[(gi0  )*68 + gj] = w0;  wb[(gi0  )*64 + gj] = w0;
                Wf[(gi0+1)*68 + gj] = w1;  wb[(gi0+1)*64 + gj] = w1;
                Wf[(gi0+2)*68 + gj] = w2;  wb[(gi0+2)*64 + gj] = w2;
                Wf[(gi0+3)*68 + gj] = w3;  wb[(gi0+3)*64 + gj] = w3;
            }
        }
        cur ^= 1;
        __syncthreads();
    }

    if (t < 64){
        float s = 0.f;
        for (int i2=0; i2<64; i2++) s += szs[i2]*Wf[i2*68 + t];
        wb[4096+t] = (tinv*sts[t] - zinv*s) * inv256;
    }
    if (t==0){ wb[4160] = zinv; wb[4161] = tinv; }
}

// =================== K2c: residuals (unchanged) ===================
__global__ __launch_bounds__(256) void k2c_resid(
    const float* __restrict__ fx, const float* __restrict__ fy,
    const float* __restrict__ x, const float* __restrict__ y,
    const float* __restrict__ wbuf,
    float* __restrict__ resx, float* __restrict__ resy,
    float* __restrict__ resn, float* __restrict__ rawn,
    float* __restrict__ loss_part,
    unsigned short* __restrict__ resbf, unsigned short* __restrict__ tgbf)
{
    const int blk = blockIdx.x;
    const int h = blk & 1, side = (blk>>1)&1, b = blk>>2;
    const float* feat = side ? fy : fx;
    const float* targ = side ? x : y;
    float* res = side ? resy : resx;
    const float* wb = wbuf + (size_t)(b*2+side)*WSTRIDE;
    const int t = threadIdx.x;
    const int ig = t>>4, jg = t&15, d0 = jg*4;
    const int row0 = b*NS + h*128;
    __shared__ float sZ[128*68];
    __shared__ float sW[64*68];
    __shared__ float c0s[64];
    __shared__ float rnp[128*17];
    __shared__ float rqp[128*17];
    __shared__ float red[4];

    #pragma unroll
    for (int u=0;u<8;u++){
        int id = t + 256*u; int r = id>>4, c4 = (id&15)*4;
        *(float4*)(sZ + r*68 + c4) = *(const float4*)(feat + ((size_t)(row0+r))*NH2 + c4);
    }
    #pragma unroll
    for (int u=0;u<4;u++){
        int id = t + 256*u; int r = id>>4, c4 = (id&15)*4;
        *(float4*)(sW + r*68 + c4) = *(const float4*)(wb + (size_t)r*64 + c4);
    }
    if (t<64) c0s[t] = wb[4096+t];
    const float zinv = wb[4160], tinv = wb[4161];
    __syncthreads();

    float acc[8][4];
    #pragma unroll
    for (int u=0;u<8;u++){ acc[u][0]=0.f; acc[u][1]=0.f; acc[u][2]=0.f; acc[u][3]=0.f; }
    #pragma unroll
    for (int ch=0; ch<16; ch++){
        const int k0 = ch*4;
        float4 wr[4];
        #pragma unroll
        for (int c=0;c<4;c++) wr[c] = *(const float4*)(sW + (k0+c)*68 + d0);
        #pragma unroll
        for (int u=0;u<8;u++){
            float4 zv = *(const float4*)(sZ + (ig+16*u)*68 + k0);
            #pragma unroll
            for (int c=0;c<4;c++){
                const float zc = F4E(zv, c);
                const float4 w4 = wr[c];
                acc[u][0] += zc*w4.x; acc[u][1] += zc*w4.y;
                acc[u][2] += zc*w4.z; acc[u][3] += zc*w4.w;
            }
        }
    }
    const float4 c04 = *(const float4*)(c0s + d0);
    #pragma unroll
    for (int u=0;u<8;u++){
        const int r = ig + 16*u;
        const int gr = row0 + r;
        float4 q = *(const float4*)(targ + (size_t)gr*ND + d0);
        float4 rr;
        rr.x = tinv*q.x - zinv*acc[u][0] - c04.x;
        rr.y = tinv*q.y - zinv*acc[u][1] - c04.y;
        rr.z = tinv*q.z - zinv*acc[u][2] - c04.z;
        rr.w = tinv*q.w - zinv*acc[u][3] - c04.w;
        *(float4*)(res + (size_t)gr*ND + d0) = rr;
        *(ushort4*)(resbf + ((size_t)side*NB*NS + gr)*64 + d0) =
            make_ushort4(f2bf(rr.x), f2bf(rr.y), f2bf(rr.z), f2bf(rr.w));
        *(ushort4*)(tgbf + ((size_t)side*NB*NS + gr)*64 + d0) =
            make_ushort4(f2bf(q.x), f2bf(q.y), f2bf(q.z), f2bf(q.w));
        rnp[r*17 + jg] = rr.x*rr.x + rr.y*rr.y + rr.z*rr.z + rr.w*rr.w;
        rqp[r*17 + jg] = q.x*q.x + q.y*q.y + q.z*q.z + q.w*q.w;
    }
    __syncthreads();
    float myrn = 0.f;
    if (t < 128){
        float rn=0.f, rq=0.f;
        #pragma unroll
        for (int g2=0; g2<16; g2++){ rn += rnp[t*17+g2]; rq += rqp[t*17+g2]; }
        resn[(size_t)(side*NB+b)*NS + h*128 + t] = rn;
        rawn[(size_t)(side*NB+b)*NS + h*128 + t] = rq;
        myrn = rn;
    }
    float l = myrn;
    #pragma unroll
    for (int off=32; off; off>>=1) l += __shfl_down(l, off);
    if ((t&63)==0) red[t>>6] = l;
    __syncthreads();
    if (t==0) loss_part[blk] = red[0]+red[1]+red[2]+red[3];
}

// =================== K3: Renyi-2 Grams via bf16 MFMA (unchanged) ===================
__global__ __launch_bounds__(256) void k3_renyi(
    const unsigned short* __restrict__ resbf, const unsigned short* __restrict__ tgbf,
    const float* __restrict__ resn, const float* __restrict__ rawn,
    float* __restrict__ part3)
{
    const int blk = blockIdx.x;
    const int jh = blk & 1;
    const int b = (blk >> 1) & (NB-1);
    const int side = (blk >> 1) >> 6;
    const unsigned short* Am = resbf + ((size_t)side*NB*NS + (size_t)b*NS)*64;
    const unsigned short* Bm = tgbf  + ((size_t)(1-side)*NB*NS + (size_t)b*NS)*64;
    const float* nA = resn + (size_t)(side*NB+b)*NS;
    const float* nB = rawn + (size_t)((1-side)*NB+b)*NS;
    const int t = threadIdx.x;
    const int lane = t & 63, wv = t >> 6;

    __shared__ unsigned short Abf[256*72];
    __shared__ unsigned short Bbf[256*72];
    __shared__ float nAs[256], nBs[256];
    __shared__ float red[4][3];

    #pragma unroll
    for (int u=0;u<8;u++){
        int id = t + 256*u;
        int r = id>>3, c = id&7;
        *(float4*)((char*)Abf + r*144 + c*16) = *(const float4*)(Am + (size_t)r*64 + c*8);
        *(float4*)((char*)Bbf + r*144 + c*16) = *(const float4*)(Bm + (size_t)r*64 + c*8);
    }
    nAs[t] = nA[t];
    nBs[t] = nB[t];
    __syncthreads();

    const int lrow = lane & 15;
    const int lkb  = (lane >> 4) * 16;
    const char* pA = (const char*)Abf;
    const char* pB = (const char*)Bbf;
    const f32x4 zero4 = {0.f, 0.f, 0.f, 0.f};
    const float CEXP = -2.8853900817779268f;

    float Sa=0.f, Sb=0.f, Sab=0.f;
    #pragma unroll
    for (int it=0; it<4; it++){
        const int i0 = wv*64 + it*16;
        const int arow = i0 + lrow;
        bf16x8 aA0 = *(const bf16x8*)(pA + arow*144 + lkb);
        bf16x8 aA1 = *(const bf16x8*)(pA + arow*144 + lkb + 64);
        bf16x8 aB0 = *(const bf16x8*)(pB + arow*144 + lkb);
        bf16x8 aB1 = *(const bf16x8*)(pB + arow*144 + lkb + 64);
        float nAi[4], nBi[4];
        #pragma unroll
        for (int e=0;e<4;e++){
            int gi = i0 + (lane>>4)*4 + e;
            nAi[e] = nAs[gi]; nBi[e] = nBs[gi];
        }
        #pragma unroll
        for (int jt=0; jt<8; jt++){
            const int j0 = jh*128 + jt*16;
            const int brow = j0 + lrow;
            bf16x8 bA0 = *(const bf16x8*)(pA + brow*144 + lkb);
            bf16x8 bA1 = *(const bf16x8*)(pA + brow*144 + lkb + 64);
            bf16x8 bB0 = *(const bf16x8*)(pB + brow*144 + lkb);
            bf16x8 bB1 = *(const bf16x8*)(pB + brow*144 + lkb + 64);
            f32x4 cA = __builtin_amdgcn_mfma_f32_16x16x32_bf16(aA0, bA0, zero4, 0, 0, 0);
            cA = __builtin_amdgcn_mfma_f32_16x16x32_bf16(aA1, bA1, cA, 0, 0, 0);
            f32x4 cB = __builtin_amdgcn_mfma_f32_16x16x32_bf16(aB0, bB0, zero4, 0, 0, 0);
            cB = __builtin_amdgcn_mfma_f32_16x16x32_bf16(aB1, bB1, cB, 0, 0, 0);
            const int gj = j0 + lrow;
            const float nAj = nAs[gj], nBj = nBs[gj];
            #pragma unroll
            for (int e=0;e<4;e++){
                const int gi = i0 + (lane>>4)*4 + e;
                const float dda = (gi==gj) ? 0.f : (nAi[e] + nAj - 2.f*cA[e]);
                const float ddb = (gi==gj) ? 0.f : (nBi[e] + nBj - 2.f*cB[e]);
                const float ka2 = exp2f(CEXP*dda);
                const float kb2 = exp2f(CEXP*ddb);
                Sa += ka2; Sb += kb2; Sab += ka2*kb2;
            }
        }
    }
    #pragma unroll
    for (int off=32; off; off>>=1){
        Sa += __shfl_down(Sa,off); Sb += __shfl_down(Sb,off); Sab += __shfl_down(Sab,off);
    }
    if (lane==0){ red[wv][0]=Sa; red[wv][1]=Sb; red[wv][2]=Sab; }
    __syncthreads();
    if (t==0){
        float* o = part3 + (size_t)blk*3;
        o[0] = red[0][0]+red[1][0]+red[2][0]+red[3][0];
        o[1] = red[0][1]+red[1][1]+red[2][1]+red[3][1];
        o[2] = red[0][2]+red[1][2]+red[2][2]+red[3][2];
    }
}

// =================== K4 (unchanged) ===================
__global__ __launch_bounds__(64) void k4_final(
    const float* __restrict__ mean_part, const float* __restrict__ part3,
    const float* __restrict__ loss_part,
    const float* __restrict__ wc1, const float* __restrict__ bc1,
    const float* __restrict__ bn_gamma, const float* __restrict__ bn_beta,
    const float* __restrict__ w2, const float* __restrict__ b2,
    const float* __restrict__ wc2, const float* __restrict__ bc2,
    float* __restrict__ dout)
{
    const int t = threadIdx.x;
    __shared__ float ic[64][5];
    __shared__ float mu[5], iv[5];

    dout[192+t] = loss_part[4*t+0] + loss_part[4*t+1];
    dout[256+t] = loss_part[4*t+2] + loss_part[4*t+3];

    float o0 = bc1[0], o1 = bc1[1], o2 = bc1[2];
    for (int c=0;c<64;c++){
        float mv = mean_part[(t*4+0)*64+c] + mean_part[(t*4+1)*64+c]
                 + mean_part[(t*4+2)*64+c] + mean_part[(t*4+3)*64+c];
        mv *= (1.0f/256.0f);
        o0 += mv*wc1[c*3+0]; o1 += mv*wc1[c*3+1]; o2 += mv*wc1[c*3+2];
    }
    dout[t*3+0]=o0; dout[t*3+1]=o1; dout[t*3+2]=o2;
    {
        float m = fmaxf(o0,fmaxf(o1,o2));
        float e0=__expf(o0-m), e1=__expf(o1-m), e2=__expf(o2-m);
        float inv = 1.f/(e0+e1+e2);
        dout[640+t*3+0]=e0*inv; dout[640+t*3+1]=e1*inv; dout[640+t*3+2]=e2*inv;
    }
    float exy[2];
    #pragma unroll
    for (int side=0; side<2; side++){
        const float* pp = part3 + (size_t)((side*NB + t)*2)*3;
        float Sa = pp[0]+pp[3];
        float Sb = pp[1]+pp[4];
        float Sab= pp[2]+pp[5];
        float Hx  = 16.f - log2f(Sa);
        float Hy  = 16.f - log2f(Sb);
        float Hxy = 16.f - log2f(Sab);
        float mi = (Hx + Hy - Hxy) / fmaxf(Hx, Hy);
        dout[(side?384:320)+t] = mi;
        exy[side] = mi;
    }
    ic[t][0]=o0; ic[t][1]=o1; ic[t][2]=o2; ic[t][3]=exy[0]; ic[t][4]=exy[1];
    __syncthreads();
    if (t<5){
        float m=0.f;
        for (int bb=0;bb<64;bb++) m += ic[bb][t];
        m *= (1.f/64.f);
        float v=0.f;
        for (int bb=0;bb<64;bb++){ float d=ic[bb][t]-m; v+=d*d; }
        v *= (1.f/64.f);
        mu[t]=m; iv[t]=1.f/sqrtf(v+1e-5f);
    }
    __syncthreads();
    float vn[5];
    #pragma unroll
    for (int c=0;c<5;c++) vn[c] = (ic[t][c]-mu[c])*iv[c]*bn_gamma[c]+bn_beta[c];
    float q0=bc2[0], q1=bc2[1], q2=bc2[2];
    for (int j=0;j<64;j++){
        float hh = b2[j];
        #pragma unroll
        for (int c=0;c<5;c++) hh += vn[c]*w2[c*64+j];
        hh = fmaxf(hh,0.f);
        q0 += hh*wc2[j*3+0]; q1 += hh*wc2[j*3+1]; q2 += hh*wc2[j*3+2];
    }
    dout[448+t*3+0]=q0; dout[448+t*3+1]=q1; dout[448+t*3+2]=q2;
    float m = fmaxf(q0,fmaxf(q1,q2));
    float e0=__expf(q0-m), e1=__expf(q1-m), e2=__expf(q2-m);
    float inv=1.f/(e0+e1+e2);
    dout[832+t*3+0]=e0*inv; dout[832+t*3+1]=e1*inv; dout[832+t*3+2]=e2*inv;
}

extern "C" void kernel_launch(void* const* d_in, const int* in_sizes, int n_in,
                              void* d_out, int out_size, void* d_ws, size_t ws_size,
                              hipStream_t stream)
{
    const float* x     = (const float*)d_in[0];
    const float* y     = (const float*)d_in[1];
    const float* w11_1 = (const float*)d_in[2];
    const float* b11_1 = (const float*)d_in[3];
    const float* w11_2 = (const float*)d_in[4];
    const float* b11_2 = (const float*)d_in[5];
    const float* w12_1 = (const float*)d_in[6];
    const float* b12_1 = (const float*)d_in[7];
    const float* w12_2 = (const float*)d_in[8];
    const float* b12_2 = (const float*)d_in[9];
    const float* wc1   = (const float*)d_in[10];
    const float* bc1   = (const float*)d_in[11];
    const float* bn_g  = (const float*)d_in[12];
    const float* bn_b  = (const float*)d_in[13];
    const float* w2    = (const float*)d_in[14];
    const float* b2    = (const float*)d_in[15];
    const float* wc2   = (const float*)d_in[16];
    const float* bc2   = (const float*)d_in[17];

    float* ws   = (float*)d_ws;
    float* dout = (float*)d_out;
    float* out_x = ws;
    float* out_y = ws + 1048576;
    float* resx  = ws + 2097152;
    float* resy  = ws + 3145728;
    float* resn  = ws + 4194304;                 // 32768
    float* rawn  = resn + 32768;                 // 32768
    float* mean_part = rawn + 32768;             // 16384
    float* part3 = mean_part + 16384;            // 768 (pad region 3840)
    float* loss_part = part3 + 3840;             // 256
    float* gram  = ws + 4280320;                 // 256*8448 floats
    float* wbuf  = gram + 2162688;               // 128*4224 floats
    unsigned short* resbf = (unsigned short*)gram;   // overlays gram (dead after k2b)
    unsigned short* tgbf  = resbf + 2097152;

    hipLaunchKernelGGL(k1_fused, dim3(NB*4), dim3(256), 0, stream,
        x,y,w11_1,b11_1,w11_2,b11_2,w12_1,b12_1,w12_2,b12_2,
        out_x,out_y,mean_part);
    hipLaunchKernelGGL(k2a_build, dim3(NB*4), dim3(256), 0, stream,
        out_x,out_y,x,y,gram);
    hipLaunchKernelGGL(k2b_solve, dim3(2*NB), dim3(256), 0, stream,
        gram,wbuf);
    hipLaunchKernelGGL(k2c_resid, dim3(NB*4), dim3(256), 0, stream,
        out_x,out_y,x,y,wbuf,resx,resy,resn,rawn,loss_part,resbf,tgbf);
    hipLaunchKernelGGL(k3_renyi, dim3(NB*2*2), dim3(256), 0, stream,
        resbf,tgbf,resn,rawn,part3);
    hipLaunchKernelGGL(k4_final, dim3(1), dim3(64), 0, stream,
        mean_part,part3,loss_part,wc1,bc1,bn_g,bn_b,w2,b2,wc2,bc2,dout);
}

// Round 9
// 85.251 us; speedup vs baseline: 2.7096x; 1.0378x over previous
//
#include <hip/hip_runtime.h>
#include <math.h>

#define NB 64
#define NS 256
#define ND 64
#define NH2 64
#define NH 128
#define GSTRIDE 8448
#define WSTRIDE 4224

// d_out layout (floats):
// 0: out_c[64*3]; 192: rx[64]; 256: ry[64]; 320: ex[64]; 384: ey[64];
// 448: out_c_f[64*3]; 640: prob1[64*3]; 832: prob2[64*3]

#define F4E(v_, e_) ((e_)==0?(v_).x:((e_)==1?(v_).y:((e_)==2?(v_).z:(v_).w)))

typedef __attribute__((ext_vector_type(8))) short bf16x8;
typedef __attribute__((ext_vector_type(4))) float f32x4;

__device__ __forceinline__ unsigned short f2bf(float f){
    union { float f; unsigned int u; } v; v.f = f;
    unsigned int r = v.u + 0x7fffu + ((v.u >> 16) & 1u);
    return (unsigned short)(r >> 16);
}
__device__ __forceinline__ float bf2f(unsigned short h){
    union { unsigned int u; float f; } v; v.u = ((unsigned int)h) << 16;
    return v.f;
}
__device__ __forceinline__ void sw2(unsigned short* ph, unsigned short* pl, int idx, float f){
    unsigned short h = f2bf(f);
    ph[idx] = h;
    pl[idx] = f2bf(f - bf2f(h));
}
__device__ __forceinline__ void sw2x2(unsigned short* ph, unsigned short* pl, int idx, float f0, float f1){
    unsigned short h0 = f2bf(f0), h1 = f2bf(f1);
    ushort2 hh; hh.x = h0; hh.y = h1;
    *(ushort2*)(ph + idx) = hh;
    ushort2 ll; ll.x = f2bf(f0 - bf2f(h0)); ll.y = f2bf(f1 - bf2f(h1));
    *(ushort2*)(pl + idx) = ll;
}

#define LD8(P_, row_, kb_) (*(const bf16x8*)((const char*)(P_) + (size_t)(row_)*144 + (kb_)))

// K=64 tile MAC: acc += A[ar..ar+15][0:64] * B[br..br+15][0:64]^T  (hi/lo 3-combo)
__device__ __forceinline__ f32x4 mm64(
    const unsigned short* Ah, const unsigned short* Al,
    const unsigned short* Bh, const unsigned short* Bl,
    int ar, int br, int lrow, int lkb, f32x4 acc)
{
    const int ra = ar + lrow, rb = br + lrow;
    bf16x8 ah0 = LD8(Ah, ra, lkb), ah1 = LD8(Ah, ra, lkb+64);
    bf16x8 al0 = LD8(Al, ra, lkb), al1 = LD8(Al, ra, lkb+64);
    bf16x8 bh0 = LD8(Bh, rb, lkb), bh1 = LD8(Bh, rb, lkb+64);
    bf16x8 bl0 = LD8(Bl, rb, lkb), bl1 = LD8(Bl, rb, lkb+64);
    acc = __builtin_amdgcn_mfma_f32_16x16x32_bf16(ah0, bh0, acc, 0,0,0);
    acc = __builtin_amdgcn_mfma_f32_16x16x32_bf16(ah1, bh1, acc, 0,0,0);
    acc = __builtin_amdgcn_mfma_f32_16x16x32_bf16(ah0, bl0, acc, 0,0,0);
    acc = __builtin_amdgcn_mfma_f32_16x16x32_bf16(ah1, bl1, acc, 0,0,0);
    acc = __builtin_amdgcn_mfma_f32_16x16x32_bf16(al0, bh0, acc, 0,0,0);
    acc = __builtin_amdgcn_mfma_f32_16x16x32_bf16(al1, bh1, acc, 0,0,0);
    return acc;
}

// =================== K1: MFMA bf16-hi/lo fused MLP (unchanged) ===================
__global__ __launch_bounds__(256) void k1_fused(
    const float* __restrict__ x, const float* __restrict__ y,
    const float* __restrict__ w11_1, const float* __restrict__ b11_1,
    const float* __restrict__ w11_2, const float* __restrict__ b11_2,
    const float* __restrict__ w12_1, const float* __restrict__ b12_1,
    const float* __restrict__ w12_2, const float* __restrict__ b12_2,
    float* __restrict__ out_x, float* __restrict__ out_y,
    float* __restrict__ mean_part)
{
    const int b = blockIdx.x >> 2, tile = blockIdx.x & 3;
    const int t = threadIdx.x;
    const int lane = t & 63, wv = t >> 6;
    const int lrow = lane & 15;
    const int lkb  = (lane >> 4) * 16;
    const int row0g = b*NS + tile*64;

    __shared__ unsigned short XYh[9216], XYl[9216];
    __shared__ unsigned short W1h[4608], W1l[4608];
    __shared__ unsigned short W2h[4608], W2l[4608];
    __shared__ unsigned short Hh [9216], Hl [9216];
    __shared__ unsigned short Oh [9216], Ol [9216];
    __shared__ float msum[4*68];

    #pragma unroll
    for (int u=0;u<8;u++){
        int id = t + 256*u;
        int r = id>>4, c0 = (id&15)*4;
        const float* src = (r < 64) ? (x + ((size_t)(row0g + r))*ND)
                                    : (y + ((size_t)(row0g + r - 64))*ND);
        float4 v = *(const float4*)(src + c0);
        sw2x2(XYh, XYl, r*72 + c0,   v.x, v.y);
        sw2x2(XYh, XYl, r*72 + c0+2, v.z, v.w);
    }
    #pragma unroll
    for (int u=0;u<2;u++){
        int id = t + 256*u;
        int rp = id>>4, c0 = (id&15)*4;
        float4 a0 = *(const float4*)(w11_1 + (size_t)(2*rp  )*64 + c0);
        float4 a1 = *(const float4*)(w11_1 + (size_t)(2*rp+1)*64 + c0);
        float4 b0 = *(const float4*)(w11_2 + (size_t)(2*rp  )*64 + c0);
        float4 b1 = *(const float4*)(w11_2 + (size_t)(2*rp+1)*64 + c0);
        #pragma unroll
        for (int i2=0;i2<4;i2++){
            sw2x2(W1h, W1l, (c0+i2)*72 + 2*rp, F4E(a0,i2), F4E(a1,i2));
            sw2x2(W2h, W2l, (c0+i2)*72 + 2*rp, F4E(b0,i2), F4E(b1,i2));
        }
    }
    __syncthreads();

    #pragma unroll
    for (int it=0; it<2; it++){
        const int ar = 32*wv + 16*it;
        #pragma unroll
        for (int jt=0; jt<4; jt++){
            float bb = b11_1[jt*16 + lrow];
            f32x4 acc = {bb,bb,bb,bb};
            acc = mm64(XYh, XYl, W1h, W1l, ar, jt*16, lrow, lkb, acc);
            #pragma unroll
            for (int e=0;e<4;e++){
                int row = ar + (lane>>4)*4 + e;
                int col = jt*16 + lrow;
                sw2(Hh, Hl, row*72 + col, fmaxf(acc[e], 0.f));
            }
        }
    }
    __syncthreads();

    #pragma unroll
    for (int u=0;u<4;u++){
        int id = t + 256*u;
        int krp = id>>5, c0 = (id&31)*4;
        float4 v0 = *(const float4*)(w12_1 + (size_t)(2*krp  )*NH + c0);
        float4 v1 = *(const float4*)(w12_1 + (size_t)(2*krp+1)*NH + c0);
        #pragma unroll
        for (int i2=0;i2<4;i2++)
            sw2x2(XYh, XYl, (c0+i2)*72 + 2*krp, F4E(v0,i2), F4E(v1,i2));
    }
    #pragma unroll
    for (int it=0; it<2; it++){
        const int ar = 32*wv + 16*it;
        #pragma unroll
        for (int jt=0; jt<4; jt++){
            float bb = b11_2[jt*16 + lrow];
            f32x4 acc = {bb,bb,bb,bb};
            acc = mm64(Hh, Hl, W2h, W2l, ar, jt*16, lrow, lkb, acc);
            #pragma unroll
            for (int e=0;e<4;e++){
                int row = ar + (lane>>4)*4 + e;
                int col = jt*16 + lrow;
                float v = acc[e];
                sw2(Oh, Ol, row*72 + col, v);
                float* dst = (row < 64) ? out_x : out_y;
                dst[((size_t)(row0g + (row & 63)))*NH2 + col] = v;
            }
        }
    }
    __syncthreads();

    f32x4 acc3[8];
    #pragma unroll
    for (int jt=0; jt<8; jt++){
        float bb = b12_1[jt*16 + lrow];
        f32x4 v = {bb,bb,bb,bb};
        acc3[jt] = v;
    }
    #pragma unroll
    for (int jt=0; jt<8; jt++)
        acc3[jt] = mm64(Oh, Ol, XYh, XYl, 16*wv, jt*16, lrow, lkb, acc3[jt]);
    __syncthreads();

    #pragma unroll
    for (int u=0;u<4;u++){
        int id = t + 256*u;
        int krp = id>>5, c0 = (id&31)*4;
        float4 v0 = *(const float4*)(w12_1 + (size_t)(64+2*krp  )*NH + c0);
        float4 v1 = *(const float4*)(w12_1 + (size_t)(64+2*krp+1)*NH + c0);
        #pragma unroll
        for (int i2=0;i2<4;i2++)
            sw2x2(XYh, XYl, (c0+i2)*72 + 2*krp, F4E(v0,i2), F4E(v1,i2));
    }
    #pragma unroll
    for (int u=0;u<2;u++){
        int id = t + 256*u;
        int krp = id>>4, c0 = (id&15)*4;
        float4 h0a = *(const float4*)(w12_2 + (size_t)(2*krp  )*NH2 + c0);
        float4 h0b = *(const float4*)(w12_2 + (size_t)(2*krp+1)*NH2 + c0);
        float4 h1a = *(const float4*)(w12_2 + (size_t)(64+2*krp  )*NH2 + c0);
        float4 h1b = *(const float4*)(w12_2 + (size_t)(64+2*krp+1)*NH2 + c0);
        #pragma unroll
        for (int i2=0;i2<4;i2++){
            sw2x2(W2h, W2l, (c0+i2)*72 + 2*krp, F4E(h0a,i2), F4E(h0b,i2));
            sw2x2(W1h, W1l, (c0+i2)*72 + 2*krp, F4E(h1a,i2), F4E(h1b,i2));
        }
    }
    __syncthreads();

    #pragma unroll
    for (int jt=0; jt<8; jt++)
        acc3[jt] = mm64(Oh, Ol, XYh, XYl, 64 + 16*wv, jt*16, lrow, lkb, acc3[jt]);
    #pragma unroll
    for (int jt=0; jt<8; jt++){
        #pragma unroll
        for (int e=0;e<4;e++){
            int row = 16*wv + (lane>>4)*4 + e;
            int col = jt*16 + lrow;
            float v = fmaxf(acc3[jt][e], 0.f);
            int idx = (col < 64) ? (row*72 + col) : ((64+row)*72 + (col-64));
            sw2(Hh, Hl, idx, v);
        }
    }
    __syncthreads();

    {
        f32x4 acc2[4];
        #pragma unroll
        for (int jt=0; jt<4; jt++){
            float bb = b12_2[jt*16 + lrow];
            f32x4 v = {bb,bb,bb,bb};
            acc2[jt] = v;
        }
        #pragma unroll
        for (int jt=0; jt<4; jt++){
            acc2[jt] = mm64(Hh, Hl, W2h, W2l, 16*wv,      jt*16, lrow, lkb, acc2[jt]);
            acc2[jt] = mm64(Hh, Hl, W1h, W1l, 64 + 16*wv, jt*16, lrow, lkb, acc2[jt]);
        }
        #pragma unroll
        for (int jt=0; jt<4; jt++){
            float s = fmaxf(acc2[jt][0],0.f) + fmaxf(acc2[jt][1],0.f)
                    + fmaxf(acc2[jt][2],0.f) + fmaxf(acc2[jt][3],0.f);
            s += __shfl_down(s, 32);
            s += __shfl_down(s, 16);
            if (lane < 16) msum[wv*68 + jt*16 + lane] = s;
        }
    }
    __syncthreads();
    if (t < 64){
        float ss = msum[t] + msum[68+t] + msum[2*68+t] + msum[3*68+t];
        mean_part[((size_t)(b*4+tile))*64 + t] = ss;
    }
}

// =================== K2a: gram partials (unchanged) ===================
__global__ __launch_bounds__(256) void k2a_build(
    const float* __restrict__ fx, const float* __restrict__ fy,
    const float* __restrict__ x, const float* __restrict__ y,
    float* __restrict__ gram)
{
    const int blk = blockIdx.x;
    const int kh = blk & 1, side = (blk>>1)&1, b = blk>>2;
    const float* feat = side ? fy : fx;
    const float* targ = side ? x : y;
    float* g = gram + (size_t)blk*GSTRIDE;
    const int t = threadIdx.x;
    const int ig2 = t & 15, jg2 = t >> 4;
    const int i0 = ig2*4, j0 = jg2*4;
    __shared__ float Zt[64*68], Tt[64*68];
    __shared__ float red[4];

    float accA[4][4], accR[4][4];
    #pragma unroll
    for (int u=0;u<4;u++)
        #pragma unroll
        for (int v=0;v<4;v++){ accA[u][v]=0.f; accR[u][v]=0.f; }
    float szp=0.f, stp=0.f, tsqp=0.f;
    const int cc_ = t & 63, rq = t >> 6;

    for (int sub=0; sub<2; sub++){
        if (sub) __syncthreads();
        const int r0g = b*NS + kh*128 + sub*64;
        #pragma unroll
        for (int u=0;u<4;u++){
            int id = t + 256*u; int r = id>>4, c4 = (id&15)*4;
            *(float4*)(Zt + r*68 + c4) = *(const float4*)(feat + ((size_t)(r0g+r))*NH2 + c4);
            *(float4*)(Tt + r*68 + c4) = *(const float4*)(targ + ((size_t)(r0g+r))*ND + c4);
        }
        __syncthreads();
        #pragma unroll
        for (int ch=0; ch<16; ch++){
            const int r0 = ch*4;
            float4 zi[4], zj[4], tj[4];
            #pragma unroll
            for (int c=0;c<4;c++){
                zi[c] = *(const float4*)(Zt + (r0+c)*68 + i0);
                zj[c] = *(const float4*)(Zt + (r0+c)*68 + j0);
                tj[c] = *(const float4*)(Tt + (r0+c)*68 + j0);
            }
            #pragma unroll
            for (int c=0;c<4;c++){
                #pragma unroll
                for (int u=0;u<4;u++){
                    const float zv = F4E(zi[c], u);
                    const float4 a4 = zj[c], r4 = tj[c];
                    accA[u][0] += zv*a4.x; accA[u][1] += zv*a4.y;
                    accA[u][2] += zv*a4.z; accA[u][3] += zv*a4.w;
                    accR[u][0] += zv*r4.x; accR[u][1] += zv*r4.y;
                    accR[u][2] += zv*r4.z; accR[u][3] += zv*r4.w;
                }
            }
        }
        #pragma unroll
        for (int rr=0; rr<16; rr++){
            int r = rq*16 + rr;
            szp += Zt[r*68 + cc_];
            float tv = Tt[r*68 + cc_];
            stp += tv; tsqp += tv*tv;
        }
    }
    #pragma unroll
    for (int u=0;u<4;u++){
        *(float4*)(g + (i0+u)*64 + j0) = make_float4(accA[u][0],accA[u][1],accA[u][2],accA[u][3]);
        *(float4*)(g + 4096 + (i0+u)*64 + j0) = make_float4(accR[u][0],accR[u][1],accR[u][2],accR[u][3]);
    }
    __syncthreads();
    Zt[rq*68 + cc_] = szp;
    Tt[rq*68 + cc_] = stp;
    float tq = tsqp;
    #pragma unroll
    for (int off=32; off; off>>=1) tq += __shfl_down(tq, off);
    if ((t&63)==0) red[t>>6] = tq;
    __syncthreads();
    if (t < 64){
        g[8192+t] = Zt[t] + Zt[68+t] + Zt[2*68+t] + Zt[3*68+t];
        g[8256+t] = Tt[t] + Tt[68+t] + Tt[2*68+t] + Tt[3*68+t];
    }
    if (t==0) g[8320] = red[0]+red[1]+red[2]+red[3];
}

// =================== K2b: Neumann/Horner solve via MFMA (unchanged) ===================
__global__ __launch_bounds__(256) void k2b_solve(
    const float* __restrict__ gram, float* __restrict__ wbuf)
{
    const int bs = blockIdx.x;
    const float* g0 = gram + (size_t)(bs*2+0)*GSTRIDE;
    const float* g1 = gram + (size_t)(bs*2+1)*GSTRIDE;
    float* wb = wbuf + (size_t)bs*WSTRIDE;
    const int t = threadIdx.x;
    const int lane = t & 63, wv = t >> 6;
    const int lrow = lane & 15;
    const int lkb  = (lane >> 4) * 16;

    __shared__ float Rf[64*68];
    __shared__ float Wf[64*68];
    __shared__ unsigned short Eh[4608], El[4608];
    __shared__ unsigned short Wth[2][4608], Wtl[2][4608];
    __shared__ float szs[64], sts[64];
    __shared__ float sc[8];

    #pragma unroll
    for (int u=0;u<16;u++){
        int id = t + 256*u; int r = id>>6, c = id&63;
        Wf[r*68+c] = g0[id] + g1[id];
        Rf[r*68+c] = g0[4096+id] + g1[4096+id];
    }
    if (t<64){ szs[t] = g0[8192+t]+g1[8192+t]; sts[t] = g0[8256+t]+g1[8256+t]; }
    if (t==0) sc[1] = g0[8320]+g1[8320];
    __syncthreads();
    if (t<64){
        float dg = Wf[t*68+t];
        #pragma unroll
        for (int off=32; off; off>>=1) dg += __shfl_down(dg, off);
        if (t==0){ sc[0] = 1.0f/sqrtf(dg); sc[1] = 1.0f/sqrtf(sc[1]); }
    }
    __syncthreads();
    const float zinv = sc[0], tinv = sc[1];
    const float z2 = zinv*zinv, zt = zinv*tinv, inv256 = 1.0f/256.0f;
    const float i23 = 2.0f/3.0f;
    const int i = t>>2, qd = t&3;
    {
        const float szi = szs[i];
        #pragma unroll
        for (int q=0;q<4;q++){
            const int j = qd*16 + q*4;
            float4 a4 = *(const float4*)(Wf + i*68 + j);
            float4 sj = *(const float4*)(szs + j);
            float v0 = z2*(a4.x - szi*sj.x*inv256);
            float v1 = z2*(a4.y - szi*sj.y*inv256);
            float v2 = z2*(a4.z - szi*sj.z*inv256);
            float v3 = z2*(a4.w - szi*sj.w*inv256);
            if (i == j)   v0 += 1.f;
            else if (i == j+1) v1 += 1.f;
            else if (i == j+2) v2 += 1.f;
            else if (i == j+3) v3 += 1.f;
            float e0 = v0*i23 - ((i==j  ) ? 1.f : 0.f);
            float e1 = v1*i23 - ((i==j+1) ? 1.f : 0.f);
            float e2 = v2*i23 - ((i==j+2) ? 1.f : 0.f);
            float e3 = v3*i23 - ((i==j+3) ? 1.f : 0.f);
            sw2x2(Eh, El, i*72 + j,   e0, e1);
            sw2x2(Eh, El, i*72 + j+2, e2, e3);
            float4 rv = *(float4*)(Rf + i*68 + j);
            float4 t4 = *(const float4*)(sts + j);
            float r0 = zt*(rv.x - szi*t4.x*inv256)*i23;
            float r1 = zt*(rv.y - szi*t4.y*inv256)*i23;
            float r2 = zt*(rv.z - szi*t4.z*inv256)*i23;
            float r3 = zt*(rv.w - szi*t4.w*inv256)*i23;
            *(float4*)(Rf + i*68 + j) = make_float4(r0,r1,r2,r3);
            sw2(Wth[0], Wtl[0], (j  )*72 + i, r0);
            sw2(Wth[0], Wtl[0], (j+1)*72 + i, r1);
            sw2(Wth[0], Wtl[0], (j+2)*72 + i, r2);
            sw2(Wth[0], Wtl[0], (j+3)*72 + i, r3);
        }
    }
    __syncthreads();

    int cur = 0;
    for (int n=0; n<12; n++){
        f32x4 acc[4];
        #pragma unroll
        for (int jt=0; jt<4; jt++){
            f32x4 zz = {0.f,0.f,0.f,0.f};
            acc[jt] = mm64(Eh, El, Wth[cur], Wtl[cur], 16*wv, jt*16, lrow, lkb, zz);
        }
        const int gi0 = 16*wv + (lane>>4)*4;
        #pragma unroll
        for (int jt=0; jt<4; jt++){
            const int gj = jt*16 + lrow;
            float w0 = Rf[(gi0  )*68 + gj] - acc[jt][0];
            float w1 = Rf[(gi0+1)*68 + gj] - acc[jt][1];
            float w2 = Rf[(gi0+2)*68 + gj] - acc[jt][2];
            float w3 = Rf[(gi0+3)*68 + gj] - acc[jt][3];
            sw2x2(Wth[cur^1], Wtl[cur^1], gj*72 + gi0,   w0, w1);
            sw2x2(Wth[cur^1], Wtl[cur^1], gj*72 + gi0+2, w2, w3);
            if (n == 11){
                Wf[(gi0  )*68 + gj] = w0;  wb[(gi0  )*64 + gj] = w0;
                Wf[(gi0+1)*68 + gj] = w1;  wb[(gi0+1)*64 + gj] = w1;
                Wf[(gi0+2)*68 + gj] = w2;  wb[(gi0+2)*64 + gj] = w2;
                Wf[(gi0+3)*68 + gj] = w3;  wb[(gi0+3)*64 + gj] = w3;
            }
        }
        cur ^= 1;
        __syncthreads();
    }

    if (t < 64){
        float s = 0.f;
        for (int i2=0; i2<64; i2++) s += szs[i2]*Wf[i2*68 + t];
        wb[4096+t] = (tinv*sts[t] - zinv*s) * inv256;
    }
    if (t==0){ wb[4160] = zinv; wb[4161] = tinv; }
}

// =================== KRG: fused residual (MFMA) + Renyi Gram (MFMA) ===================
// blk = (side*NB + b)*2 + jh; 256 thr = 4 waves.
// Computes full 256-row residual in LDS (bf16), row norms, then Gram over
// i in [0,256) x j in [jh*128, jh*128+128). jh==0 block writes rx/ry.
__global__ __launch_bounds__(256) void kRG(
    const float* __restrict__ fx, const float* __restrict__ fy,
    const float* __restrict__ x, const float* __restrict__ y,
    const float* __restrict__ wbuf,
    float* __restrict__ part3, float* __restrict__ dout)
{
    const int blk = blockIdx.x;
    const int jh = blk & 1;
    const int b = (blk >> 1) & (NB-1);
    const int side = (blk >> 1) >> 6;
    const float* feat = side ? fy : fx;
    const float* targ = side ? x : y;     // regression target
    const float* bmat = side ? y : x;     // second MI operand (raw)
    const float* wb = wbuf + (size_t)(b*2+side)*WSTRIDE;
    const int t = threadIdx.x;
    const int lane = t & 63, wv = t >> 6;
    const int lrow = lane & 15, lkb = (lane>>4)*16;

    __shared__ unsigned short resA[256*72];          // residual, bf16
    __shared__ unsigned short tgB [256*72];          // bmat, bf16
    __shared__ unsigned short Zh[2*4608], Zl[2*4608];// feat chunk, hi/lo, dbuf
    __shared__ unsigned short Wth[4608], Wtl[4608];  // W^T hi/lo
    __shared__ float c0s[64];
    __shared__ float nAs[256], nBs[256];
    __shared__ float red[4][3];
    __shared__ float lred[4];

    // ---- stage W^T, c0s, tgB, Z chunk0 ----
    #pragma unroll
    for (int u=0;u<4;u++){
        int id = t + 256*u;              // 1024 float4 over W rows k
        int k = id>>4, c0 = (id&15)*4;
        float4 v = *(const float4*)(wb + (size_t)k*64 + c0);
        sw2(Wth, Wtl, (c0+0)*72 + k, v.x);
        sw2(Wth, Wtl, (c0+1)*72 + k, v.y);
        sw2(Wth, Wtl, (c0+2)*72 + k, v.z);
        sw2(Wth, Wtl, (c0+3)*72 + k, v.w);
    }
    if (t<64) c0s[t] = wb[4096+t];
    const float zinv = wb[4160], tinv = wb[4161];
    #pragma unroll
    for (int u=0;u<16;u++){
        int id = t + 256*u;              // 4096 float4
        int r = id>>4, c0 = (id&15)*4;
        float4 v = *(const float4*)(bmat + ((size_t)(b*NS+r))*ND + c0);
        ushort4 h;
        h.x=f2bf(v.x); h.y=f2bf(v.y); h.z=f2bf(v.z); h.w=f2bf(v.w);
        *(ushort4*)(tgB + r*72 + c0) = h;
    }
    #pragma unroll
    for (int u=0;u<4;u++){
        int id = t + 256*u;              // 1024 float4, chunk 0
        int r = id>>4, c0 = (id&15)*4;
        float4 v = *(const float4*)(feat + ((size_t)(b*NS + r))*NH2 + c0);
        sw2x2(Zh, Zl, r*72+c0,   v.x, v.y);
        sw2x2(Zh, Zl, r*72+c0+2, v.z, v.w);
    }
    __syncthreads();

    // ---- residual: 4 chunks of 64 rows, double-buffered Z ----
    float lacc = 0.f;
    for (int c=0; c<4; c++){
        if (c < 3){
            unsigned short* zh = Zh + ((c+1)&1)*4608;
            unsigned short* zl = Zl + ((c+1)&1)*4608;
            #pragma unroll
            for (int u=0;u<4;u++){
                int id = t + 256*u;
                int r = id>>4, c0 = (id&15)*4;
                float4 v = *(const float4*)(feat + ((size_t)(b*NS + (c+1)*64 + r))*NH2 + c0);
                sw2x2(zh, zl, r*72+c0,   v.x, v.y);
                sw2x2(zh, zl, r*72+c0+2, v.z, v.w);
            }
        }
        const unsigned short* zh = Zh + (c&1)*4608;
        const unsigned short* zl = Zl + (c&1)*4608;
        f32x4 acc[4];
        #pragma unroll
        for (int jt=0; jt<4; jt++){
            f32x4 zz = {0.f,0.f,0.f,0.f};
            acc[jt] = mm64(zh, zl, Wth, Wtl, 16*wv, jt*16, lrow, lkb, zz);
        }
        const int r0 = 16*wv + (lane>>4)*4;
        #pragma unroll
        for (int jt=0; jt<4; jt++){
            const int gj = jt*16 + lrow;
            const float cc = c0s[gj];
            #pragma unroll
            for (int e=0;e<4;e++){
                const int grow = c*64 + r0 + e;
                float q = targ[((size_t)(b*NS+grow))*ND + gj];
                float rr = tinv*q - zinv*acc[jt][e] - cc;
                lacc += rr*rr;
                resA[grow*72 + gj] = f2bf(rr);
            }
        }
        __syncthreads();
    }

    // ---- loss reduce + row norms from bf16 planes ----
    {
        float l = lacc;
        #pragma unroll
        for (int off=32; off; off>>=1) l += __shfl_down(l, off);
        if (lane==0) lred[wv] = l;
    }
    {
        float sa=0.f, sb=0.f;
        #pragma unroll
        for (int j8=0;j8<8;j8++){
            bf16x8 va = *(const bf16x8*)((const char*)resA + (size_t)t*144 + j8*16);
            bf16x8 vb = *(const bf16x8*)((const char*)tgB  + (size_t)t*144 + j8*16);
            #pragma unroll
            for (int e2=0;e2<8;e2++){
                float fa = bf2f((unsigned short)va[e2]);
                float fb = bf2f((unsigned short)vb[e2]);
                sa += fa*fa; sb += fb*fb;
            }
        }
        nAs[t] = sa; nBs[t] = sb;
    }
    __syncthreads();
    if (t==0 && jh==0)
        dout[(side?256:192)+b] = lred[0]+lred[1]+lred[2]+lred[3];

    // ---- Gram + exp ----
    const char* pA = (const char*)resA;
    const char* pB = (const char*)tgB;
    const f32x4 zero4 = {0.f, 0.f, 0.f, 0.f};
    const float CEXP = -2.8853900817779268f;

    float Sa=0.f, Sb=0.f, Sab=0.f;
    #pragma unroll
    for (int it=0; it<4; it++){
        const int i0 = wv*64 + it*16;
        const int arow = i0 + lrow;
        bf16x8 aA0 = *(const bf16x8*)(pA + arow*144 + lkb);
        bf16x8 aA1 = *(const bf16x8*)(pA + arow*144 + lkb + 64);
        bf16x8 aB0 = *(const bf16x8*)(pB + arow*144 + lkb);
        bf16x8 aB1 = *(const bf16x8*)(pB + arow*144 + lkb + 64);
        float nAi[4], nBi[4];
        #pragma unroll
        for (int e=0;e<4;e++){
            int gi = i0 + (lane>>4)*4 + e;
            nAi[e] = nAs[gi]; nBi[e] = nBs[gi];
        }
        #pragma unroll
        for (int jt=0; jt<8; jt++){
            const int j0 = jh*128 + jt*16;
            const int brow = j0 + lrow;
            bf16x8 bA0 = *(const bf16x8*)(pA + brow*144 + lkb);
            bf16x8 bA1 = *(const bf16x8*)(pA + brow*144 + lkb + 64);
            bf16x8 bB0 = *(const bf16x8*)(pB + brow*144 + lkb);
            bf16x8 bB1 = *(const bf16x8*)(pB + brow*144 + lkb + 64);
            f32x4 cA = __builtin_amdgcn_mfma_f32_16x16x32_bf16(aA0, bA0, zero4, 0, 0, 0);
            cA = __builtin_amdgcn_mfma_f32_16x16x32_bf16(aA1, bA1, cA, 0, 0, 0);
            f32x4 cB = __builtin_amdgcn_mfma_f32_16x16x32_bf16(aB0, bB0, zero4, 0, 0, 0);
            cB = __builtin_amdgcn_mfma_f32_16x16x32_bf16(aB1, bB1, cB, 0, 0, 0);
            const int gj = j0 + lrow;
            const float nAj = nAs[gj], nBj = nBs[gj];
            #pragma unroll
            for (int e=0;e<4;e++){
                const int gi = i0 + (lane>>4)*4 + e;
                const float dda = (gi==gj) ? 0.f : (nAi[e] + nAj - 2.f*cA[e]);
                const float ddb = (gi==gj) ? 0.f : (nBi[e] + nBj - 2.f*cB[e]);
                const float ka2 = exp2f(CEXP*dda);
                const float kb2 = exp2f(CEXP*ddb);
                Sa += ka2; Sb += kb2; Sab += ka2*kb2;
            }
        }
    }
    #pragma unroll
    for (int off=32; off; off>>=1){
        Sa += __shfl_down(Sa,off); Sb += __shfl_down(Sb,off); Sab += __shfl_down(Sab,off);
    }
    if (lane==0){ red[wv][0]=Sa; red[wv][1]=Sb; red[wv][2]=Sab; }
    __syncthreads();
    if (t==0){
        float* o = part3 + (size_t)blk*3;
        o[0] = red[0][0]+red[1][0]+red[2][0]+red[3][0];
        o[1] = red[0][1]+red[1][1]+red[2][1]+red[3][1];
        o[2] = red[0][2]+red[1][2]+red[2][2]+red[3][2];
    }
}

// =================== K4 ===================
__global__ __launch_bounds__(64) void k4_final(
    const float* __restrict__ mean_part, const float* __restrict__ part3,
    const float* __restrict__ wc1, const float* __restrict__ bc1,
    const float* __restrict__ bn_gamma, const float* __restrict__ bn_beta,
    const float* __restrict__ w2, const float* __restrict__ b2,
    const float* __restrict__ wc2, const float* __restrict__ bc2,
    float* __restrict__ dout)
{
    const int t = threadIdx.x;
    __shared__ float ic[64][5];
    __shared__ float mu[5], iv[5];

    float o0 = bc1[0], o1 = bc1[1], o2 = bc1[2];
    for (int c=0;c<64;c++){
        float mv = mean_part[(t*4+0)*64+c] + mean_part[(t*4+1)*64+c]
                 + mean_part[(t*4+2)*64+c] + mean_part[(t*4+3)*64+c];
        mv *= (1.0f/256.0f);
        o0 += mv*wc1[c*3+0]; o1 += mv*wc1[c*3+1]; o2 += mv*wc1[c*3+2];
    }
    dout[t*3+0]=o0; dout[t*3+1]=o1; dout[t*3+2]=o2;
    {
        float m = fmaxf(o0,fmaxf(o1,o2));
        float e0=__expf(o0-m), e1=__expf(o1-m), e2=__expf(o2-m);
        float inv = 1.f/(e0+e1+e2);
        dout[640+t*3+0]=e0*inv; dout[640+t*3+1]=e1*inv; dout[640+t*3+2]=e2*inv;
    }
    float exy[2];
    #pragma unroll
    for (int side=0; side<2; side++){
        const float* pp = part3 + (size_t)((side*NB + t)*2)*3;
        float Sa = pp[0]+pp[3];
        float Sb = pp[1]+pp[4];
        float Sab= pp[2]+pp[5];
        float Hx  = 16.f - log2f(Sa);
        float Hy  = 16.f - log2f(Sb);
        float Hxy = 16.f - log2f(Sab);
        float mi = (Hx + Hy - Hxy) / fmaxf(Hx, Hy);
        dout[(side?384:320)+t] = mi;
        exy[side] = mi;
    }
    ic[t][0]=o0; ic[t][1]=o1; ic[t][2]=o2; ic[t][3]=exy[0]; ic[t][4]=exy[1];
    __syncthreads();
    if (t<5){
        float m=0.f;
        for (int bb=0;bb<64;bb++) m += ic[bb][t];
        m *= (1.f/64.f);
        float v=0.f;
        for (int bb=0;bb<64;bb++){ float d=ic[bb][t]-m; v+=d*d; }
        v *= (1.f/64.f);
        mu[t]=m; iv[t]=1.f/sqrtf(v+1e-5f);
    }
    __syncthreads();
    float vn[5];
    #pragma unroll
    for (int c=0;c<5;c++) vn[c] = (ic[t][c]-mu[c])*iv[c]*bn_gamma[c]+bn_beta[c];
    float q0=bc2[0], q1=bc2[1], q2=bc2[2];
    for (int j=0;j<64;j++){
        float hh = b2[j];
        #pragma unroll
        for (int c=0;c<5;c++) hh += vn[c]*w2[c*64+j];
        hh = fmaxf(hh,0.f);
        q0 += hh*wc2[j*3+0]; q1 += hh*wc2[j*3+1]; q2 += hh*wc2[j*3+2];
    }
    dout[448+t*3+0]=q0; dout[448+t*3+1]=q1; dout[448+t*3+2]=q2;
    float m = fmaxf(q0,fmaxf(q1,q2));
    float e0=__expf(q0-m), e1=__expf(q1-m), e2=__expf(q2-m);
    float inv=1.f/(e0+e1+e2);
    dout[832+t*3+0]=e0*inv; dout[832+t*3+1]=e1*inv; dout[832+t*3+2]=e2*inv;
}

extern "C" void kernel_launch(void* const* d_in, const int* in_sizes, int n_in,
                              void* d_out, int out_size, void* d_ws, size_t ws_size,
                              hipStream_t stream)
{
    const float* x     = (const float*)d_in[0];
    const float* y     = (const float*)d_in[1];
    const float* w11_1 = (const float*)d_in[2];
    const float* b11_1 = (const float*)d_in[3];
    const float* w11_2 = (const float*)d_in[4];
    const float* b11_2 = (const float*)d_in[5];
    const float* w12_1 = (const float*)d_in[6];
    const float* b12_1 = (const float*)d_in[7];
    const float* w12_2 = (const float*)d_in[8];
    const float* b12_2 = (const float*)d_in[9];
    const float* wc1   = (const float*)d_in[10];
    const float* bc1   = (const float*)d_in[11];
    const float* bn_g  = (const float*)d_in[12];
    const float* bn_b  = (const float*)d_in[13];
    const float* w2    = (const float*)d_in[14];
    const float* b2    = (const float*)d_in[15];
    const float* wc2   = (const float*)d_in[16];
    const float* bc2   = (const float*)d_in[17];

    float* ws   = (float*)d_ws;
    float* dout = (float*)d_out;
    float* out_x = ws;
    float* out_y = ws + 1048576;
    float* mean_part = ws + 4259840;             // 16384
    float* part3 = mean_part + 16384;            // 768 (pad region 3840)
    float* gram  = ws + 4280320;                 // 256*8448 floats
    float* wbuf  = gram + 2162688;               // 128*4224 floats

    hipLaunchKernelGGL(k1_fused, dim3(NB*4), dim3(256), 0, stream,
        x,y,w11_1,b11_1,w11_2,b11_2,w12_1,b12_1,w12_2,b12_2,
        out_x,out_y,mean_part);
    hipLaunchKernelGGL(k2a_build, dim3(NB*4), dim3(256), 0, stream,
        out_x,out_y,x,y,gram);
    hipLaunchKernelGGL(k2b_solve, dim3(2*NB), dim3(256), 0, stream,
        gram,wbuf);
    hipLaunchKernelGGL(kRG, dim3(NB*2*2), dim3(256), 0, stream,
        out_x,out_y,x,y,wbuf,part3,dout);
    hipLaunchKernelGGL(k4_final, dim3(1), dim3(64), 0, stream,
        mean_part,part3,wc1,bc1,bn_g,bn_b,w2,b2,wc2,bc2,dout);
}

// Round 11
// 79.798 us; speedup vs baseline: 2.8948x; 1.0683x over previous
//
#include <hip/hip_runtime.h>
#include <math.h>

#define NB 64
#define NS 256
#define ND 64
#define NH2 64
#define NH 128
#define WSTRIDE 4224

// d_out layout (floats):
// 0: out_c[64*3]; 192: rx[64]; 256: ry[64]; 320: ex[64]; 384: ey[64];
// 448: out_c_f[64*3]; 640: prob1[64*3]; 832: prob2[64*3]

#define F4E(v_, e_) ((e_)==0?(v_).x:((e_)==1?(v_).y:((e_)==2?(v_).z:(v_).w)))

typedef __attribute__((ext_vector_type(8))) short bf16x8;
typedef __attribute__((ext_vector_type(4))) float f32x4;

__device__ __forceinline__ unsigned short f2bf(float f){
    union { float f; unsigned int u; } v; v.f = f;
    unsigned int r = v.u + 0x7fffu + ((v.u >> 16) & 1u);
    return (unsigned short)(r >> 16);
}
__device__ __forceinline__ float bf2f(unsigned short h){
    union { unsigned int u; float f; } v; v.u = ((unsigned int)h) << 16;
    return v.f;
}
__device__ __forceinline__ void sw2(unsigned short* ph, unsigned short* pl, int idx, float f){
    unsigned short h = f2bf(f);
    ph[idx] = h;
    pl[idx] = f2bf(f - bf2f(h));
}
__device__ __forceinline__ void sw2x2(unsigned short* ph, unsigned short* pl, int idx, float f0, float f1){
    unsigned short h0 = f2bf(f0), h1 = f2bf(f1);
    ushort2 hh; hh.x = h0; hh.y = h1;
    *(ushort2*)(ph + idx) = hh;
    ushort2 ll; ll.x = f2bf(f0 - bf2f(h0)); ll.y = f2bf(f1 - bf2f(h1));
    *(ushort2*)(pl + idx) = ll;
}

#define LD8(P_, row_, kb_) (*(const bf16x8*)((const char*)(P_) + (size_t)(row_)*144 + (kb_)))

// K=64 tile MAC: acc += A[ar..ar+15][0:64] * B[br..br+15][0:64]^T  (hi/lo 3-combo)
__device__ __forceinline__ f32x4 mm64(
    const unsigned short* Ah, const unsigned short* Al,
    const unsigned short* Bh, const unsigned short* Bl,
    int ar, int br, int lrow, int lkb, f32x4 acc)
{
    const int ra = ar + lrow, rb = br + lrow;
    bf16x8 ah0 = LD8(Ah, ra, lkb), ah1 = LD8(Ah, ra, lkb+64);
    bf16x8 al0 = LD8(Al, ra, lkb), al1 = LD8(Al, ra, lkb+64);
    bf16x8 bh0 = LD8(Bh, rb, lkb), bh1 = LD8(Bh, rb, lkb+64);
    bf16x8 bl0 = LD8(Bl, rb, lkb), bl1 = LD8(Bl, rb, lkb+64);
    acc = __builtin_amdgcn_mfma_f32_16x16x32_bf16(ah0, bh0, acc, 0,0,0);
    acc = __builtin_amdgcn_mfma_f32_16x16x32_bf16(ah1, bh1, acc, 0,0,0);
    acc = __builtin_amdgcn_mfma_f32_16x16x32_bf16(ah0, bl0, acc, 0,0,0);
    acc = __builtin_amdgcn_mfma_f32_16x16x32_bf16(ah1, bl1, acc, 0,0,0);
    acc = __builtin_amdgcn_mfma_f32_16x16x32_bf16(al0, bh0, acc, 0,0,0);
    acc = __builtin_amdgcn_mfma_f32_16x16x32_bf16(al1, bh1, acc, 0,0,0);
    return acc;
}

// =================== K1: MFMA bf16-hi/lo fused MLP, 512 threads / 8 waves ===================
__global__ __launch_bounds__(512) void k1_fused(
    const float* __restrict__ x, const float* __restrict__ y,
    const float* __restrict__ w11_1, const float* __restrict__ b11_1,
    const float* __restrict__ w11_2, const float* __restrict__ b11_2,
    const float* __restrict__ w12_1, const float* __restrict__ b12_1,
    const float* __restrict__ w12_2, const float* __restrict__ b12_2,
    float* __restrict__ out_x, float* __restrict__ out_y,
    float* __restrict__ mean_part)
{
    const int b = blockIdx.x >> 2, tile = blockIdx.x & 3;
    const int t = threadIdx.x;
    const int lane = t & 63, wv = t >> 6;          // wv 0..7
    const int lrow = lane & 15;
    const int lkb  = (lane >> 4) * 16;
    const int row0g = b*NS + tile*64;

    __shared__ unsigned short XYh[9216], XYl[9216];   // 128 rows
    __shared__ unsigned short W1h[4608], W1l[4608];   // 64 rows
    __shared__ unsigned short W2h[4608], W2l[4608];
    __shared__ unsigned short Hh [9216], Hl [9216];
    __shared__ unsigned short Oh [9216], Ol [9216];
    __shared__ float msum[8*68];

    // ---- P0: stage XY + W1^T + W2^T ----
    #pragma unroll
    for (int u=0;u<4;u++){
        int id = t + 512*u;                 // 2048 float4
        int r = id>>4, c0 = (id&15)*4;
        const float* src = (r < 64) ? (x + ((size_t)(row0g + r))*ND)
                                    : (y + ((size_t)(row0g + r - 64))*ND);
        float4 v = *(const float4*)(src + c0);
        sw2x2(XYh, XYl, r*72 + c0,   v.x, v.y);
        sw2x2(XYh, XYl, r*72 + c0+2, v.z, v.w);
    }
    {
        int rp = t>>4, c0 = (t&15)*4;       // 512 row-pair jobs
        float4 a0 = *(const float4*)(w11_1 + (size_t)(2*rp  )*64 + c0);
        float4 a1 = *(const float4*)(w11_1 + (size_t)(2*rp+1)*64 + c0);
        float4 b0 = *(const float4*)(w11_2 + (size_t)(2*rp  )*64 + c0);
        float4 b1 = *(const float4*)(w11_2 + (size_t)(2*rp+1)*64 + c0);
        #pragma unroll
        for (int i2=0;i2<4;i2++){
            sw2x2(W1h, W1l, (c0+i2)*72 + 2*rp, F4E(a0,i2), F4E(a1,i2));
            sw2x2(W2h, W2l, (c0+i2)*72 + 2*rp, F4E(b0,i2), F4E(b1,i2));
        }
    }
    __syncthreads();

    // ---- P1: G1  H = relu(XY @ W1 + b1)  (128x64) : wave w -> rows 16w ----
    {
        const int ar = 16*wv;
        #pragma unroll
        for (int jt=0; jt<4; jt++){
            float bb = b11_1[jt*16 + lrow];
            f32x4 acc = {bb,bb,bb,bb};
            acc = mm64(XYh, XYl, W1h, W1l, ar, jt*16, lrow, lkb, acc);
            #pragma unroll
            for (int e=0;e<4;e++){
                int row = ar + (lane>>4)*4 + e;
                int col = jt*16 + lrow;
                sw2(Hh, Hl, row*72 + col, fmaxf(acc[e], 0.f));
            }
        }
    }
    __syncthreads();

    // ---- P2: stage w12_1^T half0 -> XY region; G2  O = H @ W2 + b2 ----
    #pragma unroll
    for (int u=0;u<2;u++){
        int id = t + 512*u;                 // 1024 row-pair jobs
        int krp = id>>5, c0 = (id&31)*4;
        float4 v0 = *(const float4*)(w12_1 + (size_t)(2*krp  )*NH + c0);
        float4 v1 = *(const float4*)(w12_1 + (size_t)(2*krp+1)*NH + c0);
        #pragma unroll
        for (int i2=0;i2<4;i2++)
            sw2x2(XYh, XYl, (c0+i2)*72 + 2*krp, F4E(v0,i2), F4E(v1,i2));
    }
    {
        const int ar = 16*wv;
        #pragma unroll
        for (int jt=0; jt<4; jt++){
            float bb = b11_2[jt*16 + lrow];
            f32x4 acc = {bb,bb,bb,bb};
            acc = mm64(Hh, Hl, W2h, W2l, ar, jt*16, lrow, lkb, acc);
            #pragma unroll
            for (int e=0;e<4;e++){
                int row = ar + (lane>>4)*4 + e;
                int col = jt*16 + lrow;
                float v = acc[e];
                sw2(Oh, Ol, row*72 + col, v);
                float* dst = (row < 64) ? out_x : out_y;
                dst[((size_t)(row0g + (row & 63)))*NH2 + col] = v;
            }
        }
    }
    __syncthreads();

    // ---- P3: G3 pass0: wave w -> (row-tile rt=w&3, col-tiles 4*(w>>2)+q) ----
    const int rt = wv & 3, cq = wv >> 2;
    f32x4 acc3[4];
    #pragma unroll
    for (int q=0; q<4; q++){
        float bb = b12_1[(4*cq+q)*16 + lrow];
        f32x4 v = {bb,bb,bb,bb};
        acc3[q] = v;
    }
    #pragma unroll
    for (int q=0; q<4; q++)
        acc3[q] = mm64(Oh, Ol, XYh, XYl, 16*rt, 16*(4*cq+q), lrow, lkb, acc3[q]);
    __syncthreads();

    // ---- P4: stage w12_1^T half1 -> XY; w12_2^T halves -> W2(h0)/W1(h1) ----
    #pragma unroll
    for (int u=0;u<2;u++){
        int id = t + 512*u;
        int krp = id>>5, c0 = (id&31)*4;
        float4 v0 = *(const float4*)(w12_1 + (size_t)(64+2*krp  )*NH + c0);
        float4 v1 = *(const float4*)(w12_1 + (size_t)(64+2*krp+1)*NH + c0);
        #pragma unroll
        for (int i2=0;i2<4;i2++)
            sw2x2(XYh, XYl, (c0+i2)*72 + 2*krp, F4E(v0,i2), F4E(v1,i2));
    }
    {
        int krp = t>>4, c0 = (t&15)*4;      // 512 row-pair jobs
        float4 h0a = *(const float4*)(w12_2 + (size_t)(2*krp  )*NH2 + c0);
        float4 h0b = *(const float4*)(w12_2 + (size_t)(2*krp+1)*NH2 + c0);
        float4 h1a = *(const float4*)(w12_2 + (size_t)(64+2*krp  )*NH2 + c0);
        float4 h1b = *(const float4*)(w12_2 + (size_t)(64+2*krp+1)*NH2 + c0);
        #pragma unroll
        for (int i2=0;i2<4;i2++){
            sw2x2(W2h, W2l, (c0+i2)*72 + 2*krp, F4E(h0a,i2), F4E(h0b,i2));
            sw2x2(W1h, W1l, (c0+i2)*72 + 2*krp, F4E(h1a,i2), F4E(h1b,i2));
        }
    }
    __syncthreads();

    // ---- P5: G3 pass1 + epi -> H1 into H region ----
    #pragma unroll
    for (int q=0; q<4; q++)
        acc3[q] = mm64(Oh, Ol, XYh, XYl, 64 + 16*rt, 16*(4*cq+q), lrow, lkb, acc3[q]);
    #pragma unroll
    for (int q=0; q<4; q++){
        #pragma unroll
        for (int e=0;e<4;e++){
            int row = 16*rt + (lane>>4)*4 + e;        // sample 0..63
            int col = 16*(4*cq+q) + lrow;             // 0..127
            float v = fmaxf(acc3[q][e], 0.f);
            int idx = (col < 64) ? (row*72 + col) : ((64+row)*72 + (col-64));
            sw2(Hh, Hl, idx, v);
        }
    }
    __syncthreads();

    // ---- P6: G4: wave w -> (rt, cols (2*cq+q)*16) ----
    {
        f32x4 acc2[2];
        #pragma unroll
        for (int q=0; q<2; q++){
            const int jc = 2*cq + q;
            float bb = b12_2[jc*16 + lrow];
            f32x4 v = {bb,bb,bb,bb};
            acc2[q] = v;
            acc2[q] = mm64(Hh, Hl, W2h, W2l, 16*rt,      16*jc, lrow, lkb, acc2[q]);
            acc2[q] = mm64(Hh, Hl, W1h, W1l, 64 + 16*rt, 16*jc, lrow, lkb, acc2[q]);
        }
        #pragma unroll
        for (int q=0; q<2; q++){
            const int jc = 2*cq + q;
            float s = fmaxf(acc2[q][0],0.f) + fmaxf(acc2[q][1],0.f)
                    + fmaxf(acc2[q][2],0.f) + fmaxf(acc2[q][3],0.f);
            s += __shfl_down(s, 32);
            s += __shfl_down(s, 16);
            if (lane < 16) msum[wv*68 + jc*16 + lane] = s;
        }
    }
    __syncthreads();
    // FIX: only the 4 waves that own column-half (t>>5) wrote those entries.
    if (t < 64){
        const int w0 = (t>>5)*4;    // cols 0-31 -> waves 0-3 (cq=0); cols 32-63 -> waves 4-7
        float ss = msum[(w0+0)*68 + t] + msum[(w0+1)*68 + t]
                 + msum[(w0+2)*68 + t] + msum[(w0+3)*68 + t];
        mean_part[((size_t)(b*4+tile))*64 + t] = ss;
    }
}

// =================== K2AB: center-first MFMA gram + Neumann/Horner solve ===================
// grid 128: bs = b*2+side
__global__ __launch_bounds__(256) void k2ab(
    const float* __restrict__ fx, const float* __restrict__ fy,
    const float* __restrict__ x, const float* __restrict__ y,
    float* __restrict__ wbuf)
{
    const int bs = blockIdx.x;
    const int side = bs & 1, b = bs >> 1;
    const float* feat = side ? fy : fx;
    const float* targ = side ? x : y;
    float* wb = wbuf + (size_t)bs*WSTRIDE;
    const int t = threadIdx.x;
    const int lane = t & 63, wv = t >> 6;
    const int lrow = lane & 15;
    const int lkb  = (lane >> 4) * 16;
    const float inv256 = 1.0f/256.0f;

    __shared__ float Wf[64*68];                 // Ac -> final W
    __shared__ float Rf[64*68];                 // Rc -> R''
    __shared__ unsigned short Zh[4608], Zl[4608], Th[4608], Tl[4608];
    __shared__ unsigned short Eh[4608], El[4608];
    __shared__ unsigned short Wth[2][4608], Wtl[2][4608];
    __shared__ float cspA[16*68], cspB[16*68];
    __shared__ float szs[64], sts[64];
    __shared__ float sc[8], red4[4];

    // ---- Phase A: raw col sums of Z,T and sum T^2 (global read pass) ----
    {
        float szp0=0.f,szp1=0.f,szp2=0.f,szp3=0.f;
        float stp0=0.f,stp1=0.f,stp2=0.f,stp3=0.f;
        float tsq=0.f;
        for (int c=0;c<4;c++){
            #pragma unroll
            for (int u=0;u<4;u++){
                int id = t + 256*u;
                int r = id>>4, c0 = (id&15)*4;
                float4 v = *(const float4*)(feat + ((size_t)(b*NS + c*64 + r))*NH2 + c0);
                float4 w = *(const float4*)(targ + ((size_t)(b*NS + c*64 + r))*ND + c0);
                szp0+=v.x; szp1+=v.y; szp2+=v.z; szp3+=v.w;
                stp0+=w.x; stp1+=w.y; stp2+=w.z; stp3+=w.w;
                tsq += w.x*w.x + w.y*w.y + w.z*w.z + w.w*w.w;
            }
        }
        const int g2 = t>>4, c0 = (t&15)*4;
        cspA[g2*68 + c0+0] = szp0; cspA[g2*68 + c0+1] = szp1;
        cspA[g2*68 + c0+2] = szp2; cspA[g2*68 + c0+3] = szp3;
        cspB[g2*68 + c0+0] = stp0; cspB[g2*68 + c0+1] = stp1;
        cspB[g2*68 + c0+2] = stp2; cspB[g2*68 + c0+3] = stp3;
        float tq = tsq;
        #pragma unroll
        for (int off=32; off; off>>=1) tq += __shfl_down(tq, off);
        if (lane==0) red4[wv] = tq;
    }
    __syncthreads();
    if (t < 64){
        float sa=0.f, sb=0.f;
        #pragma unroll
        for (int g2=0; g2<16; g2++){ sa += cspA[g2*68+t]; sb += cspB[g2*68+t]; }
        szs[t] = sa; sts[t] = sb;
        float s2 = sa*sa;
        #pragma unroll
        for (int off=32; off; off>>=1) s2 += __shfl_down(s2, off);
        if (t==0) sc[2] = s2;                  // sum of col-sum squares
    }
    if (t==0) sc[1] = red4[0]+red4[1]+red4[2]+red4[3];   // tn2
    __syncthreads();

    // ---- Phase B: gram of CENTERED Z (no cancellation), Rc = Zc^T T ----
    f32x4 accA[4], accR[4];
    #pragma unroll
    for (int jt=0;jt<4;jt++){
        f32x4 z = {0.f,0.f,0.f,0.f};
        accA[jt]=z; accR[jt]=z;
    }
    for (int c=0;c<4;c++){
        if (c) __syncthreads();
        #pragma unroll
        for (int u=0;u<4;u++){
            int id = t + 256*u;
            int r = id>>4, c0 = (id&15)*4;
            float4 v = *(const float4*)(feat + ((size_t)(b*NS + c*64 + r))*NH2 + c0);
            float4 w = *(const float4*)(targ + ((size_t)(b*NS + c*64 + r))*ND + c0);
            v.x -= szs[c0+0]*inv256; v.y -= szs[c0+1]*inv256;
            v.z -= szs[c0+2]*inv256; v.w -= szs[c0+3]*inv256;
            sw2(Zh,Zl,(c0+0)*72+r, v.x); sw2(Zh,Zl,(c0+1)*72+r, v.y);
            sw2(Zh,Zl,(c0+2)*72+r, v.z); sw2(Zh,Zl,(c0+3)*72+r, v.w);
            sw2(Th,Tl,(c0+0)*72+r, w.x); sw2(Th,Tl,(c0+1)*72+r, w.y);
            sw2(Th,Tl,(c0+2)*72+r, w.z); sw2(Th,Tl,(c0+3)*72+r, w.w);
        }
        __syncthreads();
        #pragma unroll
        for (int jt=0;jt<4;jt++){
            accA[jt] = mm64(Zh,Zl,Zh,Zl, 16*wv, 16*jt, lrow, lkb, accA[jt]);
            accR[jt] = mm64(Zh,Zl,Th,Tl, 16*wv, 16*jt, lrow, lkb, accR[jt]);
        }
    }
    {
        const int gi0 = 16*wv + (lane>>4)*4;
        #pragma unroll
        for (int jt=0;jt<4;jt++){
            #pragma unroll
            for (int e=0;e<4;e++){
                Wf[(gi0+e)*68 + 16*jt + lrow] = accA[jt][e];   // Ac
                Rf[(gi0+e)*68 + 16*jt + lrow] = accR[jt][e];   // Rc
            }
        }
    }
    __syncthreads();
    // zn2 = sum(diag(Ac)) + sum(szs^2)/256 (raw Frobenius^2); tinv from tn2
    if (t<64){
        float dg = Wf[t*68+t];
        #pragma unroll
        for (int off=32; off; off>>=1) dg += __shfl_down(dg, off);
        if (t==0){
            float zn2 = dg + sc[2]*inv256;
            sc[0] = 1.0f/sqrtf(zn2);
            sc[1] = 1.0f/sqrtf(sc[1]);
        }
    }
    __syncthreads();
    const float zinv = sc[0], tinv = sc[1];
    const float z2 = zinv*zinv, zt = zinv*tinv;
    const float i23 = 2.0f/3.0f, i13 = 1.0f/3.0f;
    const int i = t>>2, qd = t&3;
    // E = (2/3) z2 Ac - (1/3) I ; R'' = (2/3) zt Rc ; Wt0 = R''^T planes
    {
        #pragma unroll
        for (int q=0;q<4;q++){
            const int j = qd*16 + q*4;
            float4 a4 = *(const float4*)(Wf + i*68 + j);
            float e0 = i23*z2*a4.x - ((i==j  ) ? i13 : 0.f);
            float e1 = i23*z2*a4.y - ((i==j+1) ? i13 : 0.f);
            float e2 = i23*z2*a4.z - ((i==j+2) ? i13 : 0.f);
            float e3 = i23*z2*a4.w - ((i==j+3) ? i13 : 0.f);
            sw2x2(Eh, El, i*72 + j,   e0, e1);
            sw2x2(Eh, El, i*72 + j+2, e2, e3);
            float4 rv = *(float4*)(Rf + i*68 + j);
            float r0 = i23*zt*rv.x;
            float r1 = i23*zt*rv.y;
            float r2 = i23*zt*rv.z;
            float r3 = i23*zt*rv.w;
            *(float4*)(Rf + i*68 + j) = make_float4(r0,r1,r2,r3);
            sw2(Wth[0], Wtl[0], (j  )*72 + i, r0);
            sw2(Wth[0], Wtl[0], (j+1)*72 + i, r1);
            sw2(Wth[0], Wtl[0], (j+2)*72 + i, r2);
            sw2(Wth[0], Wtl[0], (j+3)*72 + i, r3);
        }
    }
    __syncthreads();

    // Horner: W <- R'' - E*W  (12 iterations)
    int cur = 0;
    for (int n=0; n<12; n++){
        f32x4 acc[4];
        #pragma unroll
        for (int jt=0; jt<4; jt++){
            f32x4 zz = {0.f,0.f,0.f,0.f};
            acc[jt] = mm64(Eh, El, Wth[cur], Wtl[cur], 16*wv, jt*16, lrow, lkb, zz);
        }
        const int gi0 = 16*wv + (lane>>4)*4;
        #pragma unroll
        for (int jt=0; jt<4; jt++){
            const int gj = jt*16 + lrow;
            float w0 = Rf[(gi0  )*68 + gj] - acc[jt][0];
            float w1 = Rf[(gi0+1)*68 + gj] - acc[jt][1];
            float w2 = Rf[(gi0+2)*68 + gj] - acc[jt][2];
            float w3 = Rf[(gi0+3)*68 + gj] - acc[jt][3];
            sw2x2(Wth[cur^1], Wtl[cur^1], gj*72 + gi0,   w0, w1);
            sw2x2(Wth[cur^1], Wtl[cur^1], gj*72 + gi0+2, w2, w3);
            if (n == 11){
                Wf[(gi0  )*68 + gj] = w0;  wb[(gi0  )*64 + gj] = w0;
                Wf[(gi0+1)*68 + gj] = w1;  wb[(gi0+1)*64 + gj] = w1;
                Wf[(gi0+2)*68 + gj] = w2;  wb[(gi0+2)*64 + gj] = w2;
                Wf[(gi0+3)*68 + gj] = w3;  wb[(gi0+3)*64 + gj] = w3;
            }
        }
        cur ^= 1;
        __syncthreads();
    }

    if (t < 64){
        float s = 0.f;
        for (int i2=0; i2<64; i2++) s += szs[i2]*Wf[i2*68 + t];
        wb[4096+t] = (tinv*sts[t] - zinv*s) * inv256;
    }
    if (t==0){ wb[4160] = zinv; wb[4161] = tinv; }
}

// =================== KRG: fused residual (MFMA) + Renyi Gram (MFMA) ===================
__global__ __launch_bounds__(256) void kRG(
    const float* __restrict__ fx, const float* __restrict__ fy,
    const float* __restrict__ x, const float* __restrict__ y,
    const float* __restrict__ wbuf,
    float* __restrict__ part3, float* __restrict__ dout)
{
    const int blk = blockIdx.x;
    const int jh = blk & 1;
    const int b = (blk >> 1) & (NB-1);
    const int side = (blk >> 1) >> 6;
    const float* feat = side ? fy : fx;
    const float* targ = side ? x : y;
    const float* bmat = side ? y : x;
    const float* wb = wbuf + (size_t)(b*2+side)*WSTRIDE;
    const int t = threadIdx.x;
    const int lane = t & 63, wv = t >> 6;
    const int lrow = lane & 15, lkb = (lane>>4)*16;

    __shared__ unsigned short resA[256*72];
    __shared__ unsigned short tgB [256*72];
    __shared__ unsigned short Zh[2*4608], Zl[2*4608];
    __shared__ unsigned short Wth[4608], Wtl[4608];
    __shared__ float c0s[64];
    __shared__ float nAs[256], nBs[256];
    __shared__ float red[4][3];
    __shared__ float lred[4];

    #pragma unroll
    for (int u=0;u<4;u++){
        int id = t + 256*u;
        int k = id>>4, c0 = (id&15)*4;
        float4 v = *(const float4*)(wb + (size_t)k*64 + c0);
        sw2(Wth, Wtl, (c0+0)*72 + k, v.x);
        sw2(Wth, Wtl, (c0+1)*72 + k, v.y);
        sw2(Wth, Wtl, (c0+2)*72 + k, v.z);
        sw2(Wth, Wtl, (c0+3)*72 + k, v.w);
    }
    if (t<64) c0s[t] = wb[4096+t];
    const float zinv = wb[4160], tinv = wb[4161];
    #pragma unroll
    for (int u=0;u<16;u++){
        int id = t + 256*u;
        int r = id>>4, c0 = (id&15)*4;
        float4 v = *(const float4*)(bmat + ((size_t)(b*NS+r))*ND + c0);
        ushort4 h;
        h.x=f2bf(v.x); h.y=f2bf(v.y); h.z=f2bf(v.z); h.w=f2bf(v.w);
        *(ushort4*)(tgB + r*72 + c0) = h;
    }
    #pragma unroll
    for (int u=0;u<4;u++){
        int id = t + 256*u;
        int r = id>>4, c0 = (id&15)*4;
        float4 v = *(const float4*)(feat + ((size_t)(b*NS + r))*NH2 + c0);
        sw2x2(Zh, Zl, r*72+c0,   v.x, v.y);
        sw2x2(Zh, Zl, r*72+c0+2, v.z, v.w);
    }
    __syncthreads();

    float lacc = 0.f;
    for (int c=0; c<4; c++){
        if (c < 3){
            unsigned short* zh = Zh + ((c+1)&1)*4608;
            unsigned short* zl = Zl + ((c+1)&1)*4608;
            #pragma unroll
            for (int u=0;u<4;u++){
                int id = t + 256*u;
                int r = id>>4, c0 = (id&15)*4;
                float4 v = *(const float4*)(feat + ((size_t)(b*NS + (c+1)*64 + r))*NH2 + c0);
                sw2x2(zh, zl, r*72+c0,   v.x, v.y);
                sw2x2(zh, zl, r*72+c0+2, v.z, v.w);
            }
        }
        const unsigned short* zh = Zh + (c&1)*4608;
        const unsigned short* zl = Zl + (c&1)*4608;
        f32x4 acc[4];
        #pragma unroll
        for (int jt=0; jt<4; jt++){
            f32x4 zz = {0.f,0.f,0.f,0.f};
            acc[jt] = mm64(zh, zl, Wth, Wtl, 16*wv, jt*16, lrow, lkb, zz);
        }
        const int r0 = 16*wv + (lane>>4)*4;
        #pragma unroll
        for (int jt=0; jt<4; jt++){
            const int gj = jt*16 + lrow;
            const float cc = c0s[gj];
            #pragma unroll
            for (int e=0;e<4;e++){
                const int grow = c*64 + r0 + e;
                float q = targ[((size_t)(b*NS+grow))*ND + gj];
                float rr = tinv*q - zinv*acc[jt][e] - cc;
                lacc += rr*rr;
                resA[grow*72 + gj] = f2bf(rr);
            }
        }
        __syncthreads();
    }

    {
        float l = lacc;
        #pragma unroll
        for (int off=32; off; off>>=1) l += __shfl_down(l, off);
        if (lane==0) lred[wv] = l;
    }
    {
        float sa=0.f, sb=0.f;
        #pragma unroll
        for (int j8=0;j8<8;j8++){
            bf16x8 va = *(const bf16x8*)((const char*)resA + (size_t)t*144 + j8*16);
            bf16x8 vb = *(const bf16x8*)((const char*)tgB  + (size_t)t*144 + j8*16);
            #pragma unroll
            for (int e2=0;e2<8;e2++){
                float fa = bf2f((unsigned short)va[e2]);
                float fb = bf2f((unsigned short)vb[e2]);
                sa += fa*fa; sb += fb*fb;
            }
        }
        nAs[t] = sa; nBs[t] = sb;
    }
    __syncthreads();
    if (t==0 && jh==0)
        dout[(side?256:192)+b] = lred[0]+lred[1]+lred[2]+lred[3];

    const char* pA = (const char*)resA;
    const char* pB = (const char*)tgB;
    const f32x4 zero4 = {0.f, 0.f, 0.f, 0.f};
    const float CEXP = -2.8853900817779268f;

    float Sa=0.f, Sb=0.f, Sab=0.f;
    #pragma unroll
    for (int it=0; it<4; it++){
        const int i0 = wv*64 + it*16;
        const int arow = i0 + lrow;
        bf16x8 aA0 = *(const bf16x8*)(pA + arow*144 + lkb);
        bf16x8 aA1 = *(const bf16x8*)(pA + arow*144 + lkb + 64);
        bf16x8 aB0 = *(const bf16x8*)(pB + arow*144 + lkb);
        bf16x8 aB1 = *(const bf16x8*)(pB + arow*144 + lkb + 64);
        float nAi[4], nBi[4];
        #pragma unroll
        for (int e=0;e<4;e++){
            int gi = i0 + (lane>>4)*4 + e;
            nAi[e] = nAs[gi]; nBi[e] = nBs[gi];
        }
        #pragma unroll
        for (int jt=0; jt<8; jt++){
            const int j0 = jh*128 + jt*16;
            const int brow = j0 + lrow;
            bf16x8 bA0 = *(const bf16x8*)(pA + brow*144 + lkb);
            bf16x8 bA1 = *(const bf16x8*)(pA + brow*144 + lkb + 64);
            bf16x8 bB0 = *(const bf16x8*)(pB + brow*144 + lkb);
            bf16x8 bB1 = *(const bf16x8*)(pB + brow*144 + lkb + 64);
            f32x4 cA = __builtin_amdgcn_mfma_f32_16x16x32_bf16(aA0, bA0, zero4, 0, 0, 0);
            cA = __builtin_amdgcn_mfma_f32_16x16x32_bf16(aA1, bA1, cA, 0, 0, 0);
            f32x4 cB = __builtin_amdgcn_mfma_f32_16x16x32_bf16(aB0, bB0, zero4, 0, 0, 0);
            cB = __builtin_amdgcn_mfma_f32_16x16x32_bf16(aB1, bB1, cB, 0, 0, 0);
            const int gj = j0 + lrow;
            const float nAj = nAs[gj], nBj = nBs[gj];
            #pragma unroll
            for (int e=0;e<4;e++){
                const int gi = i0 + (lane>>4)*4 + e;
                const float dda = (gi==gj) ? 0.f : (nAi[e] + nAj - 2.f*cA[e]);
                const float ddb = (gi==gj) ? 0.f : (nBi[e] + nBj - 2.f*cB[e]);
                const float ka2 = exp2f(CEXP*dda);
                const float kb2 = exp2f(CEXP*ddb);
                Sa += ka2; Sb += kb2; Sab += ka2*kb2;
            }
        }
    }
    #pragma unroll
    for (int off=32; off; off>>=1){
        Sa += __shfl_down(Sa,off); Sb += __shfl_down(Sb,off); Sab += __shfl_down(Sab,off);
    }
    if (lane==0){ red[wv][0]=Sa; red[wv][1]=Sb; red[wv][2]=Sab; }
    __syncthreads();
    if (t==0){
        float* o = part3 + (size_t)blk*3;
        o[0] = red[0][0]+red[1][0]+red[2][0]+red[3][0];
        o[1] = red[0][1]+red[1][1]+red[2][1]+red[3][1];
        o[2] = red[0][2]+red[1][2]+red[2][2]+red[3][2];
    }
}

// =================== K4 ===================
__global__ __launch_bounds__(64) void k4_final(
    const float* __restrict__ mean_part, const float* __restrict__ part3,
    const float* __restrict__ wc1, const float* __restrict__ bc1,
    const float* __restrict__ bn_gamma, const float* __restrict__ bn_beta,
    const float* __restrict__ w2, const float* __restrict__ b2,
    const float* __restrict__ wc2, const float* __restrict__ bc2,
    float* __restrict__ dout)
{
    const int t = threadIdx.x;
    __shared__ float ic[64][5];
    __shared__ float mu[5], iv[5];

    float o0 = bc1[0], o1 = bc1[1], o2 = bc1[2];
    for (int c=0;c<64;c++){
        float mv = mean_part[(t*4+0)*64+c] + mean_part[(t*4+1)*64+c]
                 + mean_part[(t*4+2)*64+c] + mean_part[(t*4+3)*64+c];
        mv *= (1.0f/256.0f);
        o0 += mv*wc1[c*3+0]; o1 += mv*wc1[c*3+1]; o2 += mv*wc1[c*3+2];
    }
    dout[t*3+0]=o0; dout[t*3+1]=o1; dout[t*3+2]=o2;
    {
        float m = fmaxf(o0,fmaxf(o1,o2));
        float e0=__expf(o0-m), e1=__expf(o1-m), e2=__expf(o2-m);
        float inv = 1.f/(e0+e1+e2);
        dout[640+t*3+0]=e0*inv; dout[640+t*3+1]=e1*inv; dout[640+t*3+2]=e2*inv;
    }
    float exy[2];
    #pragma unroll
    for (int side=0; side<2; side++){
        const float* pp = part3 + (size_t)((side*NB + t)*2)*3;
        float Sa = pp[0]+pp[3];
        float Sb = pp[1]+pp[4];
        float Sab= pp[2]+pp[5];
        float Hx  = 16.f - log2f(Sa);
        float Hy  = 16.f - log2f(Sb);
        float Hxy = 16.f - log2f(Sab);
        float mi = (Hx + Hy - Hxy) / fmaxf(Hx, Hy);
        dout[(side?384:320)+t] = mi;
        exy[side] = mi;
    }
    ic[t][0]=o0; ic[t][1]=o1; ic[t][2]=o2; ic[t][3]=exy[0]; ic[t][4]=exy[1];
    __syncthreads();
    if (t<5){
        float m=0.f;
        for (int bb=0;bb<64;bb++) m += ic[bb][t];
        m *= (1.f/64.f);
        float v=0.f;
        for (int bb=0;bb<64;bb++){ float d=ic[bb][t]-m; v+=d*d; }
        v *= (1.f/64.f);
        mu[t]=m; iv[t]=1.f/sqrtf(v+1e-5f);
    }
    __syncthreads();
    float vn[5];
    #pragma unroll
    for (int c=0;c<5;c++) vn[c] = (ic[t][c]-mu[c])*iv[c]*bn_gamma[c]+bn_beta[c];
    float q0=bc2[0], q1=bc2[1], q2=bc2[2];
    for (int j=0;j<64;j++){
        float hh = b2[j];
        #pragma unroll
        for (int c=0;c<5;c++) hh += vn[c]*w2[c*64+j];
        hh = fmaxf(hh,0.f);
        q0 += hh*wc2[j*3+0]; q1 += hh*wc2[j*3+1]; q2 += hh*wc2[j*3+2];
    }
    dout[448+t*3+0]=q0; dout[448+t*3+1]=q1; dout[448+t*3+2]=q2;
    float m = fmaxf(q0,fmaxf(q1,q2));
    float e0=__expf(q0-m), e1=__expf(q1-m), e2=__expf(q2-m);
    float inv=1.f/(e0+e1+e2);
    dout[832+t*3+0]=e0*inv; dout[832+t*3+1]=e1*inv; dout[832+t*3+2]=e2*inv;
}

extern "C" void kernel_launch(void* const* d_in, const int* in_sizes, int n_in,
                              void* d_out, int out_size, void* d_ws, size_t ws_size,
                              hipStream_t stream)
{
    const float* x     = (const float*)d_in[0];
    const float* y     = (const float*)d_in[1];
    const float* w11_1 = (const float*)d_in[2];
    const float* b11_1 = (const float*)d_in[3];
    const float* w11_2 = (const float*)d_in[4];
    const float* b11_2 = (const float*)d_in[5];
    const float* w12_1 = (const float*)d_in[6];
    const float* b12_1 = (const float*)d_in[7];
    const float* w12_2 = (const float*)d_in[8];
    const float* b12_2 = (const float*)d_in[9];
    const float* wc1   = (const float*)d_in[10];
    const float* bc1   = (const float*)d_in[11];
    const float* bn_g  = (const float*)d_in[12];
    const float* bn_b  = (const float*)d_in[13];
    const float* w2    = (const float*)d_in[14];
    const float* b2    = (const float*)d_in[15];
    const float* wc2   = (const float*)d_in[16];
    const float* bc2   = (const float*)d_in[17];

    float* ws   = (float*)d_ws;
    float* dout = (float*)d_out;
    float* out_x = ws;                           // 1,048,576 floats
    float* out_y = ws + 1048576;
    float* mean_part = ws + 2097152;             // 16384
    float* part3 = mean_part + 16384;            // 768 (alloc 3840)
    float* wbuf  = part3 + 3840;                 // 128*4224 = 540672

    hipLaunchKernelGGL(k1_fused, dim3(NB*4), dim3(512), 0, stream,
        x,y,w11_1,b11_1,w11_2,b11_2,w12_1,b12_1,w12_2,b12_2,
        out_x,out_y,mean_part);
    hipLaunchKernelGGL(k2ab, dim3(2*NB), dim3(256), 0, stream,
        out_x,out_y,x,y,wbuf);
    hipLaunchKernelGGL(kRG, dim3(NB*2*2), dim3(256), 0, stream,
        out_x,out_y,x,y,wbuf,part3,dout);
    hipLaunchKernelGGL(k4_final, dim3(1), dim3(64), 0, stream,
        mean_part,part3,wc1,bc1,bn_g,bn_b,w2,b2,wc2,bc2,dout);
}